// Round 3
// baseline (476.099 us; speedup 1.0000x reference)
//
#include <hip/hip_runtime.h>
#include <math.h>

#define B_ 2
#define S_ 2048
#define D_ 2048
#define H_ 16
#define QLORA 1536
#define KVLORA 512
#define DN 128
#define DR 64
#define DQK 192
#define DV 128
#define EPSF 1e-6f
#define SCALEF 0.07216878364870322f   // 192^-0.5

typedef short short8 __attribute__((ext_vector_type(8)));
typedef float float4v __attribute__((ext_vector_type(4)));

__device__ __forceinline__ unsigned short f2bf(float f) {
    union { float f; unsigned u; } x; x.f = f;
    unsigned r = x.u + 0x7fffu + ((x.u >> 16) & 1u);   // RNE
    return (unsigned short)(r >> 16);
}
__device__ __forceinline__ float bf2f(unsigned short u) {
    union { unsigned u; float f; } x; x.u = (unsigned)u << 16;
    return x.f;
}

// async global->LDS, 16B per lane; LDS dest = wave-uniform base + lane*16
#define GLD16(src, dst)                                                        \
    __builtin_amdgcn_global_load_lds(                                          \
        (const __attribute__((address_space(1))) void*)(src),                  \
        (__attribute__((address_space(3))) void*)(dst), 16, 0, 0)

// ---------------------------------------------------------------------------
// all fp32->bf16 conversions in ONE launch (6 ranges, if-chain)
// ---------------------------------------------------------------------------
__global__ __launch_bounds__(256) void conv_all(
        const float* __restrict__ s0, unsigned short* __restrict__ d0, long e0,
        const float* __restrict__ s1, unsigned short* __restrict__ d1, long e1,
        const float* __restrict__ s2, unsigned short* __restrict__ d2, long e2,
        const float* __restrict__ s3, unsigned short* __restrict__ d3, long e3,
        const float* __restrict__ s4, unsigned short* __restrict__ d4, long e4,
        const float* __restrict__ s5, unsigned short* __restrict__ d5) {
    long c = (long)blockIdx.x * 256 + threadIdx.x;   // 8-elem chunk index
    const float* src;
    unsigned short* dst;
    if      (c < e0) { src = s0; dst = d0; }
    else if (c < e1) { src = s1; dst = d1; c -= e0; }
    else if (c < e2) { src = s2; dst = d2; c -= e1; }
    else if (c < e3) { src = s3; dst = d3; c -= e2; }
    else if (c < e4) { src = s4; dst = d4; c -= e3; }
    else             { src = s5; dst = d5; c -= e4; }
    const float* p = src + c * 8;
    float4 a = *(const float4*)(p);
    float4 b = *(const float4*)(p + 4);
    union { short8 v; unsigned short u[8]; } t;
    t.u[0] = f2bf(a.x); t.u[1] = f2bf(a.y); t.u[2] = f2bf(a.z); t.u[3] = f2bf(a.w);
    t.u[4] = f2bf(b.x); t.u[5] = f2bf(b.y); t.u[6] = f2bf(b.z); t.u[7] = f2bf(b.w);
    *(short8*)&dst[c * 8] = t.v;
}

// ---------------------------------------------------------------------------
// bf16 MFMA GEMM:  C[M,N] = A[M,K] @ W[N,K]^T; OT = float or ushort(bf16) out.
// 128x128 tile, BK=64; global_load_lds width=16 staging with XOR swizzle.
// ---------------------------------------------------------------------------
#define GBM 128
#define GBN 128
#define GBK 64

template <typename OT>
__global__ __launch_bounds__(256) void gemm_t(const unsigned short* __restrict__ A,
                                              const unsigned short* __restrict__ W,
                                              OT* __restrict__ C,
                                              int M, int N, int K) {
    __shared__ unsigned short As[GBM * GBK];   // 16384 B
    __shared__ unsigned short Ws[GBN * GBK];   // 16384 B

    const int tid = threadIdx.x;
    const int w = tid >> 6, lane = tid & 63;
    const int l16 = lane & 15, quad = lane >> 4;
    const int wm = (w >> 1) * 64, wn = (w & 1) * 64;
    const int row0 = blockIdx.y * GBM, col0 = blockIdx.x * GBN;

    const int rL  = lane >> 3;
    const int c8g = (lane & 7) ^ rL;
    const int swzk[2] = { (((0 * 4) + quad) ^ (l16 & 7)) * 8,
                          (((1 * 4) + quad) ^ (l16 & 7)) * 8 };

    const float4v zf = {0.f, 0.f, 0.f, 0.f};
    float4v acc[4][4] = {{zf, zf, zf, zf}, {zf, zf, zf, zf},
                         {zf, zf, zf, zf}, {zf, zf, zf, zf}};

    for (int k0 = 0; k0 < K; k0 += GBK) {
        __syncthreads();
#pragma unroll
        for (int j = 0; j < 4; ++j) {
            const int ch = w * 4 + j;
            const int r = ch * 8 + rL;
            GLD16(&A[(size_t)(row0 + r) * K + k0 + c8g * 8], &As[ch * 512]);
            GLD16(&W[(size_t)(col0 + r) * K + k0 + c8g * 8], &Ws[ch * 512]);
        }
        __syncthreads();

#pragma unroll
        for (int kk = 0; kk < 2; ++kk) {
            const int swz = swzk[kk];
            short8 af[4], bf[4];
#pragma unroll
            for (int mi = 0; mi < 4; ++mi)
                af[mi] = *(const short8*)&As[(wm + mi * 16 + l16) * GBK + swz];
#pragma unroll
            for (int ni = 0; ni < 4; ++ni)
                bf[ni] = *(const short8*)&Ws[(wn + ni * 16 + l16) * GBK + swz];
#pragma unroll
            for (int mi = 0; mi < 4; ++mi)
#pragma unroll
                for (int ni = 0; ni < 4; ++ni)
                    acc[mi][ni] = __builtin_amdgcn_mfma_f32_16x16x32_bf16(af[mi], bf[ni], acc[mi][ni], 0, 0, 0);
        }
    }

#pragma unroll
    for (int mi = 0; mi < 4; ++mi)
#pragma unroll
        for (int ni = 0; ni < 4; ++ni)
#pragma unroll
            for (int r = 0; r < 4; ++r) {
                size_t idx = (size_t)(row0 + wm + mi * 16 + quad * 4 + r) * N + col0 + wn + ni * 16 + l16;
                if constexpr (sizeof(OT) == 2) C[idx] = f2bf(acc[mi][ni][r]);
                else                           C[idx] = acc[mi][ni][r];
            }
}

// ---------------------------------------------------------------------------
__global__ __launch_bounds__(256) void rmsnorm_b(const float* __restrict__ X,
                                                 const float* __restrict__ w,
                                                 unsigned short* __restrict__ Y,
                                                 int n, int ld) {
    __shared__ float tmp[4];
    const int row = blockIdx.x;
    const int tid = threadIdx.x;
    const float* x = X + (size_t)row * ld;

    float ss = 0.f;
    for (int c = tid; c < n; c += 256) {
        float v = x[c];
        ss = fmaf(v, v, ss);
    }
#pragma unroll
    for (int off = 32; off; off >>= 1) ss += __shfl_xor(ss, off, 64);
    if ((tid & 63) == 0) tmp[tid >> 6] = ss;
    __syncthreads();
    ss = tmp[0] + tmp[1] + tmp[2] + tmp[3];
    float r = rsqrtf(ss / (float)n + EPSF);

    for (int c = tid; c < n; c += 256)
        Y[(size_t)row * n + c] = f2bf(x[c] * r * w[c]);
}

// ---------------------------------------------------------------------------
__global__ __launch_bounds__(256) void kv_post(const float* __restrict__ KV,
                                               const float* __restrict__ w,
                                               const float* __restrict__ fc,
                                               unsigned short* __restrict__ kvcb,
                                               float* __restrict__ kpe,
                                               int ldkv) {
    __shared__ float tmp[4];
    const int row = blockIdx.x;
    const int s = row & (S_ - 1);
    const int tid = threadIdx.x;
    const float* kv = KV + (size_t)row * ldkv;

    float ss = 0.f;
#pragma unroll
    for (int c = tid; c < KVLORA; c += 256) {
        float v = kv[c];
        ss = fmaf(v, v, ss);
    }
#pragma unroll
    for (int off = 32; off; off >>= 1) ss += __shfl_xor(ss, off, 64);
    if ((tid & 63) == 0) tmp[tid >> 6] = ss;
    __syncthreads();
    ss = tmp[0] + tmp[1] + tmp[2] + tmp[3];
    float r = rsqrtf(ss / (float)KVLORA + EPSF);

#pragma unroll
    for (int c = tid; c < KVLORA; c += 256)
        kvcb[(size_t)row * KVLORA + c] = f2bf(kv[c] * r * w[c]);

    if (tid < 32) {
        int i = tid;
        float c0 = fc[(s * 32 + i) * 2 + 0];
        float s0 = fc[(s * 32 + i) * 2 + 1];
        float x0 = kv[KVLORA + 2 * i];
        float x1 = kv[KVLORA + 2 * i + 1];
        kpe[(size_t)row * DR + 2 * i]     = x0 * c0 - x1 * s0;
        kpe[(size_t)row * DR + 2 * i + 1] = x0 * s0 + x1 * c0;
    }
}

// ---------------------------------------------------------------------------
// pack_k: Kbf (B,H,S,192) bf16 from kvbb (M,H*256) bf16 + kpe (M,64) fp32
// ---------------------------------------------------------------------------
__global__ __launch_bounds__(256) void pack_k(const unsigned short* __restrict__ kvbb,
                                              const float* __restrict__ kpe,
                                              unsigned short* __restrict__ Kbf) {
    const int c = blockIdx.x * 256 + threadIdx.x;   // chunk of 8 elems
    const int total = B_ * H_ * S_ * (DQK / 8);
    if (c >= total) return;
    const int d8 = c % (DQK / 8);
    const int hs = c / (DQK / 8);
    const int s  = hs % S_;
    const int bh = hs / S_;
    const int b  = bh / H_;
    const int h  = bh % H_;
    const int d  = d8 * 8;
    const int row = b * S_ + s;

    short8 v;
    if (d < DN) {
        v = *(const short8*)&kvbb[(size_t)row * (H_ * 256) + h * 256 + d];
    } else {
        const float* src = kpe + (size_t)row * DR + (d - DN);
        float4 a = *(const float4*)(src);
        float4 bb = *(const float4*)(src + 4);
        union { short8 v; unsigned short u[8]; } t;
        t.u[0] = f2bf(a.x);  t.u[1] = f2bf(a.y);  t.u[2] = f2bf(a.z);  t.u[3] = f2bf(a.w);
        t.u[4] = f2bf(bb.x); t.u[5] = f2bf(bb.y); t.u[6] = f2bf(bb.z); t.u[7] = f2bf(bb.w);
        v = t.v;
    }
    *(short8*)&Kbf[(size_t)c * 8] = v;
}

// ---------------------------------------------------------------------------
// pack_vt: Vt (B,H,128,S) bf16 from kvbb (M,H*256) bf16 cols h*256+128..+256
// ---------------------------------------------------------------------------
__global__ __launch_bounds__(256) void pack_vt(const unsigned short* __restrict__ kvbb,
                                               unsigned short* __restrict__ Vt) {
    __shared__ unsigned short T[DV][72];
    const int st = blockIdx.x;            // seq tile (64)
    const int bh = blockIdx.y;            // b*H+h
    const int b = bh >> 4, h = bh & 15;
    const int s0 = st * 64;
    const int tid = threadIdx.x;

    for (int c = tid; c < 64 * 16; c += 256) {
        int sp = c >> 4, ch = c & 15;
        short8 v = *(const short8*)&kvbb[(size_t)(b * S_ + s0 + sp) * (H_ * 256) + h * 256 + DN + ch * 8];
        union { short8 v; unsigned short u[8]; } t; t.v = v;
        int dv = ch * 8;
#pragma unroll
        for (int e = 0; e < 8; ++e) T[dv + e][sp] = t.u[e];
    }
    __syncthreads();
    for (int c = tid; c < 128 * 8; c += 256) {
        int dv = c >> 3, ch = c & 7;
        *(short8*)&Vt[((size_t)bh * DV + dv) * S_ + s0 + ch * 8] = *(short8*)&T[dv][ch * 8];
    }
}

// ---------------------------------------------------------------------------
// MFMA flash attention (causal), bf16 in (q with fused RoPE), fp32 acc.
//
// v4 (LDS-traffic / 2-blocks-per-CU over v3):
//  - v3 was LDS-BW bound: 8 waves x 16 q-rows each re-read the full 64-key
//    K/V tile -> ~350 KB LDS per CU per tile, ~5950 cy/tile vs ~4100 cy LDS
//    service floor. LDS bytes scale as 1/(q-rows-per-wave).
//  - v4: 4 waves x 32 q-rows (2 A-groups/wave, q-tile stays 128), KVBLK=32
//    -> block LDS = 51200 B -> 2 blocks/CU (8 waves/CU kept; the two blocks
//    overlap each other's barrier drains). LDS per unit work: ~192 KB.
//  - grid 512 = (bh | qt): blocks c and c+256 pair qt and 15-qt on one CU
//    under round-robin dispatch -> ~68 32-key tiles per CU (balance is a
//    perf heuristic only).
//  - keeps: global_load_lds(16B) XOR-swizzled staging (conflicts = 0),
//    double-buffered K/V, counted vmcnt(5), wave-private Ps, no mid barrier.
//  - swizzles at KVBLK=32 strides: K row r chunk c -> c ^ (r&7) (unchanged);
//    V (row stride 64 B, 4 chunks) -> c ^ ((dv>>1)&3); Ps stride 40 (2-way
//    on b16 writes = free per m136).
// ---------------------------------------------------------------------------
#define QTILES 16   // 2048 / 128
#define KVB 32
#define PROW 40

__global__ __launch_bounds__(256, 2) void flash_mfma(const unsigned short* __restrict__ Qb,
                                                     const float* __restrict__ fc,
                                                     const unsigned short* __restrict__ Kbf,
                                                     const unsigned short* __restrict__ Vt,
                                                     unsigned short* __restrict__ Ob) {
    __shared__ unsigned short Ks[2][KVB * 192];   // 2 x 12288 B, swizzled chunks
    __shared__ unsigned short Vs[2][DV * KVB];    // 2 x  8192 B, swizzled chunks
    __shared__ unsigned short Ps[4][32][PROW];    // 10240 B, wave-private P

    const int id = blockIdx.x;                  // 0..511
    const int bh = id & 31;                     // b*H+h
    const int t  = id >> 5;                     // 0..15
    const int qt = (t < 8) ? t : (23 - t);      // pairs (t, t+8) -> qt sums 15
    const int b = bh >> 4, h = bh & 15;
    const int tid = threadIdx.x;
    const int w = tid >> 6, lane = tid & 63;
    const int l16 = lane & 15, quad = lane >> 4;
    const int sw = l16 & 7;                     // K read-side swizzle key
    const int swv = (l16 >> 1) & 3;             // V read-side swizzle key

    const unsigned short* Kg = Kbf + (size_t)bh * S_ * DQK;
    const unsigned short* Vg = Vt + (size_t)bh * DV * S_;

    // stage K/V tile kt_ (32 keys) into buffer bufi: 5 global_load_lds/wave.
    auto stage = [&](int kt_, int bufi) {
        const int kb_ = kt_ * KVB;
#pragma unroll
        for (int i_ = 0; i_ < 3; ++i_) {             // K: 32 rows x 24 chunks
            int ch = (w * 3 + i_) * 64 + lane;
            int r_ = ch / 24, c_ = ch - r_ * 24;
            GLD16(&Kg[(size_t)(kb_ + r_) * DQK + ((c_ ^ (r_ & 7)) << 3)],
                  &Ks[bufi][(w * 3 + i_) * 512]);
        }
#pragma unroll
        for (int i_ = 0; i_ < 2; ++i_) {             // V: 128 rows x 4 chunks
            int ch = (w * 2 + i_) * 64 + lane;
            int r_ = ch >> 2, c_ = ch & 3;
            GLD16(&Vg[(size_t)r_ * S_ + kb_ + ((c_ ^ ((r_ >> 1) & 3)) << 3)],
                  &Vs[bufi][(w * 2 + i_) * 512]);
        }
    };

    const int q0 = qt * 128;
    const int ntiles = 4 * qt + 4;              // 32-key tiles
    const int wr0 = q0 + w * 32;                // wave's first q row

    stage(0, 0);                                // tile 0 DMA in flight

    // Q A-frags: 2 groups of 16 rows, RoPE fused for d >= 128
    short8 a_q[2][6];
#pragma unroll
    for (int g = 0; g < 2; ++g) {
        const int s = wr0 + g * 16 + l16;
        const unsigned short* qrow = Qb + (size_t)(b * S_ + s) * (H_ * DQK) + h * DQK;
#pragma unroll
        for (int i = 0; i < 6; ++i) {
            short8 tq = *(const short8*)&qrow[i * 32 + quad * 8];
            if (i >= 4) {
                union { short8 v; unsigned short u[8]; } x; x.v = tq;
#pragma unroll
                for (int j = 0; j < 4; ++j) {
                    int ip = (i - 4) * 16 + quad * 4 + j;
                    float c0 = fc[(s * 32 + ip) * 2 + 0];
                    float s0 = fc[(s * 32 + ip) * 2 + 1];
                    float x0 = bf2f(x.u[2 * j]);
                    float x1 = bf2f(x.u[2 * j + 1]);
                    x.u[2 * j]     = f2bf(x0 * c0 - x1 * s0);
                    x.u[2 * j + 1] = f2bf(x0 * s0 + x1 * c0);
                }
                tq = x.v;
            }
            a_q[g][i] = tq;
        }
    }

    const float4v zf = {0.f, 0.f, 0.f, 0.f};
    float4v o_acc[2][8] = {{zf, zf, zf, zf, zf, zf, zf, zf},
                           {zf, zf, zf, zf, zf, zf, zf, zf}};
    float l_r[2][4] = {{0.f, 0.f, 0.f, 0.f}, {0.f, 0.f, 0.f, 0.f}};

    int buf = 0;
    for (int kt = 0; kt < ntiles; ++kt) {
        const int kb = kt * KVB;

        // barrier 1: everyone done computing kt-1 -> buf^1 overwritable
        __builtin_amdgcn_s_barrier();
        if (kt + 1 < ntiles) {
            stage(kt + 1, buf ^ 1);
            asm volatile("s_waitcnt vmcnt(5)" ::: "memory");   // own kt loads done
        } else {
            asm volatile("s_waitcnt vmcnt(0)" ::: "memory");
        }
        __builtin_amdgcn_sched_barrier(0);
        // barrier 2: everyone's kt loads landed
        __builtin_amdgcn_s_barrier();
        __builtin_amdgcn_sched_barrier(0);

        if (kb <= wr0 + 31) {                   // wave not fully causal-masked
            const unsigned short* Kb_ = Ks[buf];
            const unsigned short* Vb_ = Vs[buf];

            // QK^T: 12 ds_read_b128 -> 24 mfma (4 independent acc chains)
            float4v sc[2][2] = {{zf, zf}, {zf, zf}};
#pragma unroll
            for (int i = 0; i < 6; ++i) {
                short8 bk[2];
#pragma unroll
                for (int kg = 0; kg < 2; ++kg)
                    bk[kg] = *(const short8*)&Kb_[(kg * 16 + l16) * 192 + (((i * 4 + quad) ^ sw) << 3)];
#pragma unroll
                for (int kg = 0; kg < 2; ++kg) {
                    sc[0][kg] = __builtin_amdgcn_mfma_f32_16x16x32_bf16(a_q[0][i], bk[kg], sc[0][kg], 0, 0, 0);
                    sc[1][kg] = __builtin_amdgcn_mfma_f32_16x16x32_bf16(a_q[1][i], bk[kg], sc[1][kg], 0, 0, 0);
                }
            }

            // max-free softmax (mask post-exp; wave-uniform mneed branch)
#pragma unroll
            for (int g = 0; g < 2; ++g) {
                const int rg0 = wr0 + g * 16;
                const bool mneed = (kb + KVB - 1 > rg0);
#pragma unroll
                for (int kg = 0; kg < 2; ++kg) {
                    const int key = kb + kg * 16 + l16;
#pragma unroll
                    for (int r = 0; r < 4; ++r) {
                        float p = __expf(sc[g][kg][r] * SCALEF);
                        if (mneed && key > rg0 + quad * 4 + r) p = 0.f;
                        l_r[g][r] += p;
                        Ps[w][g * 16 + quad * 4 + r][kg * 16 + l16] = f2bf(p);
                    }
                }
            }

            // PV: Ps is wave-private -> no barrier needed before reads
            {
                short8 pa0 = *(const short8*)&Ps[w][l16][quad * 8];
                short8 pa1 = *(const short8*)&Ps[w][16 + l16][quad * 8];
#pragma unroll
                for (int dvt = 0; dvt < 8; ++dvt) {
                    short8 vb = *(const short8*)&Vb_[(dvt * 16 + l16) * KVB + ((quad ^ swv) << 3)];
                    o_acc[0][dvt] = __builtin_amdgcn_mfma_f32_16x16x32_bf16(pa0, vb, o_acc[0][dvt], 0, 0, 0);
                    o_acc[1][dvt] = __builtin_amdgcn_mfma_f32_16x16x32_bf16(pa1, vb, o_acc[1][dvt], 0, 0, 0);
                }
            }
        }
        buf ^= 1;
    }

    // epilogue: reduce l over the 16 key-lanes, write O
#pragma unroll
    for (int g = 0; g < 2; ++g)
#pragma unroll
        for (int r = 0; r < 4; ++r) {
            float tt = l_r[g][r];
            tt += __shfl_xor(tt, 1);
            tt += __shfl_xor(tt, 2);
            tt += __shfl_xor(tt, 4);
            tt += __shfl_xor(tt, 8);
            l_r[g][r] = tt;
        }
#pragma unroll
    for (int g = 0; g < 2; ++g)
#pragma unroll
        for (int r = 0; r < 4; ++r) {
            float inv = 1.f / l_r[g][r];
            int row = wr0 + g * 16 + quad * 4 + r;
            unsigned short* op = Ob + (size_t)(b * S_ + row) * (H_ * DV) + h * DV;
#pragma unroll
            for (int dvt = 0; dvt < 8; ++dvt)
                op[dvt * 16 + l16] = f2bf(o_acc[g][dvt][r] * inv);
        }
}

// ---------------------------------------------------------------------------
extern "C" void kernel_launch(void* const* d_in, const int* in_sizes, int n_in,
                              void* d_out, int out_size, void* d_ws, size_t ws_size,
                              hipStream_t stream) {
    const float* x    = (const float*)d_in[0];
    const float* fc   = (const float*)d_in[1];
    const float* Wqa  = (const float*)d_in[2];
    const float* qlw  = (const float*)d_in[3];
    const float* Wqb  = (const float*)d_in[4];
    const float* Wkva = (const float*)d_in[5];
    const float* kvw  = (const float*)d_in[6];
    const float* Wkvb = (const float*)d_in[7];
    const float* Wo   = (const float*)d_in[8];
    float* out = (float*)d_out;

    const int M = B_ * S_;                 // 4096
    const int NQKV = QLORA + 640;          // 2176
    char* wsb = (char*)d_ws;

    // R1 (50331648 B): qb bf16 (25165824) + Wob (8388608)
    unsigned short* qb  = (unsigned short*)wsb;
    unsigned short* Wob = (unsigned short*)(wsb + 25165824);
    // R2 (67108864 B)
    char* R2 = wsb + 50331648;
    float*          qlkv  = (float*)R2;                          // 35651584
    unsigned short* xb    = (unsigned short*)(R2 + 35651584);    // 16777216
    unsigned short* Wcat  = (unsigned short*)(R2 + 52428800);    //  8912896
    unsigned short* kvbb  = (unsigned short*)R2;                 // 33554432 (after qlkv dead)
    unsigned short* attnb = (unsigned short*)R2;                 // 16777216 (after packs)
    // R3 (25165824 B)
    char* R3 = R2 + 67108864;
    unsigned short* qlatb = (unsigned short*)R3;                 // 12582912
    unsigned short* Wqbb  = (unsigned short*)(R3 + 12582912);    //  9437184
    unsigned short* Kbf   = (unsigned short*)R3;                 // 25165824 (after q-gemm)
    // R4 (16777216 B)
    char* R4 = R3 + 25165824;
    float*          kpe   = (float*)R4;                          //  1048576
    unsigned short* kvcb  = (unsigned short*)(R4 + 1048576);     //  4194304
    unsigned short* Wkvbb = (unsigned short*)(R4 + 5242880);     //  4194304
    unsigned short* Vt    = (unsigned short*)R4;                 // 16777216 (after pack_k)

    // 0) single mega-conversion: x, Wqa, Wkva, Wqb, Wkvb, Wo
    {
        const long e0 = 1048576;           // x      (M*D/8)
        const long e1 = e0 + 393216;       // Wqa    (1536*2048/8)
        const long e2 = e1 + 147456;       // Wkva   (576*2048/8)
        const long e3 = e2 + 589824;       // Wqb    (3072*1536/8)
        const long e4 = e3 + 262144;       // Wkvb   (4096*512/8)
        const long tot = e4 + 524288;      // Wo     (2048*2048/8) -> 2965504
        conv_all<<<(int)(tot / 256), 256, 0, stream>>>(
            x, xb, e0,
            Wqa, Wcat, e1,
            Wkva, Wcat + (size_t)QLORA * D_, e2,
            Wqb, Wqbb, e3,
            Wkvb, Wkvbb, e4,
            Wo, Wob);
    }

    // 1) merged: qlkv = xb @ Wcat^T (cols 0..1535 = qlat, 1536..2111 = kvraw)
    gemm_t<float><<<dim3(NQKV / GBN, M / GBM), 256, 0, stream>>>(xb, Wcat, qlkv, M, NQKV, D_);

    // 2) norms (emit bf16) + k_pe rope
    rmsnorm_b<<<M, 256, 0, stream>>>(qlkv, qlw, qlatb, QLORA, NQKV);
    kv_post<<<M, 256, 0, stream>>>(qlkv + QLORA, kvw, fc, kvcb, kpe, NQKV);

    // 3) qb = qlatb @ Wqbb^T (bf16 out; RoPE fused into flash Q load)
    //    kvbb = kvcb @ Wkvbb^T (bf16 out)
    gemm_t<unsigned short><<<dim3(H_ * DQK / GBN, M / GBM), 256, 0, stream>>>(qlatb, Wqbb, qb, M, H_ * DQK, QLORA);
    gemm_t<unsigned short><<<dim3(H_ * 256 / GBN, M / GBM), 256, 0, stream>>>(kvcb, Wkvbb, kvbb, M, H_ * 256, KVLORA);

    // 4) pack K then V (pack_k reads kpe which Vt overwrites -> strict order)
    {
        int total = B_ * H_ * S_ * (DQK / 8);
        pack_k<<<(total + 255) / 256, 256, 0, stream>>>(kvbb, kpe, Kbf);
        pack_vt<<<dim3(S_ / 64, B_ * H_), 256, 0, stream>>>(kvbb, Vt);
    }

    // 5) flash attention: 512 blocks (bh | qt), 4 waves x 32 q-rows, 2 blk/CU
    flash_mfma<<<dim3(B_ * H_ * QTILES), 256, 0, stream>>>(qb, fc, Kbf, Vt, attnb);

    // 6) out = attnb @ Wob^T
    gemm_t<float><<<dim3(D_ / GBN, M / GBM), 256, 0, stream>>>(attnb, Wob, out, M, D_, D_);
}

// Round 4
// 466.855 us; speedup vs baseline: 1.0198x; 1.0198x over previous
//
#include <hip/hip_runtime.h>
#include <math.h>

#define B_ 2
#define S_ 2048
#define D_ 2048
#define H_ 16
#define QLORA 1536
#define KVLORA 512
#define DN 128
#define DR 64
#define DQK 192
#define DV 128
#define EPSF 1e-6f
#define SCALEF 0.07216878364870322f   // 192^-0.5

typedef short short8 __attribute__((ext_vector_type(8)));
typedef float float4v __attribute__((ext_vector_type(4)));

__device__ __forceinline__ unsigned short f2bf(float f) {
    union { float f; unsigned u; } x; x.f = f;
    unsigned r = x.u + 0x7fffu + ((x.u >> 16) & 1u);   // RNE
    return (unsigned short)(r >> 16);
}
__device__ __forceinline__ float bf2f(unsigned short u) {
    union { unsigned u; float f; } x; x.u = (unsigned)u << 16;
    return x.f;
}

// async global->LDS, 16B per lane; LDS dest = wave-uniform base + lane*16
#define GLD16(src, dst)                                                        \
    __builtin_amdgcn_global_load_lds(                                          \
        (const __attribute__((address_space(1))) void*)(src),                  \
        (__attribute__((address_space(3))) void*)(dst), 16, 0, 0)

// ---------------------------------------------------------------------------
// all fp32->bf16 conversions in ONE launch (6 ranges, if-chain)
// ---------------------------------------------------------------------------
__global__ __launch_bounds__(256) void conv_all(
        const float* __restrict__ s0, unsigned short* __restrict__ d0, long e0,
        const float* __restrict__ s1, unsigned short* __restrict__ d1, long e1,
        const float* __restrict__ s2, unsigned short* __restrict__ d2, long e2,
        const float* __restrict__ s3, unsigned short* __restrict__ d3, long e3,
        const float* __restrict__ s4, unsigned short* __restrict__ d4, long e4,
        const float* __restrict__ s5, unsigned short* __restrict__ d5) {
    long c = (long)blockIdx.x * 256 + threadIdx.x;   // 8-elem chunk index
    const float* src;
    unsigned short* dst;
    if      (c < e0) { src = s0; dst = d0; }
    else if (c < e1) { src = s1; dst = d1; c -= e0; }
    else if (c < e2) { src = s2; dst = d2; c -= e1; }
    else if (c < e3) { src = s3; dst = d3; c -= e2; }
    else if (c < e4) { src = s4; dst = d4; c -= e3; }
    else             { src = s5; dst = d5; c -= e4; }
    const float* p = src + c * 8;
    float4 a = *(const float4*)(p);
    float4 b = *(const float4*)(p + 4);
    union { short8 v; unsigned short u[8]; } t;
    t.u[0] = f2bf(a.x); t.u[1] = f2bf(a.y); t.u[2] = f2bf(a.z); t.u[3] = f2bf(a.w);
    t.u[4] = f2bf(b.x); t.u[5] = f2bf(b.y); t.u[6] = f2bf(b.z); t.u[7] = f2bf(b.w);
    *(short8*)&dst[c * 8] = t.v;
}

// ---------------------------------------------------------------------------
// bf16 MFMA GEMM:  C[M,N] = A[M,K] @ W[N,K]^T; OT = float or ushort(bf16) out.
// 128x128 tile, BK=64; global_load_lds width=16 staging with XOR swizzle.
// ---------------------------------------------------------------------------
#define GBM 128
#define GBN 128
#define GBK 64

template <typename OT>
__global__ __launch_bounds__(256) void gemm_t(const unsigned short* __restrict__ A,
                                              const unsigned short* __restrict__ W,
                                              OT* __restrict__ C,
                                              int M, int N, int K) {
    __shared__ unsigned short As[GBM * GBK];   // 16384 B
    __shared__ unsigned short Ws[GBN * GBK];   // 16384 B

    const int tid = threadIdx.x;
    const int w = tid >> 6, lane = tid & 63;
    const int l16 = lane & 15, quad = lane >> 4;
    const int wm = (w >> 1) * 64, wn = (w & 1) * 64;
    const int row0 = blockIdx.y * GBM, col0 = blockIdx.x * GBN;

    const int rL  = lane >> 3;
    const int c8g = (lane & 7) ^ rL;
    const int swzk[2] = { (((0 * 4) + quad) ^ (l16 & 7)) * 8,
                          (((1 * 4) + quad) ^ (l16 & 7)) * 8 };

    const float4v zf = {0.f, 0.f, 0.f, 0.f};
    float4v acc[4][4] = {{zf, zf, zf, zf}, {zf, zf, zf, zf},
                         {zf, zf, zf, zf}, {zf, zf, zf, zf}};

    for (int k0 = 0; k0 < K; k0 += GBK) {
        __syncthreads();
#pragma unroll
        for (int j = 0; j < 4; ++j) {
            const int ch = w * 4 + j;
            const int r = ch * 8 + rL;
            GLD16(&A[(size_t)(row0 + r) * K + k0 + c8g * 8], &As[ch * 512]);
            GLD16(&W[(size_t)(col0 + r) * K + k0 + c8g * 8], &Ws[ch * 512]);
        }
        __syncthreads();

#pragma unroll
        for (int kk = 0; kk < 2; ++kk) {
            const int swz = swzk[kk];
            short8 af[4], bf[4];
#pragma unroll
            for (int mi = 0; mi < 4; ++mi)
                af[mi] = *(const short8*)&As[(wm + mi * 16 + l16) * GBK + swz];
#pragma unroll
            for (int ni = 0; ni < 4; ++ni)
                bf[ni] = *(const short8*)&Ws[(wn + ni * 16 + l16) * GBK + swz];
#pragma unroll
            for (int mi = 0; mi < 4; ++mi)
#pragma unroll
                for (int ni = 0; ni < 4; ++ni)
                    acc[mi][ni] = __builtin_amdgcn_mfma_f32_16x16x32_bf16(af[mi], bf[ni], acc[mi][ni], 0, 0, 0);
        }
    }

#pragma unroll
    for (int mi = 0; mi < 4; ++mi)
#pragma unroll
        for (int ni = 0; ni < 4; ++ni)
#pragma unroll
            for (int r = 0; r < 4; ++r) {
                size_t idx = (size_t)(row0 + wm + mi * 16 + quad * 4 + r) * N + col0 + wn + ni * 16 + l16;
                if constexpr (sizeof(OT) == 2) C[idx] = f2bf(acc[mi][ni][r]);
                else                           C[idx] = acc[mi][ni][r];
            }
}

// ---------------------------------------------------------------------------
// gemm_kv: same body as gemm_t but the epilogue routes each 128-wide column
// tile to its destination: tile (h, half). half==0 (K-nope) -> Kbf
// (B,H,S,192) cols 0..127 directly (pack_k fused away). half==1 (V) -> kvbb
// as before (pack_vt reads only the V halves).
// ---------------------------------------------------------------------------
__global__ __launch_bounds__(256) void gemm_kv(const unsigned short* __restrict__ A,
                                               const unsigned short* __restrict__ W,
                                               unsigned short* __restrict__ kvbb,
                                               unsigned short* __restrict__ Kbf,
                                               int M, int N, int K) {
    __shared__ unsigned short As[GBM * GBK];
    __shared__ unsigned short Ws[GBN * GBK];

    const int tid = threadIdx.x;
    const int w = tid >> 6, lane = tid & 63;
    const int l16 = lane & 15, quad = lane >> 4;
    const int wm = (w >> 1) * 64, wn = (w & 1) * 64;
    const int row0 = blockIdx.y * GBM, col0 = blockIdx.x * GBN;
    const int h = blockIdx.x >> 1, vhalf = blockIdx.x & 1;

    const int rL  = lane >> 3;
    const int c8g = (lane & 7) ^ rL;
    const int swzk[2] = { (((0 * 4) + quad) ^ (l16 & 7)) * 8,
                          (((1 * 4) + quad) ^ (l16 & 7)) * 8 };

    const float4v zf = {0.f, 0.f, 0.f, 0.f};
    float4v acc[4][4] = {{zf, zf, zf, zf}, {zf, zf, zf, zf},
                         {zf, zf, zf, zf}, {zf, zf, zf, zf}};

    for (int k0 = 0; k0 < K; k0 += GBK) {
        __syncthreads();
#pragma unroll
        for (int j = 0; j < 4; ++j) {
            const int ch = w * 4 + j;
            const int r = ch * 8 + rL;
            GLD16(&A[(size_t)(row0 + r) * K + k0 + c8g * 8], &As[ch * 512]);
            GLD16(&W[(size_t)(col0 + r) * K + k0 + c8g * 8], &Ws[ch * 512]);
        }
        __syncthreads();

#pragma unroll
        for (int kk = 0; kk < 2; ++kk) {
            const int swz = swzk[kk];
            short8 af[4], bf[4];
#pragma unroll
            for (int mi = 0; mi < 4; ++mi)
                af[mi] = *(const short8*)&As[(wm + mi * 16 + l16) * GBK + swz];
#pragma unroll
            for (int ni = 0; ni < 4; ++ni)
                bf[ni] = *(const short8*)&Ws[(wn + ni * 16 + l16) * GBK + swz];
#pragma unroll
            for (int mi = 0; mi < 4; ++mi)
#pragma unroll
                for (int ni = 0; ni < 4; ++ni)
                    acc[mi][ni] = __builtin_amdgcn_mfma_f32_16x16x32_bf16(af[mi], bf[ni], acc[mi][ni], 0, 0, 0);
        }
    }

#pragma unroll
    for (int mi = 0; mi < 4; ++mi)
#pragma unroll
        for (int ni = 0; ni < 4; ++ni)
#pragma unroll
            for (int r = 0; r < 4; ++r) {
                const int row = row0 + wm + mi * 16 + quad * 4 + r;      // 0..M-1
                const int d = wn + ni * 16 + l16;                        // 0..127
                const unsigned short v = f2bf(acc[mi][ni][r]);
                if (vhalf) {
                    kvbb[(size_t)row * N + col0 + d] = v;
                } else {
                    const int b = row >> 11, s = row & (S_ - 1);
                    Kbf[((size_t)(b * H_ + h) * S_ + s) * DQK + d] = v;
                }
            }
}

// ---------------------------------------------------------------------------
__global__ __launch_bounds__(256) void rmsnorm_b(const float* __restrict__ X,
                                                 const float* __restrict__ w,
                                                 unsigned short* __restrict__ Y,
                                                 int n, int ld) {
    __shared__ float tmp[4];
    const int row = blockIdx.x;
    const int tid = threadIdx.x;
    const float* x = X + (size_t)row * ld;

    float ss = 0.f;
    for (int c = tid; c < n; c += 256) {
        float v = x[c];
        ss = fmaf(v, v, ss);
    }
#pragma unroll
    for (int off = 32; off; off >>= 1) ss += __shfl_xor(ss, off, 64);
    if ((tid & 63) == 0) tmp[tid >> 6] = ss;
    __syncthreads();
    ss = tmp[0] + tmp[1] + tmp[2] + tmp[3];
    float r = rsqrtf(ss / (float)n + EPSF);

    for (int c = tid; c < n; c += 256)
        Y[(size_t)row * n + c] = f2bf(x[c] * r * w[c]);
}

// ---------------------------------------------------------------------------
// kv_post: RMS-norm of kv_c -> kvcb (bf16) AND k_pe RoPE written as bf16
// DIRECTLY into Kbf cols 128..191, broadcast to all 16 heads (kpe buffer
// and pack_k both eliminated). Must run after the q-GEMM (Kbf aliases R3).
// ---------------------------------------------------------------------------
__global__ __launch_bounds__(256) void kv_post(const float* __restrict__ KV,
                                               const float* __restrict__ w,
                                               const float* __restrict__ fc,
                                               unsigned short* __restrict__ kvcb,
                                               unsigned short* __restrict__ Kbf,
                                               int ldkv) {
    __shared__ float tmp[4];
    const int row = blockIdx.x;
    const int s = row & (S_ - 1);
    const int b = row >> 11;
    const int tid = threadIdx.x;
    const float* kv = KV + (size_t)row * ldkv;

    float ss = 0.f;
#pragma unroll
    for (int c = tid; c < KVLORA; c += 256) {
        float v = kv[c];
        ss = fmaf(v, v, ss);
    }
#pragma unroll
    for (int off = 32; off; off >>= 1) ss += __shfl_xor(ss, off, 64);
    if ((tid & 63) == 0) tmp[tid >> 6] = ss;
    __syncthreads();
    ss = tmp[0] + tmp[1] + tmp[2] + tmp[3];
    float r = rsqrtf(ss / (float)KVLORA + EPSF);

#pragma unroll
    for (int c = tid; c < KVLORA; c += 256)
        kvcb[(size_t)row * KVLORA + c] = f2bf(kv[c] * r * w[c]);

    if (tid < 32) {
        int i = tid;
        float c0 = fc[(s * 32 + i) * 2 + 0];
        float s0 = fc[(s * 32 + i) * 2 + 1];
        float x0 = kv[KVLORA + 2 * i];
        float x1 = kv[KVLORA + 2 * i + 1];
        unsigned short b0 = f2bf(x0 * c0 - x1 * s0);
        unsigned short b1 = f2bf(x0 * s0 + x1 * c0);
#pragma unroll
        for (int h = 0; h < H_; ++h) {
            unsigned short* kp = Kbf + ((size_t)(b * H_ + h) * S_ + s) * DQK + DN;
            kp[2 * i]     = b0;
            kp[2 * i + 1] = b1;
        }
    }
}

// ---------------------------------------------------------------------------
// pack_vt: Vt (B,H,128,S) bf16 from kvbb (M,H*256) bf16 cols h*256+128..+256
// ---------------------------------------------------------------------------
__global__ __launch_bounds__(256) void pack_vt(const unsigned short* __restrict__ kvbb,
                                               unsigned short* __restrict__ Vt) {
    __shared__ unsigned short T[DV][72];
    const int st = blockIdx.x;            // seq tile (64)
    const int bh = blockIdx.y;            // b*H+h
    const int b = bh >> 4, h = bh & 15;
    const int s0 = st * 64;
    const int tid = threadIdx.x;

    for (int c = tid; c < 64 * 16; c += 256) {
        int sp = c >> 4, ch = c & 15;
        short8 v = *(const short8*)&kvbb[(size_t)(b * S_ + s0 + sp) * (H_ * 256) + h * 256 + DN + ch * 8];
        union { short8 v; unsigned short u[8]; } t; t.v = v;
        int dv = ch * 8;
#pragma unroll
        for (int e = 0; e < 8; ++e) T[dv + e][sp] = t.u[e];
    }
    __syncthreads();
    for (int c = tid; c < 128 * 8; c += 256) {
        int dv = c >> 3, ch = c & 7;
        *(short8*)&Vt[((size_t)bh * DV + dv) * S_ + s0 + ch * 8] = *(short8*)&T[dv][ch * 8];
    }
}

// ---------------------------------------------------------------------------
// MFMA flash attention (causal), bf16 in (q with fused RoPE), fp32 acc.
// v3 structure (measured 84.4 µs, bank conflicts = 0) + T5 setprio around
// the MFMA clusters:
//  - 512 threads, 8 waves x 16 q-rows over a 128-row q-tile.
//  - global_load_lds(16B) XOR-swizzled staging, double-buffered K/V,
//    counted vmcnt(5), wave-private Ps (stride 76), no mid barrier.
// ---------------------------------------------------------------------------
#define QTILES 16   // 2048 / 128
#define PROW 76

__global__ __launch_bounds__(512, 1) void flash_mfma(const unsigned short* __restrict__ Qb,
                                                     const float* __restrict__ fc,
                                                     const unsigned short* __restrict__ Kbf,
                                                     const unsigned short* __restrict__ Vt,
                                                     unsigned short* __restrict__ Ob) {
    __shared__ unsigned short Ks[2][64 * 192];    // 2 x 24576 B, swizzled chunks
    __shared__ unsigned short Vs[2][128 * 64];    // 2 x 16384 B, swizzled chunks
    __shared__ unsigned short Ps[8][16][PROW];    // 19456 B, wave-private P

    const int bh = blockIdx.x;                  // b*H+h
    const int bx = blockIdx.y;                  // 0..7 pair index
    const int b = bh >> 4, h = bh & 15;
    const int tid = threadIdx.x;
    const int w = tid >> 6, lane = tid & 63;
    const int l16 = lane & 15, quad = lane >> 4;
    const int sw = l16 & 7;                     // read-side swizzle key

    const unsigned short* Kg = Kbf + (size_t)bh * S_ * DQK;
    const unsigned short* Vg = Vt + (size_t)bh * DV * S_;

    // stage K/V tile kt_ into buffer bufi: 5 global_load_lds per wave.
    auto stage = [&](int kt_, int bufi) {
        const int kb_ = kt_ * 64;
#pragma unroll
        for (int i_ = 0; i_ < 3; ++i_) {             // K: 64 rows x 24 chunks
            int ch = (w * 3 + i_) * 64 + lane;
            int r_ = ch / 24, c_ = ch - r_ * 24;
            GLD16(&Kg[(size_t)(kb_ + r_) * DQK + ((c_ ^ (r_ & 7)) << 3)],
                  &Ks[bufi][(w * 3 + i_) * 512]);
        }
#pragma unroll
        for (int i_ = 0; i_ < 2; ++i_) {             // V: 128 rows x 8 chunks
            int ch = (w * 2 + i_) * 64 + lane;
            int r_ = ch >> 3, c_ = ch & 7;
            GLD16(&Vg[(size_t)r_ * S_ + kb_ + ((c_ ^ (r_ & 7)) << 3)],
                  &Vs[bufi][(w * 2 + i_) * 512]);
        }
    };

    for (int half = 0; half < 2; ++half) {
        const int qt = half ? (QTILES - 1 - bx) : bx;
        const int q0 = qt * 128;
        const int ntiles = 2 * qt + 2;          // always even -> buf parity ok
        const int wr0 = q0 + w * 16;            // wave's first q row

        stage(0, 0);                            // tile 0 DMA in flight

        // Q A-frags (16 rows/wave), RoPE fused for d >= 128
        short8 a_q[6];
        {
            const int s = wr0 + l16;
            const unsigned short* qrow = Qb + (size_t)(b * S_ + s) * (H_ * DQK) + h * DQK;
#pragma unroll
            for (int i = 0; i < 6; ++i) {
                short8 t = *(const short8*)&qrow[i * 32 + quad * 8];
                if (i >= 4) {
                    union { short8 v; unsigned short u[8]; } x; x.v = t;
#pragma unroll
                    for (int j = 0; j < 4; ++j) {
                        int ip = (i - 4) * 16 + quad * 4 + j;
                        float c0 = fc[(s * 32 + ip) * 2 + 0];
                        float s0 = fc[(s * 32 + ip) * 2 + 1];
                        float x0 = bf2f(x.u[2 * j]);
                        float x1 = bf2f(x.u[2 * j + 1]);
                        x.u[2 * j]     = f2bf(x0 * c0 - x1 * s0);
                        x.u[2 * j + 1] = f2bf(x0 * s0 + x1 * c0);
                    }
                    t = x.v;
                }
                a_q[i] = t;
            }
        }

        const float4v zf = {0.f, 0.f, 0.f, 0.f};
        float4v o_acc[8] = {zf, zf, zf, zf, zf, zf, zf, zf};
        float l_r[4] = {0.f, 0.f, 0.f, 0.f};

        int buf = 0;
        for (int kt = 0; kt < ntiles; ++kt) {
            const int kb = kt * 64;

            // barrier 1: everyone done computing kt-1 -> buf^1 overwritable
            __builtin_amdgcn_s_barrier();
            if (kt + 1 < ntiles) {
                stage(kt + 1, buf ^ 1);
                asm volatile("s_waitcnt vmcnt(5)" ::: "memory");   // own kt loads done
            } else {
                asm volatile("s_waitcnt vmcnt(0)" ::: "memory");
            }
            __builtin_amdgcn_sched_barrier(0);
            // barrier 2: everyone's kt loads landed
            __builtin_amdgcn_s_barrier();
            __builtin_amdgcn_sched_barrier(0);

            if (kb <= wr0 + 15) {               // wave not fully causal-masked
                const unsigned short* Kb_ = Ks[buf];
                const unsigned short* Vb_ = Vs[buf];

                // QK^T: 24 ds_read_b128 -> 24 mfma (4 independent acc chains)
                float4v sc[4] = {zf, zf, zf, zf};
                __builtin_amdgcn_s_setprio(1);
#pragma unroll
                for (int i = 0; i < 6; ++i) {
                    short8 bk[4];
#pragma unroll
                    for (int kg = 0; kg < 4; ++kg)
                        bk[kg] = *(const short8*)&Kb_[(kg * 16 + l16) * 192 + (((i * 4 + quad) ^ sw) << 3)];
#pragma unroll
                    for (int kg = 0; kg < 4; ++kg)
                        sc[kg] = __builtin_amdgcn_mfma_f32_16x16x32_bf16(a_q[i], bk[kg], sc[kg], 0, 0, 0);
                }
                __builtin_amdgcn_s_setprio(0);

                // max-free softmax (mask post-exp; wave-uniform mneed branch)
                const bool mneed = (kb + 63 > wr0);
#pragma unroll
                for (int kg = 0; kg < 4; ++kg) {
                    const int key = kb + kg * 16 + l16;
#pragma unroll
                    for (int r = 0; r < 4; ++r) {
                        float p = __expf(sc[kg][r] * SCALEF);
                        if (mneed && key > wr0 + quad * 4 + r) p = 0.f;
                        l_r[r] += p;
                        Ps[w][quad * 4 + r][kg * 16 + l16] = f2bf(p);
                    }
                }

                // PV: Ps is wave-private -> no barrier needed before reads
                __builtin_amdgcn_s_setprio(1);
#pragma unroll
                for (int kc = 0; kc < 2; ++kc) {
                    short8 pa = *(const short8*)&Ps[w][l16][kc * 32 + quad * 8];
#pragma unroll
                    for (int dvt = 0; dvt < 8; ++dvt) {
                        short8 vb = *(const short8*)&Vb_[(dvt * 16 + l16) * 64 + (((kc * 4 + quad) ^ sw) << 3)];
                        o_acc[dvt] = __builtin_amdgcn_mfma_f32_16x16x32_bf16(pa, vb, o_acc[dvt], 0, 0, 0);
                    }
                }
                __builtin_amdgcn_s_setprio(0);
            }
            buf ^= 1;
        }

        // epilogue: reduce l over the 16 key-lanes, write O
#pragma unroll
        for (int r = 0; r < 4; ++r) {
            float t = l_r[r];
            t += __shfl_xor(t, 1);
            t += __shfl_xor(t, 2);
            t += __shfl_xor(t, 4);
            t += __shfl_xor(t, 8);
            l_r[r] = t;
        }
#pragma unroll
        for (int r = 0; r < 4; ++r) {
            float inv = 1.f / l_r[r];
            int row = wr0 + quad * 4 + r;
            unsigned short* op = Ob + (size_t)(b * S_ + row) * (H_ * DV) + h * DV;
#pragma unroll
            for (int dvt = 0; dvt < 8; ++dvt)
                op[dvt * 16 + l16] = f2bf(o_acc[dvt][r] * inv);
        }
    }
}

// ---------------------------------------------------------------------------
extern "C" void kernel_launch(void* const* d_in, const int* in_sizes, int n_in,
                              void* d_out, int out_size, void* d_ws, size_t ws_size,
                              hipStream_t stream) {
    const float* x    = (const float*)d_in[0];
    const float* fc   = (const float*)d_in[1];
    const float* Wqa  = (const float*)d_in[2];
    const float* qlw  = (const float*)d_in[3];
    const float* Wqb  = (const float*)d_in[4];
    const float* Wkva = (const float*)d_in[5];
    const float* kvw  = (const float*)d_in[6];
    const float* Wkvb = (const float*)d_in[7];
    const float* Wo   = (const float*)d_in[8];
    float* out = (float*)d_out;

    const int M = B_ * S_;                 // 4096
    const int NQKV = QLORA + 640;          // 2176
    char* wsb = (char*)d_ws;

    // R1 (50331648 B): qb bf16 (25165824) + Wob (8388608)
    unsigned short* qb  = (unsigned short*)wsb;
    unsigned short* Wob = (unsigned short*)(wsb + 25165824);
    // R2 (67108864 B)
    char* R2 = wsb + 50331648;
    float*          qlkv  = (float*)R2;                          // 35651584
    unsigned short* xb    = (unsigned short*)(R2 + 35651584);    // 16777216
    unsigned short* Wcat  = (unsigned short*)(R2 + 52428800);    //  8912896
    unsigned short* kvbb  = (unsigned short*)R2;                 // 33554432 (after qlkv dead)
    unsigned short* attnb = (unsigned short*)R2;                 // 16777216 (after pack_vt)
    // R3 (25165824 B)
    char* R3 = R2 + 67108864;
    unsigned short* qlatb = (unsigned short*)R3;                 // 12582912
    unsigned short* Wqbb  = (unsigned short*)(R3 + 12582912);    //  9437184
    unsigned short* Kbf   = (unsigned short*)R3;                 // 25165824 (after q-gemm)
    // R4 (16777216 B)
    char* R4 = R3 + 25165824;
    unsigned short* kvcb  = (unsigned short*)(R4 + 1048576);     //  4194304
    unsigned short* Wkvbb = (unsigned short*)(R4 + 5242880);     //  4194304
    unsigned short* Vt    = (unsigned short*)R4;                 // 16777216 (after gemm_kv)

    // 0) single mega-conversion: x, Wqa, Wkva, Wqb, Wkvb, Wo
    {
        const long e0 = 1048576;           // x      (M*D/8)
        const long e1 = e0 + 393216;       // Wqa    (1536*2048/8)
        const long e2 = e1 + 147456;       // Wkva   (576*2048/8)
        const long e3 = e2 + 589824;       // Wqb    (3072*1536/8)
        const long e4 = e3 + 262144;       // Wkvb   (4096*512/8)
        const long tot = e4 + 524288;      // Wo     (2048*2048/8) -> 2965504
        conv_all<<<(int)(tot / 256), 256, 0, stream>>>(
            x, xb, e0,
            Wqa, Wcat, e1,
            Wkva, Wcat + (size_t)QLORA * D_, e2,
            Wqb, Wqbb, e3,
            Wkvb, Wkvbb, e4,
            Wo, Wob);
    }

    // 1) merged: qlkv = xb @ Wcat^T (cols 0..1535 = qlat, 1536..2111 = kvraw)
    gemm_t<float><<<dim3(NQKV / GBN, M / GBM), 256, 0, stream>>>(xb, Wcat, qlkv, M, NQKV, D_);

    // 2) q-latent norm -> bf16
    rmsnorm_b<<<M, 256, 0, stream>>>(qlkv, qlw, qlatb, QLORA, NQKV);

    // 3) qb = qlatb @ Wqbb^T (must precede any Kbf write: Kbf aliases R3)
    gemm_t<unsigned short><<<dim3(H_ * DQK / GBN, M / GBM), 256, 0, stream>>>(qlatb, Wqbb, qb, M, H_ * DQK, QLORA);

    // 4) kv norm -> kvcb; RoPE k_pe -> Kbf cols 128..191 (broadcast 16 heads)
    kv_post<<<M, 256, 0, stream>>>(qlkv + QLORA, kvw, fc, kvcb, Kbf, NQKV);

    // 5) kv up-proj: K-nope tiles -> Kbf cols 0..127 direct; V tiles -> kvbb
    gemm_kv<<<dim3(H_ * 256 / GBN, M / GBM), 256, 0, stream>>>(kvcb, Wkvbb, kvbb, Kbf, M, H_ * 256, KVLORA);

    // 6) V transpose (reads kvbb V-halves; writes Vt over kvcb/Wkvbb - done)
    pack_vt<<<dim3(S_ / 64, B_ * H_), 256, 0, stream>>>(kvbb, Vt);

    // 7) flash attention: 128-row q-tiles, 8 waves x 16 q-rows, pairs (bx,15-bx)
    flash_mfma<<<dim3(B_ * H_, QTILES / 2), 512, 0, stream>>>(qb, fc, Kbf, Vt, attnb);

    // 8) out = attnb @ Wob^T
    gemm_t<float><<<dim3(D_ / GBN, M / GBM), 256, 0, stream>>>(attnb, Wob, out, M, D_, D_);
}

// Round 5
// 447.419 us; speedup vs baseline: 1.0641x; 1.0434x over previous
//
#include <hip/hip_runtime.h>
#include <math.h>

#define B_ 2
#define S_ 2048
#define D_ 2048
#define H_ 16
#define QLORA 1536
#define KVLORA 512
#define DN 128
#define DR 64
#define DQK 192
#define DV 128
#define EPSF 1e-6f
#define SCALEF 0.07216878364870322f   // 192^-0.5

typedef short short8 __attribute__((ext_vector_type(8)));
typedef float float4v __attribute__((ext_vector_type(4)));

__device__ __forceinline__ unsigned short f2bf(float f) {
    union { float f; unsigned u; } x; x.f = f;
    unsigned r = x.u + 0x7fffu + ((x.u >> 16) & 1u);   // RNE
    return (unsigned short)(r >> 16);
}
__device__ __forceinline__ float bf2f(unsigned short u) {
    union { unsigned u; float f; } x; x.u = (unsigned)u << 16;
    return x.f;
}

// async global->LDS, 16B per lane; LDS dest = wave-uniform base + lane*16
#define GLD16(src, dst)                                                        \
    __builtin_amdgcn_global_load_lds(                                          \
        (const __attribute__((address_space(1))) void*)(src),                  \
        (__attribute__((address_space(3))) void*)(dst), 16, 0, 0)

// ---------------------------------------------------------------------------
// all fp32->bf16 conversions in ONE launch (6 ranges, if-chain)
// ---------------------------------------------------------------------------
__global__ __launch_bounds__(256) void conv_all(
        const float* __restrict__ s0, unsigned short* __restrict__ d0, long e0,
        const float* __restrict__ s1, unsigned short* __restrict__ d1, long e1,
        const float* __restrict__ s2, unsigned short* __restrict__ d2, long e2,
        const float* __restrict__ s3, unsigned short* __restrict__ d3, long e3,
        const float* __restrict__ s4, unsigned short* __restrict__ d4, long e4,
        const float* __restrict__ s5, unsigned short* __restrict__ d5) {
    long c = (long)blockIdx.x * 256 + threadIdx.x;   // 8-elem chunk index
    const float* src;
    unsigned short* dst;
    if      (c < e0) { src = s0; dst = d0; }
    else if (c < e1) { src = s1; dst = d1; c -= e0; }
    else if (c < e2) { src = s2; dst = d2; c -= e1; }
    else if (c < e3) { src = s3; dst = d3; c -= e2; }
    else if (c < e4) { src = s4; dst = d4; c -= e3; }
    else             { src = s5; dst = d5; c -= e4; }
    const float* p = src + c * 8;
    float4 a = *(const float4*)(p);
    float4 b = *(const float4*)(p + 4);
    union { short8 v; unsigned short u[8]; } t;
    t.u[0] = f2bf(a.x); t.u[1] = f2bf(a.y); t.u[2] = f2bf(a.z); t.u[3] = f2bf(a.w);
    t.u[4] = f2bf(b.x); t.u[5] = f2bf(b.y); t.u[6] = f2bf(b.z); t.u[7] = f2bf(b.w);
    *(short8*)&dst[c * 8] = t.v;
}

// ---------------------------------------------------------------------------
// bf16 MFMA GEMM (m97-class 128x128, 2-barrier):  C = A[M,K] @ W[N,K]^T.
// Kept for the N=2176 qlkv GEMM only.
// ---------------------------------------------------------------------------
#define GBM 128
#define GBN 128
#define GBK 64

template <typename OT>
__global__ __launch_bounds__(256) void gemm_t(const unsigned short* __restrict__ A,
                                              const unsigned short* __restrict__ W,
                                              OT* __restrict__ C,
                                              int M, int N, int K) {
    __shared__ unsigned short As[GBM * GBK];   // 16384 B
    __shared__ unsigned short Ws[GBN * GBK];   // 16384 B

    const int tid = threadIdx.x;
    const int w = tid >> 6, lane = tid & 63;
    const int l16 = lane & 15, quad = lane >> 4;
    const int wm = (w >> 1) * 64, wn = (w & 1) * 64;
    const int row0 = blockIdx.y * GBM, col0 = blockIdx.x * GBN;

    const int rL  = lane >> 3;
    const int c8g = (lane & 7) ^ rL;
    const int swzk[2] = { (((0 * 4) + quad) ^ (l16 & 7)) * 8,
                          (((1 * 4) + quad) ^ (l16 & 7)) * 8 };

    const float4v zf = {0.f, 0.f, 0.f, 0.f};
    float4v acc[4][4] = {{zf, zf, zf, zf}, {zf, zf, zf, zf},
                         {zf, zf, zf, zf}, {zf, zf, zf, zf}};

    for (int k0 = 0; k0 < K; k0 += GBK) {
        __syncthreads();
#pragma unroll
        for (int j = 0; j < 4; ++j) {
            const int ch = w * 4 + j;
            const int r = ch * 8 + rL;
            GLD16(&A[(size_t)(row0 + r) * K + k0 + c8g * 8], &As[ch * 512]);
            GLD16(&W[(size_t)(col0 + r) * K + k0 + c8g * 8], &Ws[ch * 512]);
        }
        __syncthreads();

#pragma unroll
        for (int kk = 0; kk < 2; ++kk) {
            const int swz = swzk[kk];
            short8 af[4], bf[4];
#pragma unroll
            for (int mi = 0; mi < 4; ++mi)
                af[mi] = *(const short8*)&As[(wm + mi * 16 + l16) * GBK + swz];
#pragma unroll
            for (int ni = 0; ni < 4; ++ni)
                bf[ni] = *(const short8*)&Ws[(wn + ni * 16 + l16) * GBK + swz];
#pragma unroll
            for (int mi = 0; mi < 4; ++mi)
#pragma unroll
                for (int ni = 0; ni < 4; ++ni)
                    acc[mi][ni] = __builtin_amdgcn_mfma_f32_16x16x32_bf16(af[mi], bf[ni], acc[mi][ni], 0, 0, 0);
        }
    }

#pragma unroll
    for (int mi = 0; mi < 4; ++mi)
#pragma unroll
        for (int ni = 0; ni < 4; ++ni)
#pragma unroll
            for (int r = 0; r < 4; ++r) {
                size_t idx = (size_t)(row0 + wm + mi * 16 + quad * 4 + r) * N + col0 + wn + ni * 16 + l16;
                if constexpr (sizeof(OT) == 2) C[idx] = f2bf(acc[mi][ni][r]);
                else                           C[idx] = acc[mi][ni][r];
            }
}

// ---------------------------------------------------------------------------
// gemm8: 256x256 deep-pipeline bf16 GEMM (T3+T4): 512 threads = 8 waves
// (2M x 4N), per-wave 128x64 output, BK=64, double-buffered 128KB LDS,
// counted vmcnt(8) -- next-next tile's 8 DMA loads stay in flight across
// the barrier pair (never drained to 0 mid-loop). Swizzle + frag indexing
// identical to the verified gemm_t pattern (conflicts measured 0).
// MODE 0: fp32 C.  MODE 1: bf16 C.  MODE 2: kv routing (Cs=Kbf, Cp=kvbb).
// ---------------------------------------------------------------------------
#define TBM 256
#define TBN 256
#define TBK 64

template <int MODE>
__global__ __launch_bounds__(512, 2) void gemm8(const unsigned short* __restrict__ A,
                                                const unsigned short* __restrict__ W,
                                                void* __restrict__ Cp,
                                                unsigned short* __restrict__ Cs,
                                                int M, int N, int K) {
    __shared__ unsigned short As[2][TBM * TBK];   // 2 x 32768 B
    __shared__ unsigned short Ws[2][TBN * TBK];   // 2 x 32768 B

    const int tid = threadIdx.x;
    const int w = tid >> 6, lane = tid & 63;
    const int l16 = lane & 15, quad = lane >> 4;
    const int wm = (w >> 2) * 128, wn = (w & 3) * 64;
    const int row0 = blockIdx.y * TBM, col0 = blockIdx.x * TBN;
    const int NT = K / TBK;

    // staging: 2048 16B-chunks per operand per K-tile; 4 chunks/thread each.
    // chunk ch stored linearly at ch*16B; source column pre-swizzled c^(r&7).
    auto stage = [&](int t_, int bufi) {
        const int k0 = t_ * TBK;
#pragma unroll
        for (int i_ = 0; i_ < 4; ++i_) {
            const int ch = i_ * 512 + w * 64 + lane;
            const int r_ = ch >> 3, c_ = ch & 7;
            GLD16(&A[(size_t)(row0 + r_) * K + k0 + ((c_ ^ (r_ & 7)) << 3)],
                  &As[bufi][(i_ * 512 + w * 64) * 8]);
        }
#pragma unroll
        for (int i_ = 0; i_ < 4; ++i_) {
            const int ch = i_ * 512 + w * 64 + lane;
            const int r_ = ch >> 3, c_ = ch & 7;
            GLD16(&W[(size_t)(col0 + r_) * K + k0 + ((c_ ^ (r_ & 7)) << 3)],
                  &Ws[bufi][(i_ * 512 + w * 64) * 8]);
        }
    };

    const float4v zf = {0.f, 0.f, 0.f, 0.f};
    float4v acc[8][4];
#pragma unroll
    for (int mi = 0; mi < 8; ++mi)
#pragma unroll
        for (int ni = 0; ni < 4; ++ni) acc[mi][ni] = zf;

    stage(0, 0);
    stage(1, 1);
    asm volatile("s_waitcnt vmcnt(8)" ::: "memory");   // tile 0 landed
    __builtin_amdgcn_sched_barrier(0);
    __builtin_amdgcn_s_barrier();
    __builtin_amdgcn_sched_barrier(0);

    for (int t = 0; t < NT; ++t) {
        const int buf = t & 1;
        const unsigned short* Ab = As[buf];
        const unsigned short* Wb = Ws[buf];

        // B-frags once per tile (8 ds_read_b128), reused across 8 M-frags
        short8 bfr[2][4];
#pragma unroll
        for (int kk = 0; kk < 2; ++kk)
#pragma unroll
            for (int ni = 0; ni < 4; ++ni) {
                const int Rn = wn + ni * 16 + l16;
                bfr[kk][ni] = *(const short8*)&Wb[Rn * TBK + (((kk * 4 + quad) ^ (l16 & 7)) << 3)];
            }
#pragma unroll
        for (int mi = 0; mi < 8; ++mi) {
            const int Rm = wm + mi * 16 + l16;
            short8 a0 = *(const short8*)&Ab[Rm * TBK + (((0 + quad) ^ (l16 & 7)) << 3)];
            short8 a1 = *(const short8*)&Ab[Rm * TBK + (((4 + quad) ^ (l16 & 7)) << 3)];
#pragma unroll
            for (int ni = 0; ni < 4; ++ni) {
                acc[mi][ni] = __builtin_amdgcn_mfma_f32_16x16x32_bf16(a0, bfr[0][ni], acc[mi][ni], 0, 0, 0);
                acc[mi][ni] = __builtin_amdgcn_mfma_f32_16x16x32_bf16(a1, bfr[1][ni], acc[mi][ni], 0, 0, 0);
            }
        }

        // barrier 1: all waves done reading buf -> overwritable
        __builtin_amdgcn_s_barrier();
        if (t + 2 < NT) {
            stage(t + 2, buf);
            asm volatile("s_waitcnt vmcnt(8)" ::: "memory");   // tile t+1 landed
        } else if (t + 1 < NT) {
            asm volatile("s_waitcnt vmcnt(0)" ::: "memory");
        }
        __builtin_amdgcn_sched_barrier(0);
        // barrier 2: everyone's tile t+1 data in LDS
        __builtin_amdgcn_s_barrier();
        __builtin_amdgcn_sched_barrier(0);
    }

#pragma unroll
    for (int mi = 0; mi < 8; ++mi)
#pragma unroll
        for (int ni = 0; ni < 4; ++ni)
#pragma unroll
            for (int r = 0; r < 4; ++r) {
                const int row = row0 + wm + mi * 16 + quad * 4 + r;
                const int col = col0 + wn + ni * 16 + l16;
                if constexpr (MODE == 0) {
                    ((float*)Cp)[(size_t)row * N + col] = acc[mi][ni][r];
                } else if constexpr (MODE == 1) {
                    ((unsigned short*)Cp)[(size_t)row * N + col] = f2bf(acc[mi][ni][r]);
                } else {
                    const int h = col >> 8, within = col & 255;
                    const unsigned short v = f2bf(acc[mi][ni][r]);
                    if (within < 128) {
                        const int b = row >> 11, s = row & (S_ - 1);
                        Cs[((size_t)(b * H_ + h) * S_ + s) * DQK + within] = v;
                    } else {
                        ((unsigned short*)Cp)[(size_t)row * N + col] = v;
                    }
                }
            }
}

// ---------------------------------------------------------------------------
__global__ __launch_bounds__(256) void rmsnorm_b(const float* __restrict__ X,
                                                 const float* __restrict__ w,
                                                 unsigned short* __restrict__ Y,
                                                 int n, int ld) {
    __shared__ float tmp[4];
    const int row = blockIdx.x;
    const int tid = threadIdx.x;
    const float* x = X + (size_t)row * ld;

    float ss = 0.f;
    for (int c = tid; c < n; c += 256) {
        float v = x[c];
        ss = fmaf(v, v, ss);
    }
#pragma unroll
    for (int off = 32; off; off >>= 1) ss += __shfl_xor(ss, off, 64);
    if ((tid & 63) == 0) tmp[tid >> 6] = ss;
    __syncthreads();
    ss = tmp[0] + tmp[1] + tmp[2] + tmp[3];
    float r = rsqrtf(ss / (float)n + EPSF);

    for (int c = tid; c < n; c += 256)
        Y[(size_t)row * n + c] = f2bf(x[c] * r * w[c]);
}

// ---------------------------------------------------------------------------
// kv_post: RMS-norm of kv_c -> kvcb (bf16) AND k_pe RoPE written as bf16
// DIRECTLY into Kbf cols 128..191, broadcast to all 16 heads.
// Must run after the q-GEMM (Kbf aliases R3).
// ---------------------------------------------------------------------------
__global__ __launch_bounds__(256) void kv_post(const float* __restrict__ KV,
                                               const float* __restrict__ w,
                                               const float* __restrict__ fc,
                                               unsigned short* __restrict__ kvcb,
                                               unsigned short* __restrict__ Kbf,
                                               int ldkv) {
    __shared__ float tmp[4];
    const int row = blockIdx.x;
    const int s = row & (S_ - 1);
    const int b = row >> 11;
    const int tid = threadIdx.x;
    const float* kv = KV + (size_t)row * ldkv;

    float ss = 0.f;
#pragma unroll
    for (int c = tid; c < KVLORA; c += 256) {
        float v = kv[c];
        ss = fmaf(v, v, ss);
    }
#pragma unroll
    for (int off = 32; off; off >>= 1) ss += __shfl_xor(ss, off, 64);
    if ((tid & 63) == 0) tmp[tid >> 6] = ss;
    __syncthreads();
    ss = tmp[0] + tmp[1] + tmp[2] + tmp[3];
    float r = rsqrtf(ss / (float)KVLORA + EPSF);

#pragma unroll
    for (int c = tid; c < KVLORA; c += 256)
        kvcb[(size_t)row * KVLORA + c] = f2bf(kv[c] * r * w[c]);

    if (tid < 32) {
        int i = tid;
        float c0 = fc[(s * 32 + i) * 2 + 0];
        float s0 = fc[(s * 32 + i) * 2 + 1];
        float x0 = kv[KVLORA + 2 * i];
        float x1 = kv[KVLORA + 2 * i + 1];
        unsigned short b0 = f2bf(x0 * c0 - x1 * s0);
        unsigned short b1 = f2bf(x0 * s0 + x1 * c0);
#pragma unroll
        for (int h = 0; h < H_; ++h) {
            unsigned short* kp = Kbf + ((size_t)(b * H_ + h) * S_ + s) * DQK + DN;
            kp[2 * i]     = b0;
            kp[2 * i + 1] = b1;
        }
    }
}

// ---------------------------------------------------------------------------
// pack_vt: Vt (B,H,128,S) bf16 from kvbb (M,H*256) bf16 cols h*256+128..+256
// ---------------------------------------------------------------------------
__global__ __launch_bounds__(256) void pack_vt(const unsigned short* __restrict__ kvbb,
                                               unsigned short* __restrict__ Vt) {
    __shared__ unsigned short T[DV][72];
    const int st = blockIdx.x;            // seq tile (64)
    const int bh = blockIdx.y;            // b*H+h
    const int b = bh >> 4, h = bh & 15;
    const int s0 = st * 64;
    const int tid = threadIdx.x;

    for (int c = tid; c < 64 * 16; c += 256) {
        int sp = c >> 4, ch = c & 15;
        short8 v = *(const short8*)&kvbb[(size_t)(b * S_ + s0 + sp) * (H_ * 256) + h * 256 + DN + ch * 8];
        union { short8 v; unsigned short u[8]; } t; t.v = v;
        int dv = ch * 8;
#pragma unroll
        for (int e = 0; e < 8; ++e) T[dv + e][sp] = t.u[e];
    }
    __syncthreads();
    for (int c = tid; c < 128 * 8; c += 256) {
        int dv = c >> 3, ch = c & 7;
        *(short8*)&Vt[((size_t)bh * DV + dv) * S_ + s0 + ch * 8] = *(short8*)&T[dv][ch * 8];
    }
}

// ---------------------------------------------------------------------------
// MFMA flash attention (causal), bf16 in (q with fused RoPE), fp32 acc.
// Exact R2/v3 structure (measured 84.4 µs, bank conflicts = 0; setprio
// reverted -- it cost 10 µs on this lockstep schedule):
//  - 512 threads, 8 waves x 16 q-rows over a 128-row q-tile.
//  - global_load_lds(16B) XOR-swizzled staging, double-buffered K/V,
//    counted vmcnt(5), wave-private Ps (stride 76), no mid barrier.
// ---------------------------------------------------------------------------
#define QTILES 16   // 2048 / 128
#define PROW 76

__global__ __launch_bounds__(512, 1) void flash_mfma(const unsigned short* __restrict__ Qb,
                                                     const float* __restrict__ fc,
                                                     const unsigned short* __restrict__ Kbf,
                                                     const unsigned short* __restrict__ Vt,
                                                     unsigned short* __restrict__ Ob) {
    __shared__ unsigned short Ks[2][64 * 192];    // 2 x 24576 B, swizzled chunks
    __shared__ unsigned short Vs[2][128 * 64];    // 2 x 16384 B, swizzled chunks
    __shared__ unsigned short Ps[8][16][PROW];    // 19456 B, wave-private P

    const int bh = blockIdx.x;                  // b*H+h
    const int bx = blockIdx.y;                  // 0..7 pair index
    const int b = bh >> 4, h = bh & 15;
    const int tid = threadIdx.x;
    const int w = tid >> 6, lane = tid & 63;
    const int l16 = lane & 15, quad = lane >> 4;
    const int sw = l16 & 7;                     // read-side swizzle key

    const unsigned short* Kg = Kbf + (size_t)bh * S_ * DQK;
    const unsigned short* Vg = Vt + (size_t)bh * DV * S_;

    // stage K/V tile kt_ into buffer bufi: 5 global_load_lds per wave.
    auto stage = [&](int kt_, int bufi) {
        const int kb_ = kt_ * 64;
#pragma unroll
        for (int i_ = 0; i_ < 3; ++i_) {             // K: 64 rows x 24 chunks
            int ch = (w * 3 + i_) * 64 + lane;
            int r_ = ch / 24, c_ = ch - r_ * 24;
            GLD16(&Kg[(size_t)(kb_ + r_) * DQK + ((c_ ^ (r_ & 7)) << 3)],
                  &Ks[bufi][(w * 3 + i_) * 512]);
        }
#pragma unroll
        for (int i_ = 0; i_ < 2; ++i_) {             // V: 128 rows x 8 chunks
            int ch = (w * 2 + i_) * 64 + lane;
            int r_ = ch >> 3, c_ = ch & 7;
            GLD16(&Vg[(size_t)r_ * S_ + kb_ + ((c_ ^ (r_ & 7)) << 3)],
                  &Vs[bufi][(w * 2 + i_) * 512]);
        }
    };

    for (int half = 0; half < 2; ++half) {
        const int qt = half ? (QTILES - 1 - bx) : bx;
        const int q0 = qt * 128;
        const int ntiles = 2 * qt + 2;          // always even -> buf parity ok
        const int wr0 = q0 + w * 16;            // wave's first q row

        stage(0, 0);                            // tile 0 DMA in flight

        // Q A-frags (16 rows/wave), RoPE fused for d >= 128
        short8 a_q[6];
        {
            const int s = wr0 + l16;
            const unsigned short* qrow = Qb + (size_t)(b * S_ + s) * (H_ * DQK) + h * DQK;
#pragma unroll
            for (int i = 0; i < 6; ++i) {
                short8 t = *(const short8*)&qrow[i * 32 + quad * 8];
                if (i >= 4) {
                    union { short8 v; unsigned short u[8]; } x; x.v = t;
#pragma unroll
                    for (int j = 0; j < 4; ++j) {
                        int ip = (i - 4) * 16 + quad * 4 + j;
                        float c0 = fc[(s * 32 + ip) * 2 + 0];
                        float s0 = fc[(s * 32 + ip) * 2 + 1];
                        float x0 = bf2f(x.u[2 * j]);
                        float x1 = bf2f(x.u[2 * j + 1]);
                        x.u[2 * j]     = f2bf(x0 * c0 - x1 * s0);
                        x.u[2 * j + 1] = f2bf(x0 * s0 + x1 * c0);
                    }
                    t = x.v;
                }
                a_q[i] = t;
            }
        }

        const float4v zf = {0.f, 0.f, 0.f, 0.f};
        float4v o_acc[8] = {zf, zf, zf, zf, zf, zf, zf, zf};
        float l_r[4] = {0.f, 0.f, 0.f, 0.f};

        int buf = 0;
        for (int kt = 0; kt < ntiles; ++kt) {
            const int kb = kt * 64;

            // barrier 1: everyone done computing kt-1 -> buf^1 overwritable
            __builtin_amdgcn_s_barrier();
            if (kt + 1 < ntiles) {
                stage(kt + 1, buf ^ 1);
                asm volatile("s_waitcnt vmcnt(5)" ::: "memory");   // own kt loads done
            } else {
                asm volatile("s_waitcnt vmcnt(0)" ::: "memory");
            }
            __builtin_amdgcn_sched_barrier(0);
            // barrier 2: everyone's kt loads landed
            __builtin_amdgcn_s_barrier();
            __builtin_amdgcn_sched_barrier(0);

            if (kb <= wr0 + 15) {               // wave not fully causal-masked
                const unsigned short* Kb_ = Ks[buf];
                const unsigned short* Vb_ = Vs[buf];

                // QK^T: 24 ds_read_b128 -> 24 mfma (4 independent acc chains)
                float4v sc[4] = {zf, zf, zf, zf};
#pragma unroll
                for (int i = 0; i < 6; ++i) {
                    short8 bk[4];
#pragma unroll
                    for (int kg = 0; kg < 4; ++kg)
                        bk[kg] = *(const short8*)&Kb_[(kg * 16 + l16) * 192 + (((i * 4 + quad) ^ sw) << 3)];
#pragma unroll
                    for (int kg = 0; kg < 4; ++kg)
                        sc[kg] = __builtin_amdgcn_mfma_f32_16x16x32_bf16(a_q[i], bk[kg], sc[kg], 0, 0, 0);
                }

                // max-free softmax (mask post-exp; wave-uniform mneed branch)
                const bool mneed = (kb + 63 > wr0);
#pragma unroll
                for (int kg = 0; kg < 4; ++kg) {
                    const int key = kb + kg * 16 + l16;
#pragma unroll
                    for (int r = 0; r < 4; ++r) {
                        float p = __expf(sc[kg][r] * SCALEF);
                        if (mneed && key > wr0 + quad * 4 + r) p = 0.f;
                        l_r[r] += p;
                        Ps[w][quad * 4 + r][kg * 16 + l16] = f2bf(p);
                    }
                }

                // PV: Ps is wave-private -> no barrier needed before reads
#pragma unroll
                for (int kc = 0; kc < 2; ++kc) {
                    short8 pa = *(const short8*)&Ps[w][l16][kc * 32 + quad * 8];
#pragma unroll
                    for (int dvt = 0; dvt < 8; ++dvt) {
                        short8 vb = *(const short8*)&Vb_[(dvt * 16 + l16) * 64 + (((kc * 4 + quad) ^ sw) << 3)];
                        o_acc[dvt] = __builtin_amdgcn_mfma_f32_16x16x32_bf16(pa, vb, o_acc[dvt], 0, 0, 0);
                    }
                }
            }
            buf ^= 1;
        }

        // epilogue: reduce l over the 16 key-lanes, write O
#pragma unroll
        for (int r = 0; r < 4; ++r) {
            float t = l_r[r];
            t += __shfl_xor(t, 1);
            t += __shfl_xor(t, 2);
            t += __shfl_xor(t, 4);
            t += __shfl_xor(t, 8);
            l_r[r] = t;
        }
#pragma unroll
        for (int r = 0; r < 4; ++r) {
            float inv = 1.f / l_r[r];
            int row = wr0 + quad * 4 + r;
            unsigned short* op = Ob + (size_t)(b * S_ + row) * (H_ * DV) + h * DV;
#pragma unroll
            for (int dvt = 0; dvt < 8; ++dvt)
                op[dvt * 16 + l16] = f2bf(o_acc[dvt][r] * inv);
        }
    }
}

// ---------------------------------------------------------------------------
extern "C" void kernel_launch(void* const* d_in, const int* in_sizes, int n_in,
                              void* d_out, int out_size, void* d_ws, size_t ws_size,
                              hipStream_t stream) {
    const float* x    = (const float*)d_in[0];
    const float* fc   = (const float*)d_in[1];
    const float* Wqa  = (const float*)d_in[2];
    const float* qlw  = (const float*)d_in[3];
    const float* Wqb  = (const float*)d_in[4];
    const float* Wkva = (const float*)d_in[5];
    const float* kvw  = (const float*)d_in[6];
    const float* Wkvb = (const float*)d_in[7];
    const float* Wo   = (const float*)d_in[8];
    float* out = (float*)d_out;

    const int M = B_ * S_;                 // 4096
    const int NQKV = QLORA + 640;          // 2176
    char* wsb = (char*)d_ws;

    // R1 (50331648 B): qb bf16 (25165824) + Wob (8388608)
    unsigned short* qb  = (unsigned short*)wsb;
    unsigned short* Wob = (unsigned short*)(wsb + 25165824);
    // R2 (67108864 B)
    char* R2 = wsb + 50331648;
    float*          qlkv  = (float*)R2;                          // 35651584
    unsigned short* xb    = (unsigned short*)(R2 + 35651584);    // 16777216
    unsigned short* Wcat  = (unsigned short*)(R2 + 52428800);    //  8912896
    unsigned short* kvbb  = (unsigned short*)R2;                 // 33554432 (after qlkv dead)
    unsigned short* attnb = (unsigned short*)R2;                 // 16777216 (after pack_vt)
    // R3 (25165824 B)
    char* R3 = R2 + 67108864;
    unsigned short* qlatb = (unsigned short*)R3;                 // 12582912
    unsigned short* Wqbb  = (unsigned short*)(R3 + 12582912);    //  9437184
    unsigned short* Kbf   = (unsigned short*)R3;                 // 25165824 (after q-gemm)
    // R4 (16777216 B)
    char* R4 = R3 + 25165824;
    unsigned short* kvcb  = (unsigned short*)(R4 + 1048576);     //  4194304
    unsigned short* Wkvbb = (unsigned short*)(R4 + 5242880);     //  4194304
    unsigned short* Vt    = (unsigned short*)R4;                 // 16777216 (after kv-gemm)

    // 0) single mega-conversion: x, Wqa, Wkva, Wqb, Wkvb, Wo
    {
        const long e0 = 1048576;           // x      (M*D/8)
        const long e1 = e0 + 393216;       // Wqa    (1536*2048/8)
        const long e2 = e1 + 147456;       // Wkva   (576*2048/8)
        const long e3 = e2 + 589824;       // Wqb    (3072*1536/8)
        const long e4 = e3 + 262144;       // Wkvb   (4096*512/8)
        const long tot = e4 + 524288;      // Wo     (2048*2048/8) -> 2965504
        conv_all<<<(int)(tot / 256), 256, 0, stream>>>(
            x, xb, e0,
            Wqa, Wcat, e1,
            Wkva, Wcat + (size_t)QLORA * D_, e2,
            Wqb, Wqbb, e3,
            Wkvb, Wkvbb, e4,
            Wo, Wob);
    }

    // 1) merged: qlkv = xb @ Wcat^T (cols 0..1535 = qlat, 1536..2111 = kvraw)
    gemm_t<float><<<dim3(NQKV / GBN, M / GBM), 256, 0, stream>>>(xb, Wcat, qlkv, M, NQKV, D_);

    // 2) q-latent norm -> bf16
    rmsnorm_b<<<M, 256, 0, stream>>>(qlkv, qlw, qlatb, QLORA, NQKV);

    // 3) qb = qlatb @ Wqbb^T (deep-pipeline; must precede any Kbf write)
    gemm8<1><<<dim3(H_ * DQK / TBN, M / TBM), 512, 0, stream>>>(qlatb, Wqbb, qb, nullptr, M, H_ * DQK, QLORA);

    // 4) kv norm -> kvcb; RoPE k_pe -> Kbf cols 128..191 (broadcast 16 heads)
    kv_post<<<M, 256, 0, stream>>>(qlkv + QLORA, kvw, fc, kvcb, Kbf, NQKV);

    // 5) kv up-proj (deep-pipeline, routed epilogue):
    //    K-nope tiles -> Kbf cols 0..127 direct; V tiles -> kvbb
    gemm8<2><<<dim3(H_ * 256 / TBN, M / TBM), 512, 0, stream>>>(kvcb, Wkvbb, kvbb, Kbf, M, H_ * 256, KVLORA);

    // 6) V transpose (reads kvbb V-halves; writes Vt over kvcb/Wkvbb - done)
    pack_vt<<<dim3(S_ / 64, B_ * H_), 256, 0, stream>>>(kvbb, Vt);

    // 7) flash attention: 128-row q-tiles, 8 waves x 16 q-rows, pairs (bx,15-bx)
    flash_mfma<<<dim3(B_ * H_, QTILES / 2), 512, 0, stream>>>(qb, fc, Kbf, Vt, attnb);

    // 8) out = attnb @ Wob^T (deep-pipeline)
    gemm8<0><<<dim3(D_ / TBN, M / TBM), 512, 0, stream>>>(attnb, Wob, out, nullptr, M, D_, D_);
}

// Round 6
// 436.851 us; speedup vs baseline: 1.0898x; 1.0242x over previous
//
#include <hip/hip_runtime.h>
#include <math.h>

#define B_ 2
#define S_ 2048
#define D_ 2048
#define H_ 16
#define QLORA 1536
#define KVLORA 512
#define DN 128
#define DR 64
#define DQK 192
#define DV 128
#define EPSF 1e-6f
#define SCALEF 0.07216878364870322f   // 192^-0.5

typedef short short8 __attribute__((ext_vector_type(8)));
typedef float float4v __attribute__((ext_vector_type(4)));

__device__ __forceinline__ unsigned short f2bf(float f) {
    union { float f; unsigned u; } x; x.f = f;
    unsigned r = x.u + 0x7fffu + ((x.u >> 16) & 1u);   // RNE
    return (unsigned short)(r >> 16);
}
__device__ __forceinline__ float bf2f(unsigned short u) {
    union { unsigned u; float f; } x; x.u = (unsigned)u << 16;
    return x.f;
}

// async global->LDS, 16B per lane; LDS dest = wave-uniform base + lane*16
#define GLD16(src, dst)                                                        \
    __builtin_amdgcn_global_load_lds(                                          \
        (const __attribute__((address_space(1))) void*)(src),                  \
        (__attribute__((address_space(3))) void*)(dst), 16, 0, 0)

// ---------------------------------------------------------------------------
// all fp32->bf16 conversions in ONE launch (6 ranges, if-chain)
// ---------------------------------------------------------------------------
__global__ __launch_bounds__(256) void conv_all(
        const float* __restrict__ s0, unsigned short* __restrict__ d0, long e0,
        const float* __restrict__ s1, unsigned short* __restrict__ d1, long e1,
        const float* __restrict__ s2, unsigned short* __restrict__ d2, long e2,
        const float* __restrict__ s3, unsigned short* __restrict__ d3, long e3,
        const float* __restrict__ s4, unsigned short* __restrict__ d4, long e4,
        const float* __restrict__ s5, unsigned short* __restrict__ d5) {
    long c = (long)blockIdx.x * 256 + threadIdx.x;   // 8-elem chunk index
    const float* src;
    unsigned short* dst;
    if      (c < e0) { src = s0; dst = d0; }
    else if (c < e1) { src = s1; dst = d1; c -= e0; }
    else if (c < e2) { src = s2; dst = d2; c -= e1; }
    else if (c < e3) { src = s3; dst = d3; c -= e2; }
    else if (c < e4) { src = s4; dst = d4; c -= e3; }
    else             { src = s5; dst = d5; c -= e4; }
    const float* p = src + c * 8;
    float4 a = *(const float4*)(p);
    float4 b = *(const float4*)(p + 4);
    union { short8 v; unsigned short u[8]; } t;
    t.u[0] = f2bf(a.x); t.u[1] = f2bf(a.y); t.u[2] = f2bf(a.z); t.u[3] = f2bf(a.w);
    t.u[4] = f2bf(b.x); t.u[5] = f2bf(b.y); t.u[6] = f2bf(b.z); t.u[7] = f2bf(b.w);
    *(short8*)&dst[c * 8] = t.v;
}

// ---------------------------------------------------------------------------
// bf16 MFMA GEMM (m97-class 128x128, 2-barrier):  C = A[M,K] @ W[N,K]^T.
// Kept for the N=2176 qlkv GEMM only.
// ---------------------------------------------------------------------------
#define GBM 128
#define GBN 128
#define GBK 64

template <typename OT>
__global__ __launch_bounds__(256) void gemm_t(const unsigned short* __restrict__ A,
                                              const unsigned short* __restrict__ W,
                                              OT* __restrict__ C,
                                              int M, int N, int K) {
    __shared__ unsigned short As[GBM * GBK];   // 16384 B
    __shared__ unsigned short Ws[GBN * GBK];   // 16384 B

    const int tid = threadIdx.x;
    const int w = tid >> 6, lane = tid & 63;
    const int l16 = lane & 15, quad = lane >> 4;
    const int wm = (w >> 1) * 64, wn = (w & 1) * 64;
    const int row0 = blockIdx.y * GBM, col0 = blockIdx.x * GBN;

    const int rL  = lane >> 3;
    const int c8g = (lane & 7) ^ rL;
    const int swzk[2] = { (((0 * 4) + quad) ^ (l16 & 7)) * 8,
                          (((1 * 4) + quad) ^ (l16 & 7)) * 8 };

    const float4v zf = {0.f, 0.f, 0.f, 0.f};
    float4v acc[4][4] = {{zf, zf, zf, zf}, {zf, zf, zf, zf},
                         {zf, zf, zf, zf}, {zf, zf, zf, zf}};

    for (int k0 = 0; k0 < K; k0 += GBK) {
        __syncthreads();
#pragma unroll
        for (int j = 0; j < 4; ++j) {
            const int ch = w * 4 + j;
            const int r = ch * 8 + rL;
            GLD16(&A[(size_t)(row0 + r) * K + k0 + c8g * 8], &As[ch * 512]);
            GLD16(&W[(size_t)(col0 + r) * K + k0 + c8g * 8], &Ws[ch * 512]);
        }
        __syncthreads();

#pragma unroll
        for (int kk = 0; kk < 2; ++kk) {
            const int swz = swzk[kk];
            short8 af[4], bf[4];
#pragma unroll
            for (int mi = 0; mi < 4; ++mi)
                af[mi] = *(const short8*)&As[(wm + mi * 16 + l16) * GBK + swz];
#pragma unroll
            for (int ni = 0; ni < 4; ++ni)
                bf[ni] = *(const short8*)&Ws[(wn + ni * 16 + l16) * GBK + swz];
#pragma unroll
            for (int mi = 0; mi < 4; ++mi)
#pragma unroll
                for (int ni = 0; ni < 4; ++ni)
                    acc[mi][ni] = __builtin_amdgcn_mfma_f32_16x16x32_bf16(af[mi], bf[ni], acc[mi][ni], 0, 0, 0);
        }
    }

#pragma unroll
    for (int mi = 0; mi < 4; ++mi)
#pragma unroll
        for (int ni = 0; ni < 4; ++ni)
#pragma unroll
            for (int r = 0; r < 4; ++r) {
                size_t idx = (size_t)(row0 + wm + mi * 16 + quad * 4 + r) * N + col0 + wn + ni * 16 + l16;
                if constexpr (sizeof(OT) == 2) C[idx] = f2bf(acc[mi][ni][r]);
                else                           C[idx] = acc[mi][ni][r];
            }
}

// ---------------------------------------------------------------------------
// gemm8: 256xBN deep-pipeline bf16 GEMM (T3+T4): 512 threads = 8 waves,
// BK=64, double-buffered LDS, counted vmcnt (never 0 mid-loop).
// BN=256: waves 2Mx4N (128x64 each), 8 A + 8 W stage loads -> vmcnt(8).
// BN=128: waves 4Mx2N ( 64x64 each), 8 A + 4 W stage loads -> vmcnt(6);
//         grid doubles in x -> full 256-block chip fill for N=2048.
// MODE 0: fp32 C.  MODE 1: bf16 C.  MODE 2: kv routing (Cs=Kbf, Cp=kvbb).
// ---------------------------------------------------------------------------
#define TBM 256
#define TBK 64

template <int MODE, int BN>
__global__ __launch_bounds__(512, 2) void gemm8(const unsigned short* __restrict__ A,
                                                const unsigned short* __restrict__ W,
                                                void* __restrict__ Cp,
                                                unsigned short* __restrict__ Cs,
                                                int M, int N, int K) {
    constexpr int NWCH = BN / 64;                  // W stage loads per thread
    constexpr int MF = (BN == 256) ? 8 : 4;        // per-wave M frags
    __shared__ unsigned short As[2][TBM * TBK];
    __shared__ unsigned short Ws[2][BN * TBK];

    const int tid = threadIdx.x;
    const int w = tid >> 6, lane = tid & 63;
    const int l16 = lane & 15, quad = lane >> 4;
    const int wm = (BN == 256) ? (w >> 2) * 128 : (w >> 1) * 64;
    const int wn = (BN == 256) ? (w & 3) * 64 : (w & 1) * 64;
    const int row0 = blockIdx.y * TBM, col0 = blockIdx.x * BN;
    const int NT = K / TBK;

    auto stage = [&](int t_, int bufi) {
        const int k0 = t_ * TBK;
#pragma unroll
        for (int i_ = 0; i_ < 4; ++i_) {
            const int ch = i_ * 512 + w * 64 + lane;
            const int r_ = ch >> 3, c_ = ch & 7;
            GLD16(&A[(size_t)(row0 + r_) * K + k0 + ((c_ ^ (r_ & 7)) << 3)],
                  &As[bufi][(i_ * 512 + w * 64) * 8]);
        }
#pragma unroll
        for (int i_ = 0; i_ < NWCH; ++i_) {
            const int ch = i_ * 512 + w * 64 + lane;
            const int r_ = ch >> 3, c_ = ch & 7;
            GLD16(&W[(size_t)(col0 + r_) * K + k0 + ((c_ ^ (r_ & 7)) << 3)],
                  &Ws[bufi][(i_ * 512 + w * 64) * 8]);
        }
    };

    const float4v zf = {0.f, 0.f, 0.f, 0.f};
    float4v acc[MF][4];
#pragma unroll
    for (int mi = 0; mi < MF; ++mi)
#pragma unroll
        for (int ni = 0; ni < 4; ++ni) acc[mi][ni] = zf;

    stage(0, 0);
    stage(1, 1);
    if constexpr (BN == 256) asm volatile("s_waitcnt vmcnt(8)" ::: "memory");
    else                     asm volatile("s_waitcnt vmcnt(6)" ::: "memory");
    __builtin_amdgcn_sched_barrier(0);
    __builtin_amdgcn_s_barrier();
    __builtin_amdgcn_sched_barrier(0);

    for (int t = 0; t < NT; ++t) {
        const int buf = t & 1;
        const unsigned short* Ab = As[buf];
        const unsigned short* Wb = Ws[buf];

        short8 bfr[2][4];
#pragma unroll
        for (int kk = 0; kk < 2; ++kk)
#pragma unroll
            for (int ni = 0; ni < 4; ++ni) {
                const int Rn = wn + ni * 16 + l16;
                bfr[kk][ni] = *(const short8*)&Wb[Rn * TBK + (((kk * 4 + quad) ^ (l16 & 7)) << 3)];
            }
#pragma unroll
        for (int mi = 0; mi < MF; ++mi) {
            const int Rm = wm + mi * 16 + l16;
            short8 a0 = *(const short8*)&Ab[Rm * TBK + (((0 + quad) ^ (l16 & 7)) << 3)];
            short8 a1 = *(const short8*)&Ab[Rm * TBK + (((4 + quad) ^ (l16 & 7)) << 3)];
#pragma unroll
            for (int ni = 0; ni < 4; ++ni) {
                acc[mi][ni] = __builtin_amdgcn_mfma_f32_16x16x32_bf16(a0, bfr[0][ni], acc[mi][ni], 0, 0, 0);
                acc[mi][ni] = __builtin_amdgcn_mfma_f32_16x16x32_bf16(a1, bfr[1][ni], acc[mi][ni], 0, 0, 0);
            }
        }

        __builtin_amdgcn_s_barrier();
        if (t + 2 < NT) {
            stage(t + 2, buf);
            if constexpr (BN == 256) asm volatile("s_waitcnt vmcnt(8)" ::: "memory");
            else                     asm volatile("s_waitcnt vmcnt(6)" ::: "memory");
        } else if (t + 1 < NT) {
            asm volatile("s_waitcnt vmcnt(0)" ::: "memory");
        }
        __builtin_amdgcn_sched_barrier(0);
        __builtin_amdgcn_s_barrier();
        __builtin_amdgcn_sched_barrier(0);
    }

#pragma unroll
    for (int mi = 0; mi < MF; ++mi)
#pragma unroll
        for (int ni = 0; ni < 4; ++ni)
#pragma unroll
            for (int r = 0; r < 4; ++r) {
                const int row = row0 + wm + mi * 16 + quad * 4 + r;
                const int col = col0 + wn + ni * 16 + l16;
                if constexpr (MODE == 0) {
                    ((float*)Cp)[(size_t)row * N + col] = acc[mi][ni][r];
                } else if constexpr (MODE == 1) {
                    ((unsigned short*)Cp)[(size_t)row * N + col] = f2bf(acc[mi][ni][r]);
                } else {
                    const int h = col >> 8, within = col & 255;
                    const unsigned short v = f2bf(acc[mi][ni][r]);
                    if (within < 128) {
                        const int b = row >> 11, s = row & (S_ - 1);
                        Cs[((size_t)(b * H_ + h) * S_ + s) * DQK + within] = v;
                    } else {
                        ((unsigned short*)Cp)[(size_t)row * N + col] = v;
                    }
                }
            }
}

// ---------------------------------------------------------------------------
__global__ __launch_bounds__(256) void rmsnorm_b(const float* __restrict__ X,
                                                 const float* __restrict__ w,
                                                 unsigned short* __restrict__ Y,
                                                 int n, int ld) {
    __shared__ float tmp[4];
    const int row = blockIdx.x;
    const int tid = threadIdx.x;
    const float* x = X + (size_t)row * ld;

    float ss = 0.f;
    for (int c = tid; c < n; c += 256) {
        float v = x[c];
        ss = fmaf(v, v, ss);
    }
#pragma unroll
    for (int off = 32; off; off >>= 1) ss += __shfl_xor(ss, off, 64);
    if ((tid & 63) == 0) tmp[tid >> 6] = ss;
    __syncthreads();
    ss = tmp[0] + tmp[1] + tmp[2] + tmp[3];
    float r = rsqrtf(ss / (float)n + EPSF);

    for (int c = tid; c < n; c += 256)
        Y[(size_t)row * n + c] = f2bf(x[c] * r * w[c]);
}

// ---------------------------------------------------------------------------
// kv_post: RMS-norm of kv_c -> kvcb (bf16) AND k_pe RoPE written as bf16
// DIRECTLY into Kbf cols 128..191, broadcast to all 16 heads.
// Must run after the q-GEMM (Kbf aliases R3).
// ---------------------------------------------------------------------------
__global__ __launch_bounds__(256) void kv_post(const float* __restrict__ KV,
                                               const float* __restrict__ w,
                                               const float* __restrict__ fc,
                                               unsigned short* __restrict__ kvcb,
                                               unsigned short* __restrict__ Kbf,
                                               int ldkv) {
    __shared__ float tmp[4];
    const int row = blockIdx.x;
    const int s = row & (S_ - 1);
    const int b = row >> 11;
    const int tid = threadIdx.x;
    const float* kv = KV + (size_t)row * ldkv;

    float ss = 0.f;
#pragma unroll
    for (int c = tid; c < KVLORA; c += 256) {
        float v = kv[c];
        ss = fmaf(v, v, ss);
    }
#pragma unroll
    for (int off = 32; off; off >>= 1) ss += __shfl_xor(ss, off, 64);
    if ((tid & 63) == 0) tmp[tid >> 6] = ss;
    __syncthreads();
    ss = tmp[0] + tmp[1] + tmp[2] + tmp[3];
    float r = rsqrtf(ss / (float)KVLORA + EPSF);

#pragma unroll
    for (int c = tid; c < KVLORA; c += 256)
        kvcb[(size_t)row * KVLORA + c] = f2bf(kv[c] * r * w[c]);

    if (tid < 32) {
        int i = tid;
        float c0 = fc[(s * 32 + i) * 2 + 0];
        float s0 = fc[(s * 32 + i) * 2 + 1];
        float x0 = kv[KVLORA + 2 * i];
        float x1 = kv[KVLORA + 2 * i + 1];
        unsigned short b0 = f2bf(x0 * c0 - x1 * s0);
        unsigned short b1 = f2bf(x0 * s0 + x1 * c0);
#pragma unroll
        for (int h = 0; h < H_; ++h) {
            unsigned short* kp = Kbf + ((size_t)(b * H_ + h) * S_ + s) * DQK + DN;
            kp[2 * i]     = b0;
            kp[2 * i + 1] = b1;
        }
    }
}

// ---------------------------------------------------------------------------
// pack_vt: Vt (B,H,128,S) bf16 from kvbb (M,H*256) bf16 cols h*256+128..+256
// ---------------------------------------------------------------------------
__global__ __launch_bounds__(256) void pack_vt(const unsigned short* __restrict__ kvbb,
                                               unsigned short* __restrict__ Vt) {
    __shared__ unsigned short T[DV][72];
    const int st = blockIdx.x;            // seq tile (64)
    const int bh = blockIdx.y;            // b*H+h
    const int b = bh >> 4, h = bh & 15;
    const int s0 = st * 64;
    const int tid = threadIdx.x;

    for (int c = tid; c < 64 * 16; c += 256) {
        int sp = c >> 4, ch = c & 15;
        short8 v = *(const short8*)&kvbb[(size_t)(b * S_ + s0 + sp) * (H_ * 256) + h * 256 + DN + ch * 8];
        union { short8 v; unsigned short u[8]; } t; t.v = v;
        int dv = ch * 8;
#pragma unroll
        for (int e = 0; e < 8; ++e) T[dv + e][sp] = t.u[e];
    }
    __syncthreads();
    for (int c = tid; c < 128 * 8; c += 256) {
        int dv = c >> 3, ch = c & 7;
        *(short8*)&Vt[((size_t)bh * DV + dv) * S_ + s0 + ch * 8] = *(short8*)&T[dv][ch * 8];
    }
}

// ---------------------------------------------------------------------------
// MFMA flash attention (causal), bf16 in (q with fused RoPE), fp32 acc.
// v5 = R2/v3 structure with TRIPLE-buffered K/V and ONE barrier per k-tile:
//  - with 3 buffers, stage(kt+2) targets the buffer whose last reader
//    (compute kt-1) was proven done by the previous barrier; the
//    "overwritable" barrier is redundant. Single barrier bounds wave skew
//    to <1 iteration. Each wave's counted vmcnt(5) before the barrier
//    guarantees its own stage loads landed; the barrier publishes them.
//  - 512 threads, 8 waves x 16 q-rows over a 128-row q-tile; XOR-swizzled
//    global_load_lds staging (conflicts 0); wave-private Ps (stride 76).
// ---------------------------------------------------------------------------
#define QTILES 16   // 2048 / 128
#define PROW 76

__global__ __launch_bounds__(512, 1) void flash_mfma(const unsigned short* __restrict__ Qb,
                                                     const float* __restrict__ fc,
                                                     const unsigned short* __restrict__ Kbf,
                                                     const unsigned short* __restrict__ Vt,
                                                     unsigned short* __restrict__ Ob) {
    __shared__ unsigned short Ks[3][64 * 192];    // 3 x 24576 B, swizzled chunks
    __shared__ unsigned short Vs[3][128 * 64];    // 3 x 16384 B, swizzled chunks
    __shared__ unsigned short Ps[8][16][PROW];    // 19456 B, wave-private P

    const int bh = blockIdx.x;                  // b*H+h
    const int bx = blockIdx.y;                  // 0..7 pair index
    const int b = bh >> 4, h = bh & 15;
    const int tid = threadIdx.x;
    const int w = tid >> 6, lane = tid & 63;
    const int l16 = lane & 15, quad = lane >> 4;
    const int sw = l16 & 7;                     // read-side swizzle key

    const unsigned short* Kg = Kbf + (size_t)bh * S_ * DQK;
    const unsigned short* Vg = Vt + (size_t)bh * DV * S_;

    // stage K/V tile kt_ into buffer bufi: 5 global_load_lds per wave.
    auto stage = [&](int kt_, int bufi) {
        const int kb_ = kt_ * 64;
#pragma unroll
        for (int i_ = 0; i_ < 3; ++i_) {             // K: 64 rows x 24 chunks
            int ch = (w * 3 + i_) * 64 + lane;
            int r_ = ch / 24, c_ = ch - r_ * 24;
            GLD16(&Kg[(size_t)(kb_ + r_) * DQK + ((c_ ^ (r_ & 7)) << 3)],
                  &Ks[bufi][(w * 3 + i_) * 512]);
        }
#pragma unroll
        for (int i_ = 0; i_ < 2; ++i_) {             // V: 128 rows x 8 chunks
            int ch = (w * 2 + i_) * 64 + lane;
            int r_ = ch >> 3, c_ = ch & 7;
            GLD16(&Vg[(size_t)r_ * S_ + kb_ + ((c_ ^ (r_ & 7)) << 3)],
                  &Vs[bufi][(w * 2 + i_) * 512]);
        }
    };

    for (int half = 0; half < 2; ++half) {
        const int qt = half ? (QTILES - 1 - bx) : bx;
        const int q0 = qt * 128;
        const int ntiles = 2 * qt + 2;
        const int wr0 = q0 + w * 16;            // wave's first q row

        // Q A-frags (16 rows/wave), RoPE fused for d >= 128 -- issued BEFORE
        // the stages so their implicit waits don't drain the stage queue.
        short8 a_q[6];
        {
            const int s = wr0 + l16;
            const unsigned short* qrow = Qb + (size_t)(b * S_ + s) * (H_ * DQK) + h * DQK;
#pragma unroll
            for (int i = 0; i < 6; ++i) {
                short8 t = *(const short8*)&qrow[i * 32 + quad * 8];
                if (i >= 4) {
                    union { short8 v; unsigned short u[8]; } x; x.v = t;
#pragma unroll
                    for (int j = 0; j < 4; ++j) {
                        int ip = (i - 4) * 16 + quad * 4 + j;
                        float c0 = fc[(s * 32 + ip) * 2 + 0];
                        float s0 = fc[(s * 32 + ip) * 2 + 1];
                        float x0 = bf2f(x.u[2 * j]);
                        float x1 = bf2f(x.u[2 * j + 1]);
                        x.u[2 * j]     = f2bf(x0 * c0 - x1 * s0);
                        x.u[2 * j + 1] = f2bf(x0 * s0 + x1 * c0);
                    }
                    t = x.v;
                }
                a_q[i] = t;
            }
        }

        stage(0, 0);
        if (ntiles > 1) stage(1, 1);
        // everything except the newest 5 loads (tile1) retired => tile0 landed
        asm volatile("s_waitcnt vmcnt(5)" ::: "memory");
        __builtin_amdgcn_sched_barrier(0);
        __builtin_amdgcn_s_barrier();
        __builtin_amdgcn_sched_barrier(0);

        const float4v zf = {0.f, 0.f, 0.f, 0.f};
        float4v o_acc[8] = {zf, zf, zf, zf, zf, zf, zf, zf};
        float l_r[4] = {0.f, 0.f, 0.f, 0.f};

        int cb = 0;                             // compute buffer = kt % 3
        for (int kt = 0; kt < ntiles; ++kt) {
            const int kb = kt * 64;

            if (kt + 2 < ntiles) {
                int sb = cb + 2; if (sb >= 3) sb -= 3;
                stage(kt + 2, sb);              // target's readers done at bar(kt-1)
            }

            if (kb <= wr0 + 15) {               // wave not fully causal-masked
                const unsigned short* Kb_ = Ks[cb];
                const unsigned short* Vb_ = Vs[cb];

                // QK^T: 24 ds_read_b128 -> 24 mfma (4 independent acc chains)
                float4v sc[4] = {zf, zf, zf, zf};
#pragma unroll
                for (int i = 0; i < 6; ++i) {
                    short8 bk[4];
#pragma unroll
                    for (int kg = 0; kg < 4; ++kg)
                        bk[kg] = *(const short8*)&Kb_[(kg * 16 + l16) * 192 + (((i * 4 + quad) ^ sw) << 3)];
#pragma unroll
                    for (int kg = 0; kg < 4; ++kg)
                        sc[kg] = __builtin_amdgcn_mfma_f32_16x16x32_bf16(a_q[i], bk[kg], sc[kg], 0, 0, 0);
                }

                // max-free softmax (mask post-exp; wave-uniform mneed branch)
                const bool mneed = (kb + 63 > wr0);
#pragma unroll
                for (int kg = 0; kg < 4; ++kg) {
                    const int key = kb + kg * 16 + l16;
#pragma unroll
                    for (int r = 0; r < 4; ++r) {
                        float p = __expf(sc[kg][r] * SCALEF);
                        if (mneed && key > wr0 + quad * 4 + r) p = 0.f;
                        l_r[r] += p;
                        Ps[w][quad * 4 + r][kg * 16 + l16] = f2bf(p);
                    }
                }

                // PV: Ps is wave-private -> no barrier needed before reads
#pragma unroll
                for (int kc = 0; kc < 2; ++kc) {
                    short8 pa = *(const short8*)&Ps[w][l16][kc * 32 + quad * 8];
#pragma unroll
                    for (int dvt = 0; dvt < 8; ++dvt) {
                        short8 vb = *(const short8*)&Vb_[(dvt * 16 + l16) * 64 + (((kc * 4 + quad) ^ sw) << 3)];
                        o_acc[dvt] = __builtin_amdgcn_mfma_f32_16x16x32_bf16(pa, vb, o_acc[dvt], 0, 0, 0);
                    }
                }
            }

            // own tile-(kt+1) loads landed (leave kt+2's 5 in flight), publish
            if (kt + 2 < ntiles) {
                asm volatile("s_waitcnt vmcnt(5)" ::: "memory");
            } else if (kt + 1 < ntiles) {
                asm volatile("s_waitcnt vmcnt(0)" ::: "memory");
            }
            __builtin_amdgcn_sched_barrier(0);
            __builtin_amdgcn_s_barrier();
            __builtin_amdgcn_sched_barrier(0);

            cb = (cb == 2) ? 0 : cb + 1;
        }

        // epilogue: reduce l over the 16 key-lanes, write O
#pragma unroll
        for (int r = 0; r < 4; ++r) {
            float t = l_r[r];
            t += __shfl_xor(t, 1);
            t += __shfl_xor(t, 2);
            t += __shfl_xor(t, 4);
            t += __shfl_xor(t, 8);
            l_r[r] = t;
        }
#pragma unroll
        for (int r = 0; r < 4; ++r) {
            float inv = 1.f / l_r[r];
            int row = wr0 + quad * 4 + r;
            unsigned short* op = Ob + (size_t)(b * S_ + row) * (H_ * DV) + h * DV;
#pragma unroll
            for (int dvt = 0; dvt < 8; ++dvt)
                op[dvt * 16 + l16] = f2bf(o_acc[dvt][r] * inv);
        }
    }
}

// ---------------------------------------------------------------------------
extern "C" void kernel_launch(void* const* d_in, const int* in_sizes, int n_in,
                              void* d_out, int out_size, void* d_ws, size_t ws_size,
                              hipStream_t stream) {
    const float* x    = (const float*)d_in[0];
    const float* fc   = (const float*)d_in[1];
    const float* Wqa  = (const float*)d_in[2];
    const float* qlw  = (const float*)d_in[3];
    const float* Wqb  = (const float*)d_in[4];
    const float* Wkva = (const float*)d_in[5];
    const float* kvw  = (const float*)d_in[6];
    const float* Wkvb = (const float*)d_in[7];
    const float* Wo   = (const float*)d_in[8];
    float* out = (float*)d_out;

    const int M = B_ * S_;                 // 4096
    const int NQKV = QLORA + 640;          // 2176
    char* wsb = (char*)d_ws;

    // R1 (50331648 B): qb bf16 (25165824) + Wob (8388608)
    unsigned short* qb  = (unsigned short*)wsb;
    unsigned short* Wob = (unsigned short*)(wsb + 25165824);
    // R2 (67108864 B)
    char* R2 = wsb + 50331648;
    float*          qlkv  = (float*)R2;                          // 35651584
    unsigned short* xb    = (unsigned short*)(R2 + 35651584);    // 16777216
    unsigned short* Wcat  = (unsigned short*)(R2 + 52428800);    //  8912896
    unsigned short* kvbb  = (unsigned short*)R2;                 // 33554432 (after qlkv dead)
    unsigned short* attnb = (unsigned short*)R2;                 // 16777216 (after pack_vt)
    // R3 (25165824 B)
    char* R3 = R2 + 67108864;
    unsigned short* qlatb = (unsigned short*)R3;                 // 12582912
    unsigned short* Wqbb  = (unsigned short*)(R3 + 12582912);    //  9437184
    unsigned short* Kbf   = (unsigned short*)R3;                 // 25165824 (after q-gemm)
    // R4 (16777216 B)
    char* R4 = R3 + 25165824;
    unsigned short* kvcb  = (unsigned short*)(R4 + 1048576);     //  4194304
    unsigned short* Wkvbb = (unsigned short*)(R4 + 5242880);     //  4194304
    unsigned short* Vt    = (unsigned short*)R4;                 // 16777216 (after kv-gemm)

    // 0) single mega-conversion: x, Wqa, Wkva, Wqb, Wkvb, Wo
    {
        const long e0 = 1048576;           // x      (M*D/8)
        const long e1 = e0 + 393216;       // Wqa    (1536*2048/8)
        const long e2 = e1 + 147456;       // Wkva   (576*2048/8)
        const long e3 = e2 + 589824;       // Wqb    (3072*1536/8)
        const long e4 = e3 + 262144;       // Wkvb   (4096*512/8)
        const long tot = e4 + 524288;      // Wo     (2048*2048/8) -> 2965504
        conv_all<<<(int)(tot / 256), 256, 0, stream>>>(
            x, xb, e0,
            Wqa, Wcat, e1,
            Wkva, Wcat + (size_t)QLORA * D_, e2,
            Wqb, Wqbb, e3,
            Wkvb, Wkvbb, e4,
            Wo, Wob);
    }

    // 1) merged: qlkv = xb @ Wcat^T (cols 0..1535 = qlat, 1536..2111 = kvraw)
    gemm_t<float><<<dim3(NQKV / GBN, M / GBM), 256, 0, stream>>>(xb, Wcat, qlkv, M, NQKV, D_);

    // 2) q-latent norm -> bf16
    rmsnorm_b<<<M, 256, 0, stream>>>(qlkv, qlw, qlatb, QLORA, NQKV);

    // 3) qb = qlatb @ Wqbb^T (deep-pipeline 256x256; must precede Kbf writes)
    gemm8<1, 256><<<dim3(H_ * DQK / 256, M / TBM), 512, 0, stream>>>(qlatb, Wqbb, qb, nullptr, M, H_ * DQK, QLORA);

    // 4) kv norm -> kvcb; RoPE k_pe -> Kbf cols 128..191 (broadcast 16 heads)
    kv_post<<<M, 256, 0, stream>>>(qlkv + QLORA, kvw, fc, kvcb, Kbf, NQKV);

    // 5) kv up-proj (deep-pipeline 256x256, routed epilogue):
    //    K-nope tiles -> Kbf cols 0..127 direct; V tiles -> kvbb
    gemm8<2, 256><<<dim3(H_ * 256 / 256, M / TBM), 512, 0, stream>>>(kvcb, Wkvbb, kvbb, Kbf, M, H_ * 256, KVLORA);

    // 6) V transpose (reads kvbb V-halves; writes Vt over kvcb/Wkvbb - done)
    pack_vt<<<dim3(S_ / 64, B_ * H_), 256, 0, stream>>>(kvbb, Vt);

    // 7) flash attention: 128-row q-tiles, 8 waves x 16 q-rows, pairs (bx,15-bx)
    flash_mfma<<<dim3(B_ * H_, QTILES / 2), 512, 0, stream>>>(qb, fc, Kbf, Vt, attnb);

    // 8) out = attnb @ Wob^T (deep-pipeline 256x128 -> 256 blocks, full fill)
    gemm8<0, 128><<<dim3(D_ / 128, M / TBM), 512, 0, stream>>>(attnb, Wob, out, nullptr, M, D_, D_);
}

// Round 7
// 430.049 us; speedup vs baseline: 1.1071x; 1.0158x over previous
//
#include <hip/hip_runtime.h>
#include <math.h>

#define B_ 2
#define S_ 2048
#define D_ 2048
#define H_ 16
#define QLORA 1536
#define KVLORA 512
#define DN 128
#define DR 64
#define DQK 192
#define DV 128
#define EPSF 1e-6f
#define SCALEF 0.07216878364870322f   // 192^-0.5

typedef short short8 __attribute__((ext_vector_type(8)));
typedef float float4v __attribute__((ext_vector_type(4)));

__device__ __forceinline__ unsigned short f2bf(float f) {
    union { float f; unsigned u; } x; x.f = f;
    unsigned r = x.u + 0x7fffu + ((x.u >> 16) & 1u);   // RNE
    return (unsigned short)(r >> 16);
}
__device__ __forceinline__ float bf2f(unsigned short u) {
    union { unsigned u; float f; } x; x.u = (unsigned)u << 16;
    return x.f;
}

// async global->LDS, 16B per lane; LDS dest = wave-uniform base + lane*16
#define GLD16(src, dst)                                                        \
    __builtin_amdgcn_global_load_lds(                                          \
        (const __attribute__((address_space(1))) void*)(src),                  \
        (__attribute__((address_space(3))) void*)(dst), 16, 0, 0)

// ---------------------------------------------------------------------------
// all fp32->bf16 conversions in ONE launch (6 ranges, if-chain)
// ---------------------------------------------------------------------------
__global__ __launch_bounds__(256) void conv_all(
        const float* __restrict__ s0, unsigned short* __restrict__ d0, long e0,
        const float* __restrict__ s1, unsigned short* __restrict__ d1, long e1,
        const float* __restrict__ s2, unsigned short* __restrict__ d2, long e2,
        const float* __restrict__ s3, unsigned short* __restrict__ d3, long e3,
        const float* __restrict__ s4, unsigned short* __restrict__ d4, long e4,
        const float* __restrict__ s5, unsigned short* __restrict__ d5) {
    long c = (long)blockIdx.x * 256 + threadIdx.x;   // 8-elem chunk index
    const float* src;
    unsigned short* dst;
    if      (c < e0) { src = s0; dst = d0; }
    else if (c < e1) { src = s1; dst = d1; c -= e0; }
    else if (c < e2) { src = s2; dst = d2; c -= e1; }
    else if (c < e3) { src = s3; dst = d3; c -= e2; }
    else if (c < e4) { src = s4; dst = d4; c -= e3; }
    else             { src = s5; dst = d5; c -= e4; }
    const float* p = src + c * 8;
    float4 a = *(const float4*)(p);
    float4 b = *(const float4*)(p + 4);
    union { short8 v; unsigned short u[8]; } t;
    t.u[0] = f2bf(a.x); t.u[1] = f2bf(a.y); t.u[2] = f2bf(a.z); t.u[3] = f2bf(a.w);
    t.u[4] = f2bf(b.x); t.u[5] = f2bf(b.y); t.u[6] = f2bf(b.z); t.u[7] = f2bf(b.w);
    *(short8*)&dst[c * 8] = t.v;
}

// ---------------------------------------------------------------------------
// gemm8: 256xBN deep-pipeline bf16 GEMM (T3+T4): 512 threads = 8 waves,
// BK=64, double-buffered LDS, counted vmcnt (never 0 mid-loop).
// BN=256: waves 2Mx4N (128x64 each), 8 A + 8 W stage loads -> vmcnt(8).
// BN=128: waves 4Mx2N ( 64x64 each), 8 A + 4 W stage loads -> vmcnt(6).
// MODE 0: fp32 C (Cp).  MODE 1: bf16 C (Cp).
// MODE 2 (BN=256, kv up-proj): per-head 256-col tile = 128 K-nope + 128 V.
//   K-nope -> Kbf (Cs) strided per (b,h,s); V -> LDS transpose (reuses As,
//   XOR-swizzled, <=2-way banks) -> Vt (Cp) coalesced 16B stores.
//   pack_vt kernel and the kvbb intermediate are fused away.
// ---------------------------------------------------------------------------
#define TBM 256
#define TBK 64

template <int MODE, int BN>
__global__ __launch_bounds__(512, 2) void gemm8(const unsigned short* __restrict__ A,
                                                const unsigned short* __restrict__ W,
                                                void* __restrict__ Cp,
                                                unsigned short* __restrict__ Cs,
                                                int M, int N, int K) {
    constexpr int NWCH = BN / 64;                  // W stage loads per thread
    constexpr int MF = (BN == 256) ? 8 : 4;        // per-wave M frags
    __shared__ unsigned short As[2][TBM * TBK];
    __shared__ unsigned short Ws[2][BN * TBK];

    const int tid = threadIdx.x;
    const int w = tid >> 6, lane = tid & 63;
    const int l16 = lane & 15, quad = lane >> 4;
    const int wm = (BN == 256) ? (w >> 2) * 128 : (w >> 1) * 64;
    const int wn = (BN == 256) ? (w & 3) * 64 : (w & 1) * 64;
    const int row0 = blockIdx.y * TBM, col0 = blockIdx.x * BN;
    const int NT = K / TBK;

    auto stage = [&](int t_, int bufi) {
        const int k0 = t_ * TBK;
#pragma unroll
        for (int i_ = 0; i_ < 4; ++i_) {
            const int ch = i_ * 512 + w * 64 + lane;
            const int r_ = ch >> 3, c_ = ch & 7;
            GLD16(&A[(size_t)(row0 + r_) * K + k0 + ((c_ ^ (r_ & 7)) << 3)],
                  &As[bufi][(i_ * 512 + w * 64) * 8]);
        }
#pragma unroll
        for (int i_ = 0; i_ < NWCH; ++i_) {
            const int ch = i_ * 512 + w * 64 + lane;
            const int r_ = ch >> 3, c_ = ch & 7;
            GLD16(&W[(size_t)(col0 + r_) * K + k0 + ((c_ ^ (r_ & 7)) << 3)],
                  &Ws[bufi][(i_ * 512 + w * 64) * 8]);
        }
    };

    const float4v zf = {0.f, 0.f, 0.f, 0.f};
    float4v acc[MF][4];
#pragma unroll
    for (int mi = 0; mi < MF; ++mi)
#pragma unroll
        for (int ni = 0; ni < 4; ++ni) acc[mi][ni] = zf;

    stage(0, 0);
    stage(1, 1);
    if constexpr (BN == 256) asm volatile("s_waitcnt vmcnt(8)" ::: "memory");
    else                     asm volatile("s_waitcnt vmcnt(6)" ::: "memory");
    __builtin_amdgcn_sched_barrier(0);
    __builtin_amdgcn_s_barrier();
    __builtin_amdgcn_sched_barrier(0);

    for (int t = 0; t < NT; ++t) {
        const int buf = t & 1;
        const unsigned short* Ab = As[buf];
        const unsigned short* Wb = Ws[buf];

        short8 bfr[2][4];
#pragma unroll
        for (int kk = 0; kk < 2; ++kk)
#pragma unroll
            for (int ni = 0; ni < 4; ++ni) {
                const int Rn = wn + ni * 16 + l16;
                bfr[kk][ni] = *(const short8*)&Wb[Rn * TBK + (((kk * 4 + quad) ^ (l16 & 7)) << 3)];
            }
#pragma unroll
        for (int mi = 0; mi < MF; ++mi) {
            const int Rm = wm + mi * 16 + l16;
            short8 a0 = *(const short8*)&Ab[Rm * TBK + (((0 + quad) ^ (l16 & 7)) << 3)];
            short8 a1 = *(const short8*)&Ab[Rm * TBK + (((4 + quad) ^ (l16 & 7)) << 3)];
#pragma unroll
            for (int ni = 0; ni < 4; ++ni) {
                acc[mi][ni] = __builtin_amdgcn_mfma_f32_16x16x32_bf16(a0, bfr[0][ni], acc[mi][ni], 0, 0, 0);
                acc[mi][ni] = __builtin_amdgcn_mfma_f32_16x16x32_bf16(a1, bfr[1][ni], acc[mi][ni], 0, 0, 0);
            }
        }

        __builtin_amdgcn_s_barrier();
        if (t + 2 < NT) {
            stage(t + 2, buf);
            if constexpr (BN == 256) asm volatile("s_waitcnt vmcnt(8)" ::: "memory");
            else                     asm volatile("s_waitcnt vmcnt(6)" ::: "memory");
        } else if (t + 1 < NT) {
            asm volatile("s_waitcnt vmcnt(0)" ::: "memory");
        }
        __builtin_amdgcn_sched_barrier(0);
        __builtin_amdgcn_s_barrier();
        __builtin_amdgcn_sched_barrier(0);
    }

    if constexpr (MODE != 2) {
#pragma unroll
        for (int mi = 0; mi < MF; ++mi)
#pragma unroll
            for (int ni = 0; ni < 4; ++ni)
#pragma unroll
                for (int r = 0; r < 4; ++r) {
                    const int row = row0 + wm + mi * 16 + quad * 4 + r;
                    const int col = col0 + wn + ni * 16 + l16;
                    if constexpr (MODE == 0)
                        ((float*)Cp)[(size_t)row * N + col] = acc[mi][ni][r];
                    else
                        ((unsigned short*)Cp)[(size_t)row * N + col] = f2bf(acc[mi][ni][r]);
                }
    } else {
        // ---- kv routing epilogue (BN==256: one head per x-block) ----
        const int h = blockIdx.x;
        const int b = row0 >> 11, s0 = row0 & (S_ - 1);
        char* Tb = (char*)&As[0][0];                 // 64KB transpose buffer
        if (wn < 128) {
            // K-nope -> Kbf
#pragma unroll
            for (int mi = 0; mi < MF; ++mi)
#pragma unroll
                for (int ni = 0; ni < 4; ++ni)
#pragma unroll
                    for (int r = 0; r < 4; ++r) {
                        const int sl = wm + mi * 16 + quad * 4 + r;
                        const int d = wn + ni * 16 + l16;
                        Cs[((size_t)(b * H_ + h) * S_ + s0 + sl) * DQK + d] = f2bf(acc[mi][ni][r]);
                    }
        } else {
            // V -> LDS T[dv][s], byte addr dv*512 + ((s*2) ^ ((dv&7)<<4))
#pragma unroll
            for (int mi = 0; mi < MF; ++mi)
#pragma unroll
                for (int ni = 0; ni < 4; ++ni) {
                    const int dv = wn - 128 + ni * 16 + l16;
                    const int sl = wm + mi * 16 + quad * 4;
                    union { unsigned short u[4]; uint2 v; } pk;
                    pk.u[0] = f2bf(acc[mi][ni][0]);
                    pk.u[1] = f2bf(acc[mi][ni][1]);
                    pk.u[2] = f2bf(acc[mi][ni][2]);
                    pk.u[3] = f2bf(acc[mi][ni][3]);
                    *(uint2*)(Tb + dv * 512 + ((sl * 2) ^ ((dv & 7) << 4))) = pk.v;
                }
        }
        __syncthreads();
        // T -> Vt (B,H,128,S), coalesced 16B stores
        unsigned short* VtP = (unsigned short*)Cp;
#pragma unroll
        for (int i = 0; i < 8; ++i) {
            const int idx = i * 512 + tid;           // 4096 chunks
            const int dv = idx >> 5, sc = idx & 31;
            short8 v = *(const short8*)(Tb + dv * 512 + ((sc * 16) ^ ((dv & 7) << 4)));
            *(short8*)&VtP[((size_t)((b * H_ + h) * DV + dv)) * S_ + s0 + sc * 8] = v;
        }
    }
}

// ---------------------------------------------------------------------------
__global__ __launch_bounds__(256) void rmsnorm_b(const float* __restrict__ X,
                                                 const float* __restrict__ w,
                                                 unsigned short* __restrict__ Y,
                                                 int n, int ld) {
    __shared__ float tmp[4];
    const int row = blockIdx.x;
    const int tid = threadIdx.x;
    const float* x = X + (size_t)row * ld;

    float ss = 0.f;
    for (int c = tid; c < n; c += 256) {
        float v = x[c];
        ss = fmaf(v, v, ss);
    }
#pragma unroll
    for (int off = 32; off; off >>= 1) ss += __shfl_xor(ss, off, 64);
    if ((tid & 63) == 0) tmp[tid >> 6] = ss;
    __syncthreads();
    ss = tmp[0] + tmp[1] + tmp[2] + tmp[3];
    float r = rsqrtf(ss / (float)n + EPSF);

    for (int c = tid; c < n; c += 256)
        Y[(size_t)row * n + c] = f2bf(x[c] * r * w[c]);
}

// ---------------------------------------------------------------------------
// kv_post: RMS-norm of kv_c -> kvcb (bf16) AND k_pe RoPE written as bf16
// DIRECTLY into Kbf cols 128..191, broadcast to all 16 heads.
// Must run after the q-GEMM (Kbf aliases R3).
// ---------------------------------------------------------------------------
__global__ __launch_bounds__(256) void kv_post(const float* __restrict__ KV,
                                               const float* __restrict__ w,
                                               const float* __restrict__ fc,
                                               unsigned short* __restrict__ kvcb,
                                               unsigned short* __restrict__ Kbf,
                                               int ldkv) {
    __shared__ float tmp[4];
    const int row = blockIdx.x;
    const int s = row & (S_ - 1);
    const int b = row >> 11;
    const int tid = threadIdx.x;
    const float* kv = KV + (size_t)row * ldkv;

    float ss = 0.f;
#pragma unroll
    for (int c = tid; c < KVLORA; c += 256) {
        float v = kv[c];
        ss = fmaf(v, v, ss);
    }
#pragma unroll
    for (int off = 32; off; off >>= 1) ss += __shfl_xor(ss, off, 64);
    if ((tid & 63) == 0) tmp[tid >> 6] = ss;
    __syncthreads();
    ss = tmp[0] + tmp[1] + tmp[2] + tmp[3];
    float r = rsqrtf(ss / (float)KVLORA + EPSF);

#pragma unroll
    for (int c = tid; c < KVLORA; c += 256)
        kvcb[(size_t)row * KVLORA + c] = f2bf(kv[c] * r * w[c]);

    if (tid < 32) {
        int i = tid;
        float c0 = fc[(s * 32 + i) * 2 + 0];
        float s0 = fc[(s * 32 + i) * 2 + 1];
        float x0 = kv[KVLORA + 2 * i];
        float x1 = kv[KVLORA + 2 * i + 1];
        unsigned short b0 = f2bf(x0 * c0 - x1 * s0);
        unsigned short b1 = f2bf(x0 * s0 + x1 * c0);
#pragma unroll
        for (int h = 0; h < H_; ++h) {
            unsigned short* kp = Kbf + ((size_t)(b * H_ + h) * S_ + s) * DQK + DN;
            kp[2 * i]     = b0;
            kp[2 * i + 1] = b1;
        }
    }
}

// ---------------------------------------------------------------------------
// MFMA flash attention (causal), bf16 in (q with fused RoPE), fp32 acc.
// R6 structure (measured 86.2 µs, conflicts = 0): triple-buffered K/V, one
// barrier per k-tile, counted vmcnt(5); 512 threads, 8 waves x 16 q-rows
// over a 128-row q-tile; XOR-swizzled global_load_lds staging; wave-private
// Ps (stride 76). LDS-BW bound at ~5700 cy/tile -- structural plateau.
// ---------------------------------------------------------------------------
#define QTILES 16   // 2048 / 128
#define PROW 76

__global__ __launch_bounds__(512, 1) void flash_mfma(const unsigned short* __restrict__ Qb,
                                                     const float* __restrict__ fc,
                                                     const unsigned short* __restrict__ Kbf,
                                                     const unsigned short* __restrict__ Vt,
                                                     unsigned short* __restrict__ Ob) {
    __shared__ unsigned short Ks[3][64 * 192];    // 3 x 24576 B, swizzled chunks
    __shared__ unsigned short Vs[3][128 * 64];    // 3 x 16384 B, swizzled chunks
    __shared__ unsigned short Ps[8][16][PROW];    // 19456 B, wave-private P

    const int bh = blockIdx.x;                  // b*H+h
    const int bx = blockIdx.y;                  // 0..7 pair index
    const int b = bh >> 4, h = bh & 15;
    const int tid = threadIdx.x;
    const int w = tid >> 6, lane = tid & 63;
    const int l16 = lane & 15, quad = lane >> 4;
    const int sw = l16 & 7;                     // read-side swizzle key

    const unsigned short* Kg = Kbf + (size_t)bh * S_ * DQK;
    const unsigned short* Vg = Vt + (size_t)bh * DV * S_;

    // stage K/V tile kt_ into buffer bufi: 5 global_load_lds per wave.
    auto stage = [&](int kt_, int bufi) {
        const int kb_ = kt_ * 64;
#pragma unroll
        for (int i_ = 0; i_ < 3; ++i_) {             // K: 64 rows x 24 chunks
            int ch = (w * 3 + i_) * 64 + lane;
            int r_ = ch / 24, c_ = ch - r_ * 24;
            GLD16(&Kg[(size_t)(kb_ + r_) * DQK + ((c_ ^ (r_ & 7)) << 3)],
                  &Ks[bufi][(w * 3 + i_) * 512]);
        }
#pragma unroll
        for (int i_ = 0; i_ < 2; ++i_) {             // V: 128 rows x 8 chunks
            int ch = (w * 2 + i_) * 64 + lane;
            int r_ = ch >> 3, c_ = ch & 7;
            GLD16(&Vg[(size_t)r_ * S_ + kb_ + ((c_ ^ (r_ & 7)) << 3)],
                  &Vs[bufi][(w * 2 + i_) * 512]);
        }
    };

    for (int half = 0; half < 2; ++half) {
        const int qt = half ? (QTILES - 1 - bx) : bx;
        const int q0 = qt * 128;
        const int ntiles = 2 * qt + 2;
        const int wr0 = q0 + w * 16;            // wave's first q row

        // Q A-frags (16 rows/wave), RoPE fused for d >= 128 -- issued BEFORE
        // the stages so their implicit waits don't drain the stage queue.
        short8 a_q[6];
        {
            const int s = wr0 + l16;
            const unsigned short* qrow = Qb + (size_t)(b * S_ + s) * (H_ * DQK) + h * DQK;
#pragma unroll
            for (int i = 0; i < 6; ++i) {
                short8 t = *(const short8*)&qrow[i * 32 + quad * 8];
                if (i >= 4) {
                    union { short8 v; unsigned short u[8]; } x; x.v = t;
#pragma unroll
                    for (int j = 0; j < 4; ++j) {
                        int ip = (i - 4) * 16 + quad * 4 + j;
                        float c0 = fc[(s * 32 + ip) * 2 + 0];
                        float s0 = fc[(s * 32 + ip) * 2 + 1];
                        float x0 = bf2f(x.u[2 * j]);
                        float x1 = bf2f(x.u[2 * j + 1]);
                        x.u[2 * j]     = f2bf(x0 * c0 - x1 * s0);
                        x.u[2 * j + 1] = f2bf(x0 * s0 + x1 * c0);
                    }
                    t = x.v;
                }
                a_q[i] = t;
            }
        }

        stage(0, 0);
        if (ntiles > 1) stage(1, 1);
        // everything except the newest 5 loads (tile1) retired => tile0 landed
        asm volatile("s_waitcnt vmcnt(5)" ::: "memory");
        __builtin_amdgcn_sched_barrier(0);
        __builtin_amdgcn_s_barrier();
        __builtin_amdgcn_sched_barrier(0);

        const float4v zf = {0.f, 0.f, 0.f, 0.f};
        float4v o_acc[8] = {zf, zf, zf, zf, zf, zf, zf, zf};
        float l_r[4] = {0.f, 0.f, 0.f, 0.f};

        int cb = 0;                             // compute buffer = kt % 3
        for (int kt = 0; kt < ntiles; ++kt) {
            const int kb = kt * 64;

            if (kt + 2 < ntiles) {
                int sb = cb + 2; if (sb >= 3) sb -= 3;
                stage(kt + 2, sb);              // target's readers done at bar(kt-1)
            }

            if (kb <= wr0 + 15) {               // wave not fully causal-masked
                const unsigned short* Kb_ = Ks[cb];
                const unsigned short* Vb_ = Vs[cb];

                // QK^T: 24 ds_read_b128 -> 24 mfma (4 independent acc chains)
                float4v sc[4] = {zf, zf, zf, zf};
#pragma unroll
                for (int i = 0; i < 6; ++i) {
                    short8 bk[4];
#pragma unroll
                    for (int kg = 0; kg < 4; ++kg)
                        bk[kg] = *(const short8*)&Kb_[(kg * 16 + l16) * 192 + (((i * 4 + quad) ^ sw) << 3)];
#pragma unroll
                    for (int kg = 0; kg < 4; ++kg)
                        sc[kg] = __builtin_amdgcn_mfma_f32_16x16x32_bf16(a_q[i], bk[kg], sc[kg], 0, 0, 0);
                }

                // max-free softmax (mask post-exp; wave-uniform mneed branch)
                const bool mneed = (kb + 63 > wr0);
#pragma unroll
                for (int kg = 0; kg < 4; ++kg) {
                    const int key = kb + kg * 16 + l16;
#pragma unroll
                    for (int r = 0; r < 4; ++r) {
                        float p = __expf(sc[kg][r] * SCALEF);
                        if (mneed && key > wr0 + quad * 4 + r) p = 0.f;
                        l_r[r] += p;
                        Ps[w][quad * 4 + r][kg * 16 + l16] = f2bf(p);
                    }
                }

                // PV: Ps is wave-private -> no barrier needed before reads
#pragma unroll
                for (int kc = 0; kc < 2; ++kc) {
                    short8 pa = *(const short8*)&Ps[w][l16][kc * 32 + quad * 8];
#pragma unroll
                    for (int dvt = 0; dvt < 8; ++dvt) {
                        short8 vb = *(const short8*)&Vb_[(dvt * 16 + l16) * 64 + (((kc * 4 + quad) ^ sw) << 3)];
                        o_acc[dvt] = __builtin_amdgcn_mfma_f32_16x16x32_bf16(pa, vb, o_acc[dvt], 0, 0, 0);
                    }
                }
            }

            // own tile-(kt+1) loads landed (leave kt+2's 5 in flight), publish
            if (kt + 2 < ntiles) {
                asm volatile("s_waitcnt vmcnt(5)" ::: "memory");
            } else if (kt + 1 < ntiles) {
                asm volatile("s_waitcnt vmcnt(0)" ::: "memory");
            }
            __builtin_amdgcn_sched_barrier(0);
            __builtin_amdgcn_s_barrier();
            __builtin_amdgcn_sched_barrier(0);

            cb = (cb == 2) ? 0 : cb + 1;
        }

        // epilogue: reduce l over the 16 key-lanes, write O
#pragma unroll
        for (int r = 0; r < 4; ++r) {
            float t = l_r[r];
            t += __shfl_xor(t, 1);
            t += __shfl_xor(t, 2);
            t += __shfl_xor(t, 4);
            t += __shfl_xor(t, 8);
            l_r[r] = t;
        }
#pragma unroll
        for (int r = 0; r < 4; ++r) {
            float inv = 1.f / l_r[r];
            int row = wr0 + quad * 4 + r;
            unsigned short* op = Ob + (size_t)(b * S_ + row) * (H_ * DV) + h * DV;
#pragma unroll
            for (int dvt = 0; dvt < 8; ++dvt)
                op[dvt * 16 + l16] = f2bf(o_acc[dvt][r] * inv);
        }
    }
}

// ---------------------------------------------------------------------------
extern "C" void kernel_launch(void* const* d_in, const int* in_sizes, int n_in,
                              void* d_out, int out_size, void* d_ws, size_t ws_size,
                              hipStream_t stream) {
    const float* x    = (const float*)d_in[0];
    const float* fc   = (const float*)d_in[1];
    const float* Wqa  = (const float*)d_in[2];
    const float* qlw  = (const float*)d_in[3];
    const float* Wqb  = (const float*)d_in[4];
    const float* Wkva = (const float*)d_in[5];
    const float* kvw  = (const float*)d_in[6];
    const float* Wkvb = (const float*)d_in[7];
    const float* Wo   = (const float*)d_in[8];
    float* out = (float*)d_out;

    const int M = B_ * S_;                 // 4096
    const int NQKV = QLORA + 640;          // 2176
    char* wsb = (char*)d_ws;

    // R1 (50331648 B): qb bf16 (25165824) + Wob (8388608)
    unsigned short* qb  = (unsigned short*)wsb;
    unsigned short* Wob = (unsigned short*)(wsb + 25165824);
    // R2 (67108864 B)
    char* R2 = wsb + 50331648;
    float*          qlkv  = (float*)R2;                          // 35651584
    unsigned short* xb    = (unsigned short*)(R2 + 35651584);    // 16777216
    unsigned short* Wcat  = (unsigned short*)(R2 + 52428800);    //  8912896
    unsigned short* attnb = (unsigned short*)R2;                 // 16777216 (after kv_post: qlkv dead)
    unsigned short* Vt    = (unsigned short*)(R2 + 16777216);    // 16777216 (after kv_post: qlkv dead)
    // R3 (25165824 B)
    char* R3 = R2 + 67108864;
    unsigned short* qlatb = (unsigned short*)R3;                 // 12582912
    unsigned short* Wqbb  = (unsigned short*)(R3 + 12582912);    //  9437184
    unsigned short* Kbf   = (unsigned short*)R3;                 // 25165824 (after q-gemm)
    // R4 (16777216 B)
    char* R4 = R3 + 25165824;
    unsigned short* kvcb  = (unsigned short*)(R4 + 1048576);     //  4194304
    unsigned short* Wkvbb = (unsigned short*)(R4 + 5242880);     //  4194304

    // 0) single mega-conversion: x, Wqa, Wkva, Wqb, Wkvb, Wo
    {
        const long e0 = 1048576;           // x      (M*D/8)
        const long e1 = e0 + 393216;       // Wqa    (1536*2048/8)
        const long e2 = e1 + 147456;       // Wkva   (576*2048/8)
        const long e3 = e2 + 589824;       // Wqb    (3072*1536/8)
        const long e4 = e3 + 262144;       // Wkvb   (4096*512/8)
        const long tot = e4 + 524288;      // Wo     (2048*2048/8) -> 2965504
        conv_all<<<(int)(tot / 256), 256, 0, stream>>>(
            x, xb, e0,
            Wqa, Wcat, e1,
            Wkva, Wcat + (size_t)QLORA * D_, e2,
            Wqb, Wqbb, e3,
            Wkvb, Wkvbb, e4,
            Wo, Wob);
    }

    // 1) merged: qlkv = xb @ Wcat^T (deep-pipeline, 272 blocks ~ full fill)
    gemm8<0, 128><<<dim3(NQKV / 128, M / TBM), 512, 0, stream>>>(xb, Wcat, qlkv, nullptr, M, NQKV, D_);

    // 2) q-latent norm -> bf16
    rmsnorm_b<<<M, 256, 0, stream>>>(qlkv, qlw, qlatb, QLORA, NQKV);

    // 3) qb = qlatb @ Wqbb^T (deep-pipeline 256x256; must precede Kbf writes)
    gemm8<1, 256><<<dim3(H_ * DQK / 256, M / TBM), 512, 0, stream>>>(qlatb, Wqbb, qb, nullptr, M, H_ * DQK, QLORA);

    // 4) kv norm -> kvcb; RoPE k_pe -> Kbf cols 128..191 (broadcast 16 heads)
    //    (last reader of qlkv -> Vt/attnb regions free after this)
    kv_post<<<M, 256, 0, stream>>>(qlkv + QLORA, kvw, fc, kvcb, Kbf, NQKV);

    // 5) kv up-proj (deep-pipeline, routed epilogue): K-nope -> Kbf direct;
    //    V -> in-kernel LDS transpose -> Vt (pack_vt + kvbb fused away)
    gemm8<2, 256><<<dim3(H_ * 256 / 256, M / TBM), 512, 0, stream>>>(kvcb, Wkvbb, Vt, Kbf, M, H_ * 256, KVLORA);

    // 6) flash attention: 128-row q-tiles, 8 waves x 16 q-rows, pairs (bx,15-bx)
    flash_mfma<<<dim3(B_ * H_, QTILES / 2), 512, 0, stream>>>(qb, fc, Kbf, Vt, attnb);

    // 7) out = attnb @ Wob^T (deep-pipeline 256x128 -> 256 blocks, full fill)
    gemm8<0, 128><<<dim3(D_ / 128, M / TBM), 512, 0, stream>>>(attnb, Wob, out, nullptr, M, D_, D_);
}

// Round 9
// 419.639 us; speedup vs baseline: 1.1345x; 1.0248x over previous
//
#include <hip/hip_runtime.h>
#include <math.h>

#define B_ 2
#define S_ 2048
#define D_ 2048
#define H_ 16
#define QLORA 1536
#define KVLORA 512
#define DN 128
#define DR 64
#define DQK 192
#define DV 128
#define EPSF 1e-6f
#define SCALEF 0.07216878364870322f   // 192^-0.5

typedef short short8 __attribute__((ext_vector_type(8)));
typedef float float4v __attribute__((ext_vector_type(4)));

__device__ __forceinline__ unsigned short f2bf(float f) {
    union { float f; unsigned u; } x; x.f = f;
    unsigned r = x.u + 0x7fffu + ((x.u >> 16) & 1u);   // RNE
    return (unsigned short)(r >> 16);
}
__device__ __forceinline__ float bf2f(unsigned short u) {
    union { unsigned u; float f; } x; x.u = (unsigned)u << 16;
    return x.f;
}

// async global->LDS, 16B per lane; LDS dest = wave-uniform base + lane*16
#define GLD16(src, dst)                                                        \
    __builtin_amdgcn_global_load_lds(                                          \
        (const __attribute__((address_space(1))) void*)(src),                  \
        (__attribute__((address_space(3))) void*)(dst), 16, 0, 0)

// ---------------------------------------------------------------------------
// all fp32->bf16 conversions in ONE launch (6 ranges, if-chain)
// ---------------------------------------------------------------------------
__global__ __launch_bounds__(256) void conv_all(
        const float* __restrict__ s0, unsigned short* __restrict__ d0, long e0,
        const float* __restrict__ s1, unsigned short* __restrict__ d1, long e1,
        const float* __restrict__ s2, unsigned short* __restrict__ d2, long e2,
        const float* __restrict__ s3, unsigned short* __restrict__ d3, long e3,
        const float* __restrict__ s4, unsigned short* __restrict__ d4, long e4,
        const float* __restrict__ s5, unsigned short* __restrict__ d5) {
    long c = (long)blockIdx.x * 256 + threadIdx.x;   // 8-elem chunk index
    const float* src;
    unsigned short* dst;
    if      (c < e0) { src = s0; dst = d0; }
    else if (c < e1) { src = s1; dst = d1; c -= e0; }
    else if (c < e2) { src = s2; dst = d2; c -= e1; }
    else if (c < e3) { src = s3; dst = d3; c -= e2; }
    else if (c < e4) { src = s4; dst = d4; c -= e3; }
    else             { src = s5; dst = d5; c -= e4; }
    const float* p = src + c * 8;
    float4 a = *(const float4*)(p);
    float4 b = *(const float4*)(p + 4);
    union { short8 v; unsigned short u[8]; } t;
    t.u[0] = f2bf(a.x); t.u[1] = f2bf(a.y); t.u[2] = f2bf(a.z); t.u[3] = f2bf(a.w);
    t.u[4] = f2bf(b.x); t.u[5] = f2bf(b.y); t.u[6] = f2bf(b.z); t.u[7] = f2bf(b.w);
    *(short8*)&dst[c * 8] = t.v;
}

// ---------------------------------------------------------------------------
// gemm8: 256xBN deep-pipeline bf16 GEMM (T3+T4): 512 threads = 8 waves,
// BK=64, double-buffered LDS, counted vmcnt (never 0 mid-loop).
// BN=256: waves 2Mx4N (128x64 each), 8 A + 8 W stage loads -> vmcnt(8).
// BN=128: waves 4Mx2N ( 64x64 each), 8 A + 4 W stage loads -> vmcnt(6).
// MODE 0: fp32 C (Cp).  MODE 1: bf16 C (Cp).
// MODE 2 (BN=256, kv up-proj): per-head 256-col tile = 128 K-nope + 128 V.
//   K-nope -> Kbf (Cs) strided per (b,h,s); V -> LDS transpose (reuses As,
//   XOR-swizzled, <=2-way banks) -> Vt (Cp) coalesced 16B stores.
// ---------------------------------------------------------------------------
#define TBM 256
#define TBK 64

template <int MODE, int BN>
__global__ __launch_bounds__(512, 2) void gemm8(const unsigned short* __restrict__ A,
                                                const unsigned short* __restrict__ W,
                                                void* __restrict__ Cp,
                                                unsigned short* __restrict__ Cs,
                                                int M, int N, int K) {
    constexpr int NWCH = BN / 64;                  // W stage loads per thread
    constexpr int MF = (BN == 256) ? 8 : 4;        // per-wave M frags
    __shared__ unsigned short As[2][TBM * TBK];
    __shared__ unsigned short Ws[2][BN * TBK];

    const int tid = threadIdx.x;
    const int w = tid >> 6, lane = tid & 63;
    const int l16 = lane & 15, quad = lane >> 4;
    const int wm = (BN == 256) ? (w >> 2) * 128 : (w >> 1) * 64;
    const int wn = (BN == 256) ? (w & 3) * 64 : (w & 1) * 64;
    const int row0 = blockIdx.y * TBM, col0 = blockIdx.x * BN;
    const int NT = K / TBK;

    auto stage = [&](int t_, int bufi) {
        const int k0 = t_ * TBK;
#pragma unroll
        for (int i_ = 0; i_ < 4; ++i_) {
            const int ch = i_ * 512 + w * 64 + lane;
            const int r_ = ch >> 3, c_ = ch & 7;
            GLD16(&A[(size_t)(row0 + r_) * K + k0 + ((c_ ^ (r_ & 7)) << 3)],
                  &As[bufi][(i_ * 512 + w * 64) * 8]);
        }
#pragma unroll
        for (int i_ = 0; i_ < NWCH; ++i_) {
            const int ch = i_ * 512 + w * 64 + lane;
            const int r_ = ch >> 3, c_ = ch & 7;
            GLD16(&W[(size_t)(col0 + r_) * K + k0 + ((c_ ^ (r_ & 7)) << 3)],
                  &Ws[bufi][(i_ * 512 + w * 64) * 8]);
        }
    };

    const float4v zf = {0.f, 0.f, 0.f, 0.f};
    float4v acc[MF][4];
#pragma unroll
    for (int mi = 0; mi < MF; ++mi)
#pragma unroll
        for (int ni = 0; ni < 4; ++ni) acc[mi][ni] = zf;

    stage(0, 0);
    stage(1, 1);
    if constexpr (BN == 256) asm volatile("s_waitcnt vmcnt(8)" ::: "memory");
    else                     asm volatile("s_waitcnt vmcnt(6)" ::: "memory");
    __builtin_amdgcn_sched_barrier(0);
    __builtin_amdgcn_s_barrier();
    __builtin_amdgcn_sched_barrier(0);

    for (int t = 0; t < NT; ++t) {
        const int buf = t & 1;
        const unsigned short* Ab = As[buf];
        const unsigned short* Wb = Ws[buf];

        short8 bfr[2][4];
#pragma unroll
        for (int kk = 0; kk < 2; ++kk)
#pragma unroll
            for (int ni = 0; ni < 4; ++ni) {
                const int Rn = wn + ni * 16 + l16;
                bfr[kk][ni] = *(const short8*)&Wb[Rn * TBK + (((kk * 4 + quad) ^ (l16 & 7)) << 3)];
            }
#pragma unroll
        for (int mi = 0; mi < MF; ++mi) {
            const int Rm = wm + mi * 16 + l16;
            short8 a0 = *(const short8*)&Ab[Rm * TBK + (((0 + quad) ^ (l16 & 7)) << 3)];
            short8 a1 = *(const short8*)&Ab[Rm * TBK + (((4 + quad) ^ (l16 & 7)) << 3)];
#pragma unroll
            for (int ni = 0; ni < 4; ++ni) {
                acc[mi][ni] = __builtin_amdgcn_mfma_f32_16x16x32_bf16(a0, bfr[0][ni], acc[mi][ni], 0, 0, 0);
                acc[mi][ni] = __builtin_amdgcn_mfma_f32_16x16x32_bf16(a1, bfr[1][ni], acc[mi][ni], 0, 0, 0);
            }
        }

        __builtin_amdgcn_s_barrier();
        if (t + 2 < NT) {
            stage(t + 2, buf);
            if constexpr (BN == 256) asm volatile("s_waitcnt vmcnt(8)" ::: "memory");
            else                     asm volatile("s_waitcnt vmcnt(6)" ::: "memory");
        } else if (t + 1 < NT) {
            asm volatile("s_waitcnt vmcnt(0)" ::: "memory");
        }
        __builtin_amdgcn_sched_barrier(0);
        __builtin_amdgcn_s_barrier();
        __builtin_amdgcn_sched_barrier(0);
    }

    if constexpr (MODE != 2) {
#pragma unroll
        for (int mi = 0; mi < MF; ++mi)
#pragma unroll
            for (int ni = 0; ni < 4; ++ni)
#pragma unroll
                for (int r = 0; r < 4; ++r) {
                    const int row = row0 + wm + mi * 16 + quad * 4 + r;
                    const int col = col0 + wn + ni * 16 + l16;
                    if constexpr (MODE == 0)
                        ((float*)Cp)[(size_t)row * N + col] = acc[mi][ni][r];
                    else
                        ((unsigned short*)Cp)[(size_t)row * N + col] = f2bf(acc[mi][ni][r]);
                }
    } else {
        // ---- kv routing epilogue (BN==256: one head per x-block) ----
        const int h = blockIdx.x;
        const int b = row0 >> 11, s0 = row0 & (S_ - 1);
        char* Tb = (char*)&As[0][0];                 // 64KB transpose buffer
        if (wn < 128) {
            // K-nope -> Kbf
#pragma unroll
            for (int mi = 0; mi < MF; ++mi)
#pragma unroll
                for (int ni = 0; ni < 4; ++ni)
#pragma unroll
                    for (int r = 0; r < 4; ++r) {
                        const int sl = wm + mi * 16 + quad * 4 + r;
                        const int d = wn + ni * 16 + l16;
                        Cs[((size_t)(b * H_ + h) * S_ + s0 + sl) * DQK + d] = f2bf(acc[mi][ni][r]);
                    }
        } else {
            // V -> LDS T[dv][s], byte addr dv*512 + ((s*2) ^ ((dv&7)<<4))
#pragma unroll
            for (int mi = 0; mi < MF; ++mi)
#pragma unroll
                for (int ni = 0; ni < 4; ++ni) {
                    const int dv = wn - 128 + ni * 16 + l16;
                    const int sl = wm + mi * 16 + quad * 4;
                    union { unsigned short u[4]; uint2 v; } pk;
                    pk.u[0] = f2bf(acc[mi][ni][0]);
                    pk.u[1] = f2bf(acc[mi][ni][1]);
                    pk.u[2] = f2bf(acc[mi][ni][2]);
                    pk.u[3] = f2bf(acc[mi][ni][3]);
                    *(uint2*)(Tb + dv * 512 + ((sl * 2) ^ ((dv & 7) << 4))) = pk.v;
                }
        }
        __syncthreads();
        // T -> Vt (B,H,128,S), coalesced 16B stores
        unsigned short* VtP = (unsigned short*)Cp;
#pragma unroll
        for (int i = 0; i < 8; ++i) {
            const int idx = i * 512 + tid;           // 4096 chunks
            const int dv = idx >> 5, sc = idx & 31;
            short8 v = *(const short8*)(Tb + dv * 512 + ((sc * 16) ^ ((dv & 7) << 4)));
            *(short8*)&VtP[((size_t)((b * H_ + h) * DV + dv)) * S_ + s0 + sc * 8] = v;
        }
    }
}

// ---------------------------------------------------------------------------
// norms_fused: one launch for both RMS-norms (bf16 in, bf16 out, short8
// vectorized) + k_pe RoPE broadcast into Kbf cols 128..191.
// Blocks 0..M-1: q-latent rows (1536 cols). Blocks M..2M-1: kv rows
// (512 cols + 64 rope). Kbf no longer aliases R3, so this runs right
// after the qlkv GEMM.
// ---------------------------------------------------------------------------
__global__ __launch_bounds__(256) void norms_fused(
        const unsigned short* __restrict__ Xb,    // (M, 2176) bf16
        const float* __restrict__ qlw,
        const float* __restrict__ kvw,
        const float* __restrict__ fc,
        unsigned short* __restrict__ qlatb,       // (M, 1536)
        unsigned short* __restrict__ kvcb,        // (M, 512)
        unsigned short* __restrict__ Kbf) {
    __shared__ float tmp[4];
    int row = blockIdx.x;
    const int tid = threadIdx.x;
    const bool isq = row < (B_ * S_);
    if (!isq) row -= B_ * S_;
    const unsigned short* xrow = Xb + (size_t)row * 2176 + (isq ? 0 : QLORA);
    const int nch = isq ? 192 : 64;               // short8 chunks this row
    const int n = isq ? QLORA : KVLORA;

    union { short8 v; unsigned short u[8]; } t;
    float ss = 0.f;
    if (tid < nch) {
        t.v = *(const short8*)&xrow[tid * 8];
#pragma unroll
        for (int e = 0; e < 8; ++e) { float f = bf2f(t.u[e]); ss = fmaf(f, f, ss); }
    }
#pragma unroll
    for (int off = 32; off; off >>= 1) ss += __shfl_xor(ss, off, 64);
    if ((tid & 63) == 0) tmp[tid >> 6] = ss;
    __syncthreads();
    ss = tmp[0] + tmp[1] + tmp[2] + tmp[3];
    const float r = rsqrtf(ss / (float)n + EPSF);

    if (tid < nch) {
        const float* wp = (isq ? qlw : kvw) + tid * 8;
        union { short8 v; unsigned short u[8]; } o;
#pragma unroll
        for (int e = 0; e < 8; ++e) o.u[e] = f2bf(bf2f(t.u[e]) * r * wp[e]);
        if (isq) *(short8*)&qlatb[(size_t)row * QLORA + tid * 8] = o.v;
        else     *(short8*)&kvcb[(size_t)row * KVLORA + tid * 8] = o.v;
    }

    if (!isq && tid >= 64 && tid < 96) {
        const int i = tid - 64;
        const int s = row & (S_ - 1), b = row >> 11;
        float c0 = fc[(s * 32 + i) * 2 + 0];
        float s0 = fc[(s * 32 + i) * 2 + 1];
        float x0 = bf2f(xrow[KVLORA + 2 * i]);
        float x1 = bf2f(xrow[KVLORA + 2 * i + 1]);
        unsigned pk = (unsigned)f2bf(x0 * c0 - x1 * s0) |
                      ((unsigned)f2bf(x0 * s0 + x1 * c0) << 16);
#pragma unroll
        for (int h = 0; h < H_; ++h)
            *(unsigned*)&Kbf[((size_t)(b * H_ + h) * S_ + s) * DQK + DN + 2 * i] = pk;
    }
}

// ---------------------------------------------------------------------------
// MFMA flash attention (causal), bf16 in (q with fused RoPE), fp32 acc.
// R6 structure (86-95 µs, conflicts = 0): triple-buffered K/V, one barrier
// per k-tile, counted vmcnt(5); 512 threads, 8 waves x 16 q-rows over a
// 128-row q-tile; XOR-swizzled global_load_lds staging; wave-private Ps.
// ---------------------------------------------------------------------------
#define QTILES 16   // 2048 / 128
#define PROW 76

__global__ __launch_bounds__(512, 1) void flash_mfma(const unsigned short* __restrict__ Qb,
                                                     const float* __restrict__ fc,
                                                     const unsigned short* __restrict__ Kbf,
                                                     const unsigned short* __restrict__ Vt,
                                                     unsigned short* __restrict__ Ob) {
    __shared__ unsigned short Ks[3][64 * 192];    // 3 x 24576 B, swizzled chunks
    __shared__ unsigned short Vs[3][128 * 64];    // 3 x 16384 B, swizzled chunks
    __shared__ unsigned short Ps[8][16][PROW];    // 19456 B, wave-private P

    const int bh = blockIdx.x;                  // b*H+h
    const int bx = blockIdx.y;                  // 0..7 pair index
    const int b = bh >> 4, h = bh & 15;
    const int tid = threadIdx.x;
    const int w = tid >> 6, lane = tid & 63;
    const int l16 = lane & 15, quad = lane >> 4;
    const int sw = l16 & 7;                     // read-side swizzle key

    const unsigned short* Kg = Kbf + (size_t)bh * S_ * DQK;
    const unsigned short* Vg = Vt + (size_t)bh * DV * S_;

    // stage K/V tile kt_ into buffer bufi: 5 global_load_lds per wave.
    auto stage = [&](int kt_, int bufi) {
        const int kb_ = kt_ * 64;
#pragma unroll
        for (int i_ = 0; i_ < 3; ++i_) {             // K: 64 rows x 24 chunks
            int ch = (w * 3 + i_) * 64 + lane;
            int r_ = ch / 24, c_ = ch - r_ * 24;
            GLD16(&Kg[(size_t)(kb_ + r_) * DQK + ((c_ ^ (r_ & 7)) << 3)],
                  &Ks[bufi][(w * 3 + i_) * 512]);
        }
#pragma unroll
        for (int i_ = 0; i_ < 2; ++i_) {             // V: 128 rows x 8 chunks
            int ch = (w * 2 + i_) * 64 + lane;
            int r_ = ch >> 3, c_ = ch & 7;
            GLD16(&Vg[(size_t)r_ * S_ + kb_ + ((c_ ^ (r_ & 7)) << 3)],
                  &Vs[bufi][(w * 2 + i_) * 512]);
        }
    };

    for (int half = 0; half < 2; ++half) {
        const int qt = half ? (QTILES - 1 - bx) : bx;
        const int q0 = qt * 128;
        const int ntiles = 2 * qt + 2;
        const int wr0 = q0 + w * 16;            // wave's first q row

        // Q A-frags (16 rows/wave), RoPE fused for d >= 128 -- issued BEFORE
        // the stages so their implicit waits don't drain the stage queue.
        short8 a_q[6];
        {
            const int s = wr0 + l16;
            const unsigned short* qrow = Qb + (size_t)(b * S_ + s) * (H_ * DQK) + h * DQK;
#pragma unroll
            for (int i = 0; i < 6; ++i) {
                short8 t = *(const short8*)&qrow[i * 32 + quad * 8];
                if (i >= 4) {
                    union { short8 v; unsigned short u[8]; } x; x.v = t;
#pragma unroll
                    for (int j = 0; j < 4; ++j) {
                        int ip = (i - 4) * 16 + quad * 4 + j;
                        float c0 = fc[(s * 32 + ip) * 2 + 0];
                        float s0 = fc[(s * 32 + ip) * 2 + 1];
                        float x0 = bf2f(x.u[2 * j]);
                        float x1 = bf2f(x.u[2 * j + 1]);
                        x.u[2 * j]     = f2bf(x0 * c0 - x1 * s0);
                        x.u[2 * j + 1] = f2bf(x0 * s0 + x1 * c0);
                    }
                    t = x.v;
                }
                a_q[i] = t;
            }
        }

        stage(0, 0);
        if (ntiles > 1) stage(1, 1);
        // everything except the newest 5 loads (tile1) retired => tile0 landed
        asm volatile("s_waitcnt vmcnt(5)" ::: "memory");
        __builtin_amdgcn_sched_barrier(0);
        __builtin_amdgcn_s_barrier();
        __builtin_amdgcn_sched_barrier(0);

        const float4v zf = {0.f, 0.f, 0.f, 0.f};
        float4v o_acc[8] = {zf, zf, zf, zf, zf, zf, zf, zf};
        float l_r[4] = {0.f, 0.f, 0.f, 0.f};

        int cb = 0;                             // compute buffer = kt % 3
        for (int kt = 0; kt < ntiles; ++kt) {
            const int kb = kt * 64;

            if (kt + 2 < ntiles) {
                int sb = cb + 2; if (sb >= 3) sb -= 3;
                stage(kt + 2, sb);              // target's readers done at bar(kt-1)
            }

            if (kb <= wr0 + 15) {               // wave not fully causal-masked
                const unsigned short* Kb_ = Ks[cb];
                const unsigned short* Vb_ = Vs[cb];

                // QK^T: 24 ds_read_b128 -> 24 mfma (4 independent acc chains)
                float4v sc[4] = {zf, zf, zf, zf};
#pragma unroll
                for (int i = 0; i < 6; ++i) {
                    short8 bk[4];
#pragma unroll
                    for (int kg = 0; kg < 4; ++kg)
                        bk[kg] = *(const short8*)&Kb_[(kg * 16 + l16) * 192 + (((i * 4 + quad) ^ sw) << 3)];
#pragma unroll
                    for (int kg = 0; kg < 4; ++kg)
                        sc[kg] = __builtin_amdgcn_mfma_f32_16x16x32_bf16(a_q[i], bk[kg], sc[kg], 0, 0, 0);
                }

                // max-free softmax (mask post-exp; wave-uniform mneed branch)
                const bool mneed = (kb + 63 > wr0);
#pragma unroll
                for (int kg = 0; kg < 4; ++kg) {
                    const int key = kb + kg * 16 + l16;
#pragma unroll
                    for (int r = 0; r < 4; ++r) {
                        float p = __expf(sc[kg][r] * SCALEF);
                        if (mneed && key > wr0 + quad * 4 + r) p = 0.f;
                        l_r[r] += p;
                        Ps[w][quad * 4 + r][kg * 16 + l16] = f2bf(p);
                    }
                }

                // PV: Ps is wave-private -> no barrier needed before reads
#pragma unroll
                for (int kc = 0; kc < 2; ++kc) {
                    short8 pa = *(const short8*)&Ps[w][l16][kc * 32 + quad * 8];
#pragma unroll
                    for (int dvt = 0; dvt < 8; ++dvt) {
                        short8 vb = *(const short8*)&Vb_[(dvt * 16 + l16) * 64 + (((kc * 4 + quad) ^ sw) << 3)];
                        o_acc[dvt] = __builtin_amdgcn_mfma_f32_16x16x32_bf16(pa, vb, o_acc[dvt], 0, 0, 0);
                    }
                }
            }

            // own tile-(kt+1) loads landed (leave kt+2's 5 in flight), publish
            if (kt + 2 < ntiles) {
                asm volatile("s_waitcnt vmcnt(5)" ::: "memory");
            } else if (kt + 1 < ntiles) {
                asm volatile("s_waitcnt vmcnt(0)" ::: "memory");
            }
            __builtin_amdgcn_sched_barrier(0);
            __builtin_amdgcn_s_barrier();
            __builtin_amdgcn_sched_barrier(0);

            cb = (cb == 2) ? 0 : cb + 1;
        }

        // epilogue: reduce l over the 16 key-lanes, write O
#pragma unroll
        for (int r = 0; r < 4; ++r) {
            float t = l_r[r];
            t += __shfl_xor(t, 1);
            t += __shfl_xor(t, 2);
            t += __shfl_xor(t, 4);
            t += __shfl_xor(t, 8);
            l_r[r] = t;
        }
#pragma unroll
        for (int r = 0; r < 4; ++r) {
            float inv = 1.f / l_r[r];
            int row = wr0 + quad * 4 + r;
            unsigned short* op = Ob + (size_t)(b * S_ + row) * (H_ * DV) + h * DV;
#pragma unroll
            for (int dvt = 0; dvt < 8; ++dvt)
                op[dvt * 16 + l16] = f2bf(o_acc[dvt][r] * inv);
        }
    }
}

// ---------------------------------------------------------------------------
extern "C" void kernel_launch(void* const* d_in, const int* in_sizes, int n_in,
                              void* d_out, int out_size, void* d_ws, size_t ws_size,
                              hipStream_t stream) {
    const float* x    = (const float*)d_in[0];
    const float* fc   = (const float*)d_in[1];
    const float* Wqa  = (const float*)d_in[2];
    const float* qlw  = (const float*)d_in[3];
    const float* Wqb  = (const float*)d_in[4];
    const float* Wkva = (const float*)d_in[5];
    const float* kvw  = (const float*)d_in[6];
    const float* Wkvb = (const float*)d_in[7];
    const float* Wo   = (const float*)d_in[8];
    float* out = (float*)d_out;

    const int M = B_ * S_;                 // 4096
    const int NQKV = QLORA + 640;          // 2176
    char* wsb = (char*)d_ws;

    // R1 (50331648 B): qb bf16 (25165824) + Wob (8388608)
    unsigned short* qb  = (unsigned short*)wsb;
    unsigned short* Wob = (unsigned short*)(wsb + 25165824);
    // R2 (67108864 B), time-multiplexed:
    //   phase 1: qlkvb bf16 (0..17825792), xb (35651584..52428800),
    //            Wcat (52428800..61341696)
    //   phase 2 (after norms_fused, qlkvb/xb/Wcat dead):
    //            attnb (0..16777216), Vt (16777216..33554432),
    //            Kbf (35651584..60817408)
    char* R2 = wsb + 50331648;
    unsigned short* qlkvb = (unsigned short*)R2;                 // 17825792
    unsigned short* xb    = (unsigned short*)(R2 + 35651584);    // 16777216
    unsigned short* Wcat  = (unsigned short*)(R2 + 52428800);    //  8912896
    unsigned short* attnb = (unsigned short*)R2;                 // 16777216
    unsigned short* Vt    = (unsigned short*)(R2 + 16777216);    // 16777216
    unsigned short* Kbf   = (unsigned short*)(R2 + 35651584);    // 25165824
    // R3 (25165824 B)
    char* R3 = R2 + 67108864;
    unsigned short* qlatb = (unsigned short*)R3;                 // 12582912
    unsigned short* Wqbb  = (unsigned short*)(R3 + 12582912);    //  9437184
    // R4 (16777216 B)
    char* R4 = R3 + 25165824;
    unsigned short* kvcb  = (unsigned short*)(R4 + 1048576);     //  4194304
    unsigned short* Wkvbb = (unsigned short*)(R4 + 5242880);     //  4194304

    // 0) single mega-conversion: x, Wqa, Wkva, Wqb, Wkvb, Wo
    {
        const long e0 = 1048576;           // x      (M*D/8)
        const long e1 = e0 + 393216;       // Wqa    (1536*2048/8)
        const long e2 = e1 + 147456;       // Wkva   (576*2048/8)
        const long e3 = e2 + 589824;       // Wqb    (3072*1536/8)
        const long e4 = e3 + 262144;       // Wkvb   (4096*512/8)
        const long tot = e4 + 524288;      // Wo     (2048*2048/8) -> 2965504
        conv_all<<<(int)(tot / 256), 256, 0, stream>>>(
            x, xb, e0,
            Wqa, Wcat, e1,
            Wkva, Wcat + (size_t)QLORA * D_, e2,
            Wqb, Wqbb, e3,
            Wkvb, Wkvbb, e4,
            Wo, Wob);
    }

    // 1) merged qlkv GEMM -> bf16 (halved write traffic), 272 blocks
    gemm8<1, 128><<<dim3(NQKV / 128, M / TBM), 512, 0, stream>>>(xb, Wcat, qlkvb, nullptr, M, NQKV, D_);

    // 2) both norms + rope broadcast in ONE launch (Kbf no longer aliases R3)
    norms_fused<<<2 * M, 256, 0, stream>>>(qlkvb, qlw, kvw, fc, qlatb, kvcb, Kbf);

    // 3) qb = qlatb @ Wqbb^T (deep-pipeline 256x256)
    gemm8<1, 256><<<dim3(H_ * DQK / 256, M / TBM), 512, 0, stream>>>(qlatb, Wqbb, qb, nullptr, M, H_ * DQK, QLORA);

    // 4) kv up-proj (deep-pipeline, routed epilogue): K-nope -> Kbf direct;
    //    V -> in-kernel LDS transpose -> Vt
    gemm8<2, 256><<<dim3(H_ * 256 / 256, M / TBM), 512, 0, stream>>>(kvcb, Wkvbb, Vt, Kbf, M, H_ * 256, KVLORA);

    // 5) flash attention: 128-row q-tiles, 8 waves x 16 q-rows, pairs (bx,15-bx)
    flash_mfma<<<dim3(B_ * H_, QTILES / 2), 512, 0, stream>>>(qb, fc, Kbf, Vt, attnb);

    // 6) out = attnb @ Wob^T (deep-pipeline 256x128 -> 256 blocks, full fill)
    gemm8<0, 128><<<dim3(D_ / 128, M / TBM), 512, 0, stream>>>(attnb, Wob, out, nullptr, M, D_, D_);
}

// Round 10
// 401.407 us; speedup vs baseline: 1.1861x; 1.0454x over previous
//
#include <hip/hip_runtime.h>
#include <math.h>

#define B_ 2
#define S_ 2048
#define D_ 2048
#define H_ 16
#define QLORA 1536
#define KVLORA 512
#define DN 128
#define DR 64
#define DQK 192
#define DV 128
#define EPSF 1e-6f
#define SCALEF 0.07216878364870322f   // 192^-0.5

typedef short short8 __attribute__((ext_vector_type(8)));
typedef float float4v __attribute__((ext_vector_type(4)));

__device__ __forceinline__ unsigned short f2bf(float f) {
    union { float f; unsigned u; } x; x.f = f;
    unsigned r = x.u + 0x7fffu + ((x.u >> 16) & 1u);   // RNE
    return (unsigned short)(r >> 16);
}
__device__ __forceinline__ float bf2f(unsigned short u) {
    union { unsigned u; float f; } x; x.u = (unsigned)u << 16;
    return x.f;
}

// async global->LDS, 16B per lane; LDS dest = wave-uniform base + lane*16
#define GLD16(src, dst)                                                        \
    __builtin_amdgcn_global_load_lds(                                          \
        (const __attribute__((address_space(1))) void*)(src),                  \
        (__attribute__((address_space(3))) void*)(dst), 16, 0, 0)

__device__ __forceinline__ void conv8(const float* p, unsigned short* d) {
    float4 a = *(const float4*)(p);
    float4 b = *(const float4*)(p + 4);
    union { short8 v; unsigned short u[8]; } t;
    t.u[0] = f2bf(a.x); t.u[1] = f2bf(a.y); t.u[2] = f2bf(a.z); t.u[3] = f2bf(a.w);
    t.u[4] = f2bf(b.x); t.u[5] = f2bf(b.y); t.u[6] = f2bf(b.z); t.u[7] = f2bf(b.w);
    *(short8*)d = t.v;
}

// ---------------------------------------------------------------------------
// conv_xa: fp32->bf16 for the tensors the qlkv GEMM needs NOW (x, Wqa, Wkva).
// The other weights (Wqb, Wkvb, Wo) convert inside the qlkv launch (overlap).
// ---------------------------------------------------------------------------
__global__ __launch_bounds__(256) void conv_xa(
        const float* __restrict__ s0, unsigned short* __restrict__ d0, long e0,
        const float* __restrict__ s1, unsigned short* __restrict__ d1, long e1,
        const float* __restrict__ s2, unsigned short* __restrict__ d2) {
    long c = (long)blockIdx.x * 256 + threadIdx.x;   // 8-elem chunk index
    const float* src;
    unsigned short* dst;
    if      (c < e0) { src = s0; dst = d0; }
    else if (c < e1) { src = s1; dst = d1; c -= e0; }
    else             { src = s2; dst = d2; c -= e1; }
    conv8(src + c * 8, dst + c * 8);
}

// ---------------------------------------------------------------------------
// qlkv_conv: blocks 0..271 = deep-pipeline 256x128 GEMM qlkvb = xb @ Wcat^T
// (bf16 out, N=2176, K=2048); blocks 272..335 = grid-stride fp32->bf16 for
// Wqb/Wkvb/Wo (these are only needed by the NEXT launch -> overlap here).
// ---------------------------------------------------------------------------
#define TBM 256
#define TBK 64

__global__ __launch_bounds__(512, 2) void qlkv_conv(
        const unsigned short* __restrict__ A,     // xb (M,2048)
        const unsigned short* __restrict__ W,     // Wcat (2176,2048)
        unsigned short* __restrict__ C,           // qlkvb (M,2176)
        const float* __restrict__ Wqb, unsigned short* __restrict__ Wqbb,
        const float* __restrict__ Wkvb, unsigned short* __restrict__ Wkvbb,
        const float* __restrict__ Wo, unsigned short* __restrict__ Wob) {
    const int id = blockIdx.x;
    const int tid = threadIdx.x;

    if (id >= 272) {                              // ---- conv part ----
        const long t1 = 589824, t2 = t1 + 262144, tot = t2 + 524288;
        for (long c = (long)(id - 272) * 512 + tid; c < tot; c += 64L * 512) {
            const float* s; unsigned short* d; long cc = c;
            if      (c < t1) { s = Wqb;  d = Wqbb; }
            else if (c < t2) { s = Wkvb; d = Wkvbb; cc -= t1; }
            else             { s = Wo;   d = Wob;   cc -= t2; }
            conv8(s + cc * 8, d + cc * 8);
        }
        return;
    }

    // ---- gemm part: BN=128, MF=4, N=2176, K=2048, NT=32, vmcnt(6) ----
    constexpr int N = 2176, K = 2048, NT = 32;
    __shared__ unsigned short As[2][TBM * TBK];
    __shared__ unsigned short Ws[2][128 * TBK];

    const int w = tid >> 6, lane = tid & 63;
    const int l16 = lane & 15, quad = lane >> 4;
    const int wm = (w >> 1) * 64, wn = (w & 1) * 64;
    const int row0 = (id / 17) * TBM, col0 = (id % 17) * 128;

    auto stage = [&](int t_, int bufi) {
        const int k0 = t_ * TBK;
#pragma unroll
        for (int i_ = 0; i_ < 4; ++i_) {
            const int ch = i_ * 512 + w * 64 + lane;
            const int r_ = ch >> 3, c_ = ch & 7;
            GLD16(&A[(size_t)(row0 + r_) * K + k0 + ((c_ ^ (r_ & 7)) << 3)],
                  &As[bufi][(i_ * 512 + w * 64) * 8]);
        }
#pragma unroll
        for (int i_ = 0; i_ < 2; ++i_) {
            const int ch = i_ * 512 + w * 64 + lane;
            const int r_ = ch >> 3, c_ = ch & 7;
            GLD16(&W[(size_t)(col0 + r_) * K + k0 + ((c_ ^ (r_ & 7)) << 3)],
                  &Ws[bufi][(i_ * 512 + w * 64) * 8]);
        }
    };

    const float4v zf = {0.f, 0.f, 0.f, 0.f};
    float4v acc[4][4];
#pragma unroll
    for (int mi = 0; mi < 4; ++mi)
#pragma unroll
        for (int ni = 0; ni < 4; ++ni) acc[mi][ni] = zf;

    stage(0, 0);
    stage(1, 1);
    asm volatile("s_waitcnt vmcnt(6)" ::: "memory");
    __builtin_amdgcn_sched_barrier(0);
    __builtin_amdgcn_s_barrier();
    __builtin_amdgcn_sched_barrier(0);

    for (int t = 0; t < NT; ++t) {
        const int buf = t & 1;
        const unsigned short* Ab = As[buf];
        const unsigned short* Wb = Ws[buf];

        short8 bfr[2][4];
#pragma unroll
        for (int kk = 0; kk < 2; ++kk)
#pragma unroll
            for (int ni = 0; ni < 4; ++ni) {
                const int Rn = wn + ni * 16 + l16;
                bfr[kk][ni] = *(const short8*)&Wb[Rn * TBK + (((kk * 4 + quad) ^ (l16 & 7)) << 3)];
            }
#pragma unroll
        for (int mi = 0; mi < 4; ++mi) {
            const int Rm = wm + mi * 16 + l16;
            short8 a0 = *(const short8*)&Ab[Rm * TBK + (((0 + quad) ^ (l16 & 7)) << 3)];
            short8 a1 = *(const short8*)&Ab[Rm * TBK + (((4 + quad) ^ (l16 & 7)) << 3)];
#pragma unroll
            for (int ni = 0; ni < 4; ++ni) {
                acc[mi][ni] = __builtin_amdgcn_mfma_f32_16x16x32_bf16(a0, bfr[0][ni], acc[mi][ni], 0, 0, 0);
                acc[mi][ni] = __builtin_amdgcn_mfma_f32_16x16x32_bf16(a1, bfr[1][ni], acc[mi][ni], 0, 0, 0);
            }
        }

        __builtin_amdgcn_s_barrier();
        if (t + 2 < NT) {
            stage(t + 2, buf);
            asm volatile("s_waitcnt vmcnt(6)" ::: "memory");
        } else if (t + 1 < NT) {
            asm volatile("s_waitcnt vmcnt(0)" ::: "memory");
        }
        __builtin_amdgcn_sched_barrier(0);
        __builtin_amdgcn_s_barrier();
        __builtin_amdgcn_sched_barrier(0);
    }

#pragma unroll
    for (int mi = 0; mi < 4; ++mi)
#pragma unroll
        for (int ni = 0; ni < 4; ++ni)
#pragma unroll
            for (int r = 0; r < 4; ++r) {
                const int row = row0 + wm + mi * 16 + quad * 4 + r;
                const int col = col0 + wn + ni * 16 + l16;
                C[(size_t)row * N + col] = f2bf(acc[mi][ni][r]);
            }
}

// ---------------------------------------------------------------------------
// gemm_qkv: ONE launch for both post-norm up-projections (448 blocks):
//  blocks 0..191  : qb = qlatb @ Wqbb^T  (N=3072, K=1536, bf16 out)
//  blocks 192..447: kv up-proj (N=4096, K=512) with routed epilogue:
//                   K-nope -> Kbf, V -> LDS transpose -> Vt.
// Both use the BN=256 wave geometry (8 waves, 128x64 each, vmcnt(8)).
// Long q-blocks dispatch first (LPT) -> makespan ~26 NT-units vs 32 serial.
// ---------------------------------------------------------------------------
__global__ __launch_bounds__(512, 2) void gemm_qkv(
        const unsigned short* __restrict__ qlatb,
        const unsigned short* __restrict__ Wqbb,
        unsigned short* __restrict__ qb,
        const unsigned short* __restrict__ kvcb,
        const unsigned short* __restrict__ Wkvbb,
        unsigned short* __restrict__ Vt,
        unsigned short* __restrict__ Kbf) {
    __shared__ unsigned short As[2][TBM * TBK];
    __shared__ unsigned short Ws[2][256 * TBK];

    const int id = blockIdx.x;
    const int tid = threadIdx.x;
    const bool isq = id < 192;
    const unsigned short* A;
    const unsigned short* W;
    int N, K, row0, col0, hh = 0;
    if (isq) {
        A = qlatb; W = Wqbb; N = 3072; K = 1536;
        col0 = (id % 12) * 256; row0 = (id / 12) * TBM;
    } else {
        const int idk = id - 192;
        hh = idk % 16;
        A = kvcb; W = Wkvbb; N = 4096; K = 512;
        col0 = hh * 256; row0 = (idk / 16) * TBM;
    }
    const int NT = K / TBK;

    const int w = tid >> 6, lane = tid & 63;
    const int l16 = lane & 15, quad = lane >> 4;
    const int wm = (w >> 2) * 128, wn = (w & 3) * 64;

    auto stage = [&](int t_, int bufi) {
        const int k0 = t_ * TBK;
#pragma unroll
        for (int i_ = 0; i_ < 4; ++i_) {
            const int ch = i_ * 512 + w * 64 + lane;
            const int r_ = ch >> 3, c_ = ch & 7;
            GLD16(&A[(size_t)(row0 + r_) * K + k0 + ((c_ ^ (r_ & 7)) << 3)],
                  &As[bufi][(i_ * 512 + w * 64) * 8]);
        }
#pragma unroll
        for (int i_ = 0; i_ < 4; ++i_) {
            const int ch = i_ * 512 + w * 64 + lane;
            const int r_ = ch >> 3, c_ = ch & 7;
            GLD16(&W[(size_t)(col0 + r_) * K + k0 + ((c_ ^ (r_ & 7)) << 3)],
                  &Ws[bufi][(i_ * 512 + w * 64) * 8]);
        }
    };

    const float4v zf = {0.f, 0.f, 0.f, 0.f};
    float4v acc[8][4];
#pragma unroll
    for (int mi = 0; mi < 8; ++mi)
#pragma unroll
        for (int ni = 0; ni < 4; ++ni) acc[mi][ni] = zf;

    stage(0, 0);
    stage(1, 1);
    asm volatile("s_waitcnt vmcnt(8)" ::: "memory");
    __builtin_amdgcn_sched_barrier(0);
    __builtin_amdgcn_s_barrier();
    __builtin_amdgcn_sched_barrier(0);

    for (int t = 0; t < NT; ++t) {
        const int buf = t & 1;
        const unsigned short* Ab = As[buf];
        const unsigned short* Wb = Ws[buf];

        short8 bfr[2][4];
#pragma unroll
        for (int kk = 0; kk < 2; ++kk)
#pragma unroll
            for (int ni = 0; ni < 4; ++ni) {
                const int Rn = wn + ni * 16 + l16;
                bfr[kk][ni] = *(const short8*)&Wb[Rn * TBK + (((kk * 4 + quad) ^ (l16 & 7)) << 3)];
            }
#pragma unroll
        for (int mi = 0; mi < 8; ++mi) {
            const int Rm = wm + mi * 16 + l16;
            short8 a0 = *(const short8*)&Ab[Rm * TBK + (((0 + quad) ^ (l16 & 7)) << 3)];
            short8 a1 = *(const short8*)&Ab[Rm * TBK + (((4 + quad) ^ (l16 & 7)) << 3)];
#pragma unroll
            for (int ni = 0; ni < 4; ++ni) {
                acc[mi][ni] = __builtin_amdgcn_mfma_f32_16x16x32_bf16(a0, bfr[0][ni], acc[mi][ni], 0, 0, 0);
                acc[mi][ni] = __builtin_amdgcn_mfma_f32_16x16x32_bf16(a1, bfr[1][ni], acc[mi][ni], 0, 0, 0);
            }
        }

        __builtin_amdgcn_s_barrier();
        if (t + 2 < NT) {
            stage(t + 2, buf);
            asm volatile("s_waitcnt vmcnt(8)" ::: "memory");
        } else if (t + 1 < NT) {
            asm volatile("s_waitcnt vmcnt(0)" ::: "memory");
        }
        __builtin_amdgcn_sched_barrier(0);
        __builtin_amdgcn_s_barrier();
        __builtin_amdgcn_sched_barrier(0);
    }

    if (isq) {
#pragma unroll
        for (int mi = 0; mi < 8; ++mi)
#pragma unroll
            for (int ni = 0; ni < 4; ++ni)
#pragma unroll
                for (int r = 0; r < 4; ++r) {
                    const int row = row0 + wm + mi * 16 + quad * 4 + r;
                    const int col = col0 + wn + ni * 16 + l16;
                    qb[(size_t)row * 3072 + col] = f2bf(acc[mi][ni][r]);
                }
    } else {
        // ---- kv routing epilogue (one head per block) ----
        const int b = row0 >> 11, s0 = row0 & (S_ - 1);
        char* Tb = (char*)&As[0][0];                 // 64KB transpose buffer
        if (wn < 128) {
            // K-nope -> Kbf
#pragma unroll
            for (int mi = 0; mi < 8; ++mi)
#pragma unroll
                for (int ni = 0; ni < 4; ++ni)
#pragma unroll
                    for (int r = 0; r < 4; ++r) {
                        const int sl = wm + mi * 16 + quad * 4 + r;
                        const int d = wn + ni * 16 + l16;
                        Kbf[((size_t)(b * H_ + hh) * S_ + s0 + sl) * DQK + d] = f2bf(acc[mi][ni][r]);
                    }
        } else {
            // V -> LDS T[dv][s], byte addr dv*512 + ((s*2) ^ ((dv&7)<<4))
#pragma unroll
            for (int mi = 0; mi < 8; ++mi)
#pragma unroll
                for (int ni = 0; ni < 4; ++ni) {
                    const int dv = wn - 128 + ni * 16 + l16;
                    const int sl = wm + mi * 16 + quad * 4;
                    union { unsigned short u[4]; uint2 v; } pk;
                    pk.u[0] = f2bf(acc[mi][ni][0]);
                    pk.u[1] = f2bf(acc[mi][ni][1]);
                    pk.u[2] = f2bf(acc[mi][ni][2]);
                    pk.u[3] = f2bf(acc[mi][ni][3]);
                    *(uint2*)(Tb + dv * 512 + ((sl * 2) ^ ((dv & 7) << 4))) = pk.v;
                }
        }
        __syncthreads();
        // T -> Vt (B,H,128,S), coalesced 16B stores
#pragma unroll
        for (int i = 0; i < 8; ++i) {
            const int idx = i * 512 + tid;           // 4096 chunks
            const int dv = idx >> 5, sc = idx & 31;
            short8 v = *(const short8*)(Tb + dv * 512 + ((sc * 16) ^ ((dv & 7) << 4)));
            *(short8*)&Vt[((size_t)((b * H_ + hh) * DV + dv)) * S_ + s0 + sc * 8] = v;
        }
    }
}

// ---------------------------------------------------------------------------
// gemm8 (BN=128, fp32 out): kept for the final out = attnb @ Wob^T.
// ---------------------------------------------------------------------------
__global__ __launch_bounds__(512, 2) void gemm_out(const unsigned short* __restrict__ A,
                                                   const unsigned short* __restrict__ W,
                                                   float* __restrict__ C,
                                                   int M, int N, int K) {
    __shared__ unsigned short As[2][TBM * TBK];
    __shared__ unsigned short Ws[2][128 * TBK];

    const int tid = threadIdx.x;
    const int w = tid >> 6, lane = tid & 63;
    const int l16 = lane & 15, quad = lane >> 4;
    const int wm = (w >> 1) * 64, wn = (w & 1) * 64;
    const int row0 = blockIdx.y * TBM, col0 = blockIdx.x * 128;
    const int NT = K / TBK;

    auto stage = [&](int t_, int bufi) {
        const int k0 = t_ * TBK;
#pragma unroll
        for (int i_ = 0; i_ < 4; ++i_) {
            const int ch = i_ * 512 + w * 64 + lane;
            const int r_ = ch >> 3, c_ = ch & 7;
            GLD16(&A[(size_t)(row0 + r_) * K + k0 + ((c_ ^ (r_ & 7)) << 3)],
                  &As[bufi][(i_ * 512 + w * 64) * 8]);
        }
#pragma unroll
        for (int i_ = 0; i_ < 2; ++i_) {
            const int ch = i_ * 512 + w * 64 + lane;
            const int r_ = ch >> 3, c_ = ch & 7;
            GLD16(&W[(size_t)(col0 + r_) * K + k0 + ((c_ ^ (r_ & 7)) << 3)],
                  &Ws[bufi][(i_ * 512 + w * 64) * 8]);
        }
    };

    const float4v zf = {0.f, 0.f, 0.f, 0.f};
    float4v acc[4][4];
#pragma unroll
    for (int mi = 0; mi < 4; ++mi)
#pragma unroll
        for (int ni = 0; ni < 4; ++ni) acc[mi][ni] = zf;

    stage(0, 0);
    stage(1, 1);
    asm volatile("s_waitcnt vmcnt(6)" ::: "memory");
    __builtin_amdgcn_sched_barrier(0);
    __builtin_amdgcn_s_barrier();
    __builtin_amdgcn_sched_barrier(0);

    for (int t = 0; t < NT; ++t) {
        const int buf = t & 1;
        const unsigned short* Ab = As[buf];
        const unsigned short* Wb = Ws[buf];

        short8 bfr[2][4];
#pragma unroll
        for (int kk = 0; kk < 2; ++kk)
#pragma unroll
            for (int ni = 0; ni < 4; ++ni) {
                const int Rn = wn + ni * 16 + l16;
                bfr[kk][ni] = *(const short8*)&Wb[Rn * TBK + (((kk * 4 + quad) ^ (l16 & 7)) << 3)];
            }
#pragma unroll
        for (int mi = 0; mi < 4; ++mi) {
            const int Rm = wm + mi * 16 + l16;
            short8 a0 = *(const short8*)&Ab[Rm * TBK + (((0 + quad) ^ (l16 & 7)) << 3)];
            short8 a1 = *(const short8*)&Ab[Rm * TBK + (((4 + quad) ^ (l16 & 7)) << 3)];
#pragma unroll
            for (int ni = 0; ni < 4; ++ni) {
                acc[mi][ni] = __builtin_amdgcn_mfma_f32_16x16x32_bf16(a0, bfr[0][ni], acc[mi][ni], 0, 0, 0);
                acc[mi][ni] = __builtin_amdgcn_mfma_f32_16x16x32_bf16(a1, bfr[1][ni], acc[mi][ni], 0, 0, 0);
            }
        }

        __builtin_amdgcn_s_barrier();
        if (t + 2 < NT) {
            stage(t + 2, buf);
            asm volatile("s_waitcnt vmcnt(6)" ::: "memory");
        } else if (t + 1 < NT) {
            asm volatile("s_waitcnt vmcnt(0)" ::: "memory");
        }
        __builtin_amdgcn_sched_barrier(0);
        __builtin_amdgcn_s_barrier();
        __builtin_amdgcn_sched_barrier(0);
    }

#pragma unroll
    for (int mi = 0; mi < 4; ++mi)
#pragma unroll
        for (int ni = 0; ni < 4; ++ni)
#pragma unroll
            for (int r = 0; r < 4; ++r) {
                const int row = row0 + wm + mi * 16 + quad * 4 + r;
                const int col = col0 + wn + ni * 16 + l16;
                C[(size_t)row * N + col] = acc[mi][ni][r];
            }
}

// ---------------------------------------------------------------------------
// norms_fused: both RMS-norms (bf16 in/out, short8 vectorized) + k_pe RoPE
// broadcast into Kbf cols 128..191, one launch.
// ---------------------------------------------------------------------------
__global__ __launch_bounds__(256) void norms_fused(
        const unsigned short* __restrict__ Xb,    // (M, 2176) bf16
        const float* __restrict__ qlw,
        const float* __restrict__ kvw,
        const float* __restrict__ fc,
        unsigned short* __restrict__ qlatb,       // (M, 1536)
        unsigned short* __restrict__ kvcb,        // (M, 512)
        unsigned short* __restrict__ Kbf) {
    __shared__ float tmp[4];
    int row = blockIdx.x;
    const int tid = threadIdx.x;
    const bool isq = row < (B_ * S_);
    if (!isq) row -= B_ * S_;
    const unsigned short* xrow = Xb + (size_t)row * 2176 + (isq ? 0 : QLORA);
    const int nch = isq ? 192 : 64;               // short8 chunks this row
    const int n = isq ? QLORA : KVLORA;

    union { short8 v; unsigned short u[8]; } t;
    float ss = 0.f;
    if (tid < nch) {
        t.v = *(const short8*)&xrow[tid * 8];
#pragma unroll
        for (int e = 0; e < 8; ++e) { float f = bf2f(t.u[e]); ss = fmaf(f, f, ss); }
    }
#pragma unroll
    for (int off = 32; off; off >>= 1) ss += __shfl_xor(ss, off, 64);
    if ((tid & 63) == 0) tmp[tid >> 6] = ss;
    __syncthreads();
    ss = tmp[0] + tmp[1] + tmp[2] + tmp[3];
    const float r = rsqrtf(ss / (float)n + EPSF);

    if (tid < nch) {
        const float* wp = (isq ? qlw : kvw) + tid * 8;
        union { short8 v; unsigned short u[8]; } o;
#pragma unroll
        for (int e = 0; e < 8; ++e) o.u[e] = f2bf(bf2f(t.u[e]) * r * wp[e]);
        if (isq) *(short8*)&qlatb[(size_t)row * QLORA + tid * 8] = o.v;
        else     *(short8*)&kvcb[(size_t)row * KVLORA + tid * 8] = o.v;
    }

    if (!isq && tid >= 64 && tid < 96) {
        const int i = tid - 64;
        const int s = row & (S_ - 1), b = row >> 11;
        float c0 = fc[(s * 32 + i) * 2 + 0];
        float s0 = fc[(s * 32 + i) * 2 + 1];
        float x0 = bf2f(xrow[KVLORA + 2 * i]);
        float x1 = bf2f(xrow[KVLORA + 2 * i + 1]);
        unsigned pk = (unsigned)f2bf(x0 * c0 - x1 * s0) |
                      ((unsigned)f2bf(x0 * s0 + x1 * c0) << 16);
#pragma unroll
        for (int h = 0; h < H_; ++h)
            *(unsigned*)&Kbf[((size_t)(b * H_ + h) * S_ + s) * DQK + DN + 2 * i] = pk;
    }
}

// ---------------------------------------------------------------------------
// MFMA flash attention (causal), bf16 in (q with fused RoPE), fp32 acc.
// R6/R9 structure (~87 µs, conflicts = 0): triple-buffered K/V, one barrier
// per k-tile, counted vmcnt(5); 512 threads, 8 waves x 16 q-rows over a
// 128-row q-tile; XOR-swizzled global_load_lds staging; wave-private Ps.
// ---------------------------------------------------------------------------
#define QTILES 16   // 2048 / 128
#define PROW 76

__global__ __launch_bounds__(512, 1) void flash_mfma(const unsigned short* __restrict__ Qb,
                                                     const float* __restrict__ fc,
                                                     const unsigned short* __restrict__ Kbf,
                                                     const unsigned short* __restrict__ Vt,
                                                     unsigned short* __restrict__ Ob) {
    __shared__ unsigned short Ks[3][64 * 192];    // 3 x 24576 B, swizzled chunks
    __shared__ unsigned short Vs[3][128 * 64];    // 3 x 16384 B, swizzled chunks
    __shared__ unsigned short Ps[8][16][PROW];    // 19456 B, wave-private P

    const int bh = blockIdx.x;                  // b*H+h
    const int bx = blockIdx.y;                  // 0..7 pair index
    const int b = bh >> 4, h = bh & 15;
    const int tid = threadIdx.x;
    const int w = tid >> 6, lane = tid & 63;
    const int l16 = lane & 15, quad = lane >> 4;
    const int sw = l16 & 7;                     // read-side swizzle key

    const unsigned short* Kg = Kbf + (size_t)bh * S_ * DQK;
    const unsigned short* Vg = Vt + (size_t)bh * DV * S_;

    // stage K/V tile kt_ into buffer bufi: 5 global_load_lds per wave.
    auto stage = [&](int kt_, int bufi) {
        const int kb_ = kt_ * 64;
#pragma unroll
        for (int i_ = 0; i_ < 3; ++i_) {             // K: 64 rows x 24 chunks
            int ch = (w * 3 + i_) * 64 + lane;
            int r_ = ch / 24, c_ = ch - r_ * 24;
            GLD16(&Kg[(size_t)(kb_ + r_) * DQK + ((c_ ^ (r_ & 7)) << 3)],
                  &Ks[bufi][(w * 3 + i_) * 512]);
        }
#pragma unroll
        for (int i_ = 0; i_ < 2; ++i_) {             // V: 128 rows x 8 chunks
            int ch = (w * 2 + i_) * 64 + lane;
            int r_ = ch >> 3, c_ = ch & 7;
            GLD16(&Vg[(size_t)r_ * S_ + kb_ + ((c_ ^ (r_ & 7)) << 3)],
                  &Vs[bufi][(w * 2 + i_) * 512]);
        }
    };

    for (int half = 0; half < 2; ++half) {
        const int qt = half ? (QTILES - 1 - bx) : bx;
        const int q0 = qt * 128;
        const int ntiles = 2 * qt + 2;
        const int wr0 = q0 + w * 16;            // wave's first q row

        // Q A-frags (16 rows/wave), RoPE fused for d >= 128 -- issued BEFORE
        // the stages so their implicit waits don't drain the stage queue.
        short8 a_q[6];
        {
            const int s = wr0 + l16;
            const unsigned short* qrow = Qb + (size_t)(b * S_ + s) * (H_ * DQK) + h * DQK;
#pragma unroll
            for (int i = 0; i < 6; ++i) {
                short8 t = *(const short8*)&qrow[i * 32 + quad * 8];
                if (i >= 4) {
                    union { short8 v; unsigned short u[8]; } x; x.v = t;
#pragma unroll
                    for (int j = 0; j < 4; ++j) {
                        int ip = (i - 4) * 16 + quad * 4 + j;
                        float c0 = fc[(s * 32 + ip) * 2 + 0];
                        float s0 = fc[(s * 32 + ip) * 2 + 1];
                        float x0 = bf2f(x.u[2 * j]);
                        float x1 = bf2f(x.u[2 * j + 1]);
                        x.u[2 * j]     = f2bf(x0 * c0 - x1 * s0);
                        x.u[2 * j + 1] = f2bf(x0 * s0 + x1 * c0);
                    }
                    t = x.v;
                }
                a_q[i] = t;
            }
        }

        stage(0, 0);
        if (ntiles > 1) stage(1, 1);
        // everything except the newest 5 loads (tile1) retired => tile0 landed
        asm volatile("s_waitcnt vmcnt(5)" ::: "memory");
        __builtin_amdgcn_sched_barrier(0);
        __builtin_amdgcn_s_barrier();
        __builtin_amdgcn_sched_barrier(0);

        const float4v zf = {0.f, 0.f, 0.f, 0.f};
        float4v o_acc[8] = {zf, zf, zf, zf, zf, zf, zf, zf};
        float l_r[4] = {0.f, 0.f, 0.f, 0.f};

        int cb = 0;                             // compute buffer = kt % 3
        for (int kt = 0; kt < ntiles; ++kt) {
            const int kb = kt * 64;

            if (kt + 2 < ntiles) {
                int sb = cb + 2; if (sb >= 3) sb -= 3;
                stage(kt + 2, sb);              // target's readers done at bar(kt-1)
            }

            if (kb <= wr0 + 15) {               // wave not fully causal-masked
                const unsigned short* Kb_ = Ks[cb];
                const unsigned short* Vb_ = Vs[cb];

                // QK^T: 24 ds_read_b128 -> 24 mfma (4 independent acc chains)
                float4v sc[4] = {zf, zf, zf, zf};
#pragma unroll
                for (int i = 0; i < 6; ++i) {
                    short8 bk[4];
#pragma unroll
                    for (int kg = 0; kg < 4; ++kg)
                        bk[kg] = *(const short8*)&Kb_[(kg * 16 + l16) * 192 + (((i * 4 + quad) ^ sw) << 3)];
#pragma unroll
                    for (int kg = 0; kg < 4; ++kg)
                        sc[kg] = __builtin_amdgcn_mfma_f32_16x16x32_bf16(a_q[i], bk[kg], sc[kg], 0, 0, 0);
                }

                // max-free softmax (mask post-exp; wave-uniform mneed branch)
                const bool mneed = (kb + 63 > wr0);
#pragma unroll
                for (int kg = 0; kg < 4; ++kg) {
                    const int key = kb + kg * 16 + l16;
#pragma unroll
                    for (int r = 0; r < 4; ++r) {
                        float p = __expf(sc[kg][r] * SCALEF);
                        if (mneed && key > wr0 + quad * 4 + r) p = 0.f;
                        l_r[r] += p;
                        Ps[w][quad * 4 + r][kg * 16 + l16] = f2bf(p);
                    }
                }

                // PV: Ps is wave-private -> no barrier needed before reads
#pragma unroll
                for (int kc = 0; kc < 2; ++kc) {
                    short8 pa = *(const short8*)&Ps[w][l16][kc * 32 + quad * 8];
#pragma unroll
                    for (int dvt = 0; dvt < 8; ++dvt) {
                        short8 vb = *(const short8*)&Vb_[(dvt * 16 + l16) * 64 + (((kc * 4 + quad) ^ sw) << 3)];
                        o_acc[dvt] = __builtin_amdgcn_mfma_f32_16x16x32_bf16(pa, vb, o_acc[dvt], 0, 0, 0);
                    }
                }
            }

            // own tile-(kt+1) loads landed (leave kt+2's 5 in flight), publish
            if (kt + 2 < ntiles) {
                asm volatile("s_waitcnt vmcnt(5)" ::: "memory");
            } else if (kt + 1 < ntiles) {
                asm volatile("s_waitcnt vmcnt(0)" ::: "memory");
            }
            __builtin_amdgcn_sched_barrier(0);
            __builtin_amdgcn_s_barrier();
            __builtin_amdgcn_sched_barrier(0);

            cb = (cb == 2) ? 0 : cb + 1;
        }

        // epilogue: reduce l over the 16 key-lanes, write O
#pragma unroll
        for (int r = 0; r < 4; ++r) {
            float t = l_r[r];
            t += __shfl_xor(t, 1);
            t += __shfl_xor(t, 2);
            t += __shfl_xor(t, 4);
            t += __shfl_xor(t, 8);
            l_r[r] = t;
        }
#pragma unroll
        for (int r = 0; r < 4; ++r) {
            float inv = 1.f / l_r[r];
            int row = wr0 + quad * 4 + r;
            unsigned short* op = Ob + (size_t)(b * S_ + row) * (H_ * DV) + h * DV;
#pragma unroll
            for (int dvt = 0; dvt < 8; ++dvt)
                op[dvt * 16 + l16] = f2bf(o_acc[dvt][r] * inv);
        }
    }
}

// ---------------------------------------------------------------------------
extern "C" void kernel_launch(void* const* d_in, const int* in_sizes, int n_in,
                              void* d_out, int out_size, void* d_ws, size_t ws_size,
                              hipStream_t stream) {
    const float* x    = (const float*)d_in[0];
    const float* fc   = (const float*)d_in[1];
    const float* Wqa  = (const float*)d_in[2];
    const float* qlw  = (const float*)d_in[3];
    const float* Wqb  = (const float*)d_in[4];
    const float* Wkva = (const float*)d_in[5];
    const float* kvw  = (const float*)d_in[6];
    const float* Wkvb = (const float*)d_in[7];
    const float* Wo   = (const float*)d_in[8];
    float* out = (float*)d_out;

    const int M = B_ * S_;                 // 4096
    char* wsb = (char*)d_ws;

    // R1 (50331648 B): qb bf16 (25165824) + Wob (8388608)
    unsigned short* qb  = (unsigned short*)wsb;
    unsigned short* Wob = (unsigned short*)(wsb + 25165824);
    // R2 (67108864 B), time-multiplexed:
    //   phase 1: qlkvb bf16 (0..17825792), xb (35651584..52428800),
    //            Wcat (52428800..61341696)
    //   phase 2 (after norms_fused, qlkvb/xb/Wcat dead):
    //            attnb (0..16777216), Vt (16777216..33554432),
    //            Kbf (35651584..60817408)
    char* R2 = wsb + 50331648;
    unsigned short* qlkvb = (unsigned short*)R2;                 // 17825792
    unsigned short* xb    = (unsigned short*)(R2 + 35651584);    // 16777216
    unsigned short* Wcat  = (unsigned short*)(R2 + 52428800);    //  8912896
    unsigned short* attnb = (unsigned short*)R2;                 // 16777216
    unsigned short* Vt    = (unsigned short*)(R2 + 16777216);    // 16777216
    unsigned short* Kbf   = (unsigned short*)(R2 + 35651584);    // 25165824
    // R3 (25165824 B)
    char* R3 = R2 + 67108864;
    unsigned short* qlatb = (unsigned short*)R3;                 // 12582912
    unsigned short* Wqbb  = (unsigned short*)(R3 + 12582912);    //  9437184
    // R4 (16777216 B)
    char* R4 = R3 + 25165824;
    unsigned short* kvcb  = (unsigned short*)(R4 + 1048576);     //  4194304
    unsigned short* Wkvbb = (unsigned short*)(R4 + 5242880);     //  4194304

    // 0) convert only what the qlkv GEMM needs: x, Wqa, Wkva
    {
        const long e0 = 1048576;           // x      (M*D/8)
        const long e1 = e0 + 393216;       // Wqa
        const long tot = e1 + 147456;      // Wkva -> 1589248 chunks = 6208 blk
        conv_xa<<<(int)(tot / 256), 256, 0, stream>>>(
            x, xb, e0,
            Wqa, Wcat, e1,
            Wkva, Wcat + (size_t)QLORA * D_);
    }

    // 1) qlkv GEMM (272 blocks) + overlapped Wqb/Wkvb/Wo conversion (64 blocks)
    qlkv_conv<<<336, 512, 0, stream>>>(xb, Wcat, qlkvb,
                                       Wqb, Wqbb, Wkvb, Wkvbb, Wo, Wob);

    // 2) both norms + rope broadcast in ONE launch
    norms_fused<<<2 * M, 256, 0, stream>>>(qlkvb, qlw, kvw, fc, qlatb, kvcb, Kbf);

    // 3) q up-proj + kv up-proj in ONE 448-block launch (LPT: q blocks first)
    gemm_qkv<<<448, 512, 0, stream>>>(qlatb, Wqbb, qb, kvcb, Wkvbb, Vt, Kbf);

    // 4) flash attention: 128-row q-tiles, 8 waves x 16 q-rows, pairs (bx,15-bx)
    flash_mfma<<<dim3(B_ * H_, QTILES / 2), 512, 0, stream>>>(qb, fc, Kbf, Vt, attnb);

    // 5) out = attnb @ Wob^T (256x128 -> 256 blocks, full fill)
    gemm_out<<<dim3(D_ / 128, M / TBM), 512, 0, stream>>>(attnb, Wob, out, M, D_, D_);
}